// Round 5
// baseline (776.944 us; speedup 1.0000x reference)
//
#include <hip/hip_runtime.h>
#include <cstdint>
#include <cstddef>

#define B_    16
#define CIN_  32
#define COUT_ 64
#define N_    1024
#define T_    24
#define SD_   16
#define DD_   16

#define NT_      (N_*T_)          // 24576
#define BNT_     (B_*N_*T_)       // 393216
#define UE_COLS  (B_*T_*SD_)      // 6144
#define XS_COLS  (B_*COUT_*T_)    // 24576
#define HALF_COLS (XS_COLS/2)     // 12288

typedef unsigned short ushort_t;
using bf16x8 = __attribute__((ext_vector_type(8))) short;
using f32x4  = __attribute__((ext_vector_type(4))) float;

// ---- workspace byte offsets ----
#define OFF_DELAY 0ul
#define OFF_M     98304ul
#define OFF_R     360448ul
#define OFF_U     364544ul
#define OFF_W1T   1953792ul
#define OFF_WGBF  2048000ul              // bf16 W_g copy (24576 elems = 49152 B)
#define OFF_SBF   2195456ul
#define OFF_ADJBF 4292608ul
#define OFF_STBF  6389760ul
#define OFF_L2BF  8486912ul
#define OFF_X1    10584064ul             // Ue then P (bf16 1024*6144)
#define OFF_X2    23166976ul             // UeT then XST_h
#define OFF_XS    48332800ul             // bf16 1024*24576
#define OFF_Y1H   98664448ul             // bf16 1024*12288
#define OFF_Y2H   123830272ul            // bf16 1024*12288
#define OFF_WBF   148996096ul            // bf16 weights, 40960 elems = 81920 B

// bf16 weight sub-offsets (element index within WBF)
#define WB_DE   0
#define WB_QT   2048
#define WB_1    4096
#define WB_MIIA 6144
#define WB_KT   8192
#define WB_VT   12288
#define WB_QS   16384
#define WB_KS   20480
#define WB_VS   24576
#define WB_C1A  28672   // [3][64][64]
#define WB_TOTAL 40960

__device__ __forceinline__ float bfb2f(ushort_t h) {
  union { unsigned u; float f; } v; v.u = ((unsigned)h) << 16; return v.f;
}
// software round-to-nearest-even f32->bf16 (proven numerics; R4's HW
// v_cvt_pk_bf16_f32 asm FAILED: biased rounding accumulated to 3x threshold)
__device__ __forceinline__ ushort_t f2bfb(float f) {
  union { float f; unsigned u; } v; v.f = f;
  unsigned u = v.u;
  return (ushort_t)((u + 0x7fffu + ((u >> 16) & 1u)) >> 16);
}
// RNE pack of two f32 into one u32 (lo = low 16 bits). Bit-identical to
// f2bfb(lo) | f2bfb(hi)<<16, ~7 VALU ops instead of ~11.
__device__ __forceinline__ unsigned rne2(float lo, float hi) {
  union { float f; unsigned u; } a, b;
  a.f = lo; b.f = hi;
  unsigned ua = (a.u + 0x7fffu + ((a.u >> 16) & 1u)) >> 16;
  unsigned ub = (b.u + 0x7fffu + ((b.u >> 16) & 1u)) & 0xffff0000u;
  return ua | ub;
}
__device__ __forceinline__ float sigm_(float z) { return 1.f / (1.f + __expf(-z)); }

__device__ __forceinline__ void gl_lds16(const ushort_t* g, ushort_t* l) {
  __builtin_amdgcn_global_load_lds(
      (const __attribute__((address_space(1))) unsigned int*)g,
      (__attribute__((address_space(3))) unsigned int*)l, 16, 0, 0);
}

__device__ __forceinline__ void st4bf(ushort_t* p, float v0, float v1, float v2, float v3) {
  uint2 w;
  w.x = rne2(v0, v1);
  w.y = rne2(v2, v3);
  *(uint2*)p = w;
}

// ---------------------------------------------------------------------------
// k_prep: bf16 supports/adj, f32 transposed W1 (k_final x1 path), bf16 W_g
// copy, bf16 row-major weight copies for k_attn.
// ---------------------------------------------------------------------------
__global__ __launch_bounds__(256) void k_prep(
    const float* __restrict__ supports, const float* __restrict__ adj,
    const float* __restrict__ W_de, const float* __restrict__ Wq_t,
    const float* __restrict__ W_1, const float* __restrict__ W_mii,
    const float* __restrict__ Wk_t, const float* __restrict__ Wv_t,
    const float* __restrict__ Wq_s, const float* __restrict__ Wk_s,
    const float* __restrict__ Wv_s, const float* __restrict__ W_c1,
    const float* __restrict__ W_g,
    ushort_t* __restrict__ Sbf, ushort_t* __restrict__ adjbf,
    float* __restrict__ W1T, ushort_t* __restrict__ WGBF,
    ushort_t* __restrict__ WBF)
{
  int idx = blockIdx.x * 256 + threadIdx.x;
  if (idx < N_*N_) {
    Sbf[idx]   = f2bfb(supports[idx]);
    adjbf[idx] = f2bfb(adj[idx]);
  }
  int j = idx - N_*N_;
  if (j < 0) return;
  if (j < 2048) { int k = j>>6, c = j&63; W1T[j] = W_1[c*32 + k]; return; }
  j -= 2048;
  if (j < 24576) { WGBF[j] = f2bfb(W_g[j]); return; }
  j -= 24576;
  if (j < 2048) { WBF[WB_DE + j] = f2bfb(W_de[j]); return; }
  j -= 2048;
  if (j < 2048) { WBF[WB_QT + j] = f2bfb(Wq_t[j]); return; }
  j -= 2048;
  if (j < 2048) { WBF[WB_1 + j] = f2bfb(W_1[j]); return; }
  j -= 2048;
  if (j < 2048) { int c = j>>5, k = j&31;
                  WBF[WB_MIIA + j] = (k < 16) ? f2bfb(W_mii[c*16 + k]) : (ushort_t)0; return; }
  j -= 2048;
  if (j < 4096) { WBF[WB_KT + j] = f2bfb(Wk_t[j]); return; }
  j -= 4096;
  if (j < 4096) { WBF[WB_VT + j] = f2bfb(Wv_t[j]); return; }
  j -= 4096;
  if (j < 4096) { WBF[WB_QS + j] = f2bfb(Wq_s[j]); return; }
  j -= 4096;
  if (j < 4096) { WBF[WB_KS + j] = f2bfb(Wk_s[j]); return; }
  j -= 4096;
  if (j < 4096) { WBF[WB_VS + j] = f2bfb(Wv_s[j]); return; }
  j -= 4096;
  if (j < 12288) { int d = j >> 12, r = j & 4095, c = r >> 6, jj = r & 63;
                   WBF[WB_C1A + j] = f2bfb(W_c1[(c*64 + jj)*3 + d]); return; }
}
#define PREP_TOTAL (N_*N_ + 2048 + 24576 + WB_TOTAL)

// ---------------------------------------------------------------------------
// k_pre: delay, Mbuf, Rbuf
// ---------------------------------------------------------------------------
__global__ __launch_bounds__(256) void k_pre(
    const float* __restrict__ CD, const float* __restrict__ Wd,
    const float* __restrict__ CS, const float* __restrict__ W_mii,
    const float* __restrict__ adj,
    float* __restrict__ delay, float* __restrict__ Mbuf, float* __restrict__ Rbuf)
{
  int idx = blockIdx.x * 256 + threadIdx.x;
  if (idx < NT_) {
    int n = idx / T_, t = idx % T_;
    float z = 0.f;
    #pragma unroll
    for (int d = 0; d < DD_; ++d) z += CD[n*DD_ + d] * Wd[d*T_ + t];
    delay[idx] = sigm_(tanhf(z));
  }
  int i2 = idx - NT_;
  if (i2 >= 0 && i2 < N_*COUT_) {
    int n = i2 / COUT_, c = i2 % COUT_;
    float z = 0.f;
    #pragma unroll
    for (int e = 0; e < SD_; ++e) z += CS[n*SD_ + e] * W_mii[c*SD_ + e];
    Mbuf[i2] = z;
  }
  int i3 = idx - NT_ - N_*COUT_;
  if (i3 >= 0 && i3 < 8*N_) {
    int n = i3 >> 3, jl = i3 & 7;
    const float* row = adj + (size_t)n * N_;
    float s = 0.f;
    for (int m = jl; m < N_; m += 8) s += row[m];
    s += __shfl_xor(s, 1);
    s += __shfl_xor(s, 2);
    s += __shfl_xor(s, 4);
    if (jl == 0) Rbuf[n] = s;
  }
}

// ---------------------------------------------------------------------------
// k_u: u + Ue (Ue writes packed: 8 rne2 + 2 uint4 stores)
// ---------------------------------------------------------------------------
__global__ __launch_bounds__(256) void k_u(
    const float* __restrict__ x, const float* __restrict__ W_pro,
    const float* __restrict__ b_pro, const float* __restrict__ CS,
    float* __restrict__ u, ushort_t* __restrict__ Ue)
{
  int idx = blockIdx.x * 256 + threadIdx.x;
  if (idx >= BNT_) return;
  int t = idx % T_;
  int n = (idx / T_) % N_;
  int b = idx / (T_ * N_);
  const float* xp = x + ((size_t)b * CIN_ * N_ + n) * T_ + t;
  float z = b_pro[0];
  #pragma unroll
  for (int i = 0; i < CIN_; ++i) z += W_pro[i] * xp[(size_t)i * NT_];
  u[idx] = z;
  ushort_t* up = Ue + (size_t)n * UE_COLS + (b * T_ + t) * SD_;
  unsigned w[8];
  #pragma unroll
  for (int e = 0; e < 8; ++e)
    w[e] = rne2(z * CS[n*SD_ + 2*e], z * CS[n*SD_ + 2*e + 1]);
  ((uint4*)up)[0] = make_uint4(w[0], w[1], w[2], w[3]);
  ((uint4*)up)[1] = make_uint4(w[4], w[5], w[6], w[7]);
}

// ---------------------------------------------------------------------------
// k_tr: bf16 transpose dst[c*R + r] = src[r*sstride + c]
// ---------------------------------------------------------------------------
__global__ __launch_bounds__(256) void k_tr(
    const ushort_t* __restrict__ src, ushort_t* __restrict__ dst,
    int R, int sstride)
{
  __shared__ ushort_t tb[32][33];
  const int tid = threadIdx.x;
  const int tx = tid & 31, ty = tid >> 5;
  const int c0 = blockIdx.x * 32, r0 = blockIdx.y * 32;
  #pragma unroll
  for (int p = 0; p < 4; ++p) {
    int r = r0 + ty + p*8;
    tb[ty + p*8][tx] = src[(size_t)r * sstride + c0 + tx];
  }
  __syncthreads();
  #pragma unroll
  for (int p = 0; p < 4; ++p) {
    int c = c0 + ty + p*8;
    dst[(size_t)c * R + r0 + tx] = tb[tx][ty + p*8];
  }
}

// ---------------------------------------------------------------------------
// k_mmx: MFMA GEMM
// ---------------------------------------------------------------------------
template<int MODE>
__global__ __launch_bounds__(256) void k_mmx(
    const ushort_t* __restrict__ Abf, const ushort_t* __restrict__ BT,
    ushort_t* __restrict__ Cc, int ncols)
{
  __shared__ ushort_t As[128*64];
  __shared__ ushort_t Bs[128*64];
  const int tid  = threadIdx.x;
  const int wave = tid >> 6, lane = tid & 63;
  const int row0 = blockIdx.y * 128;
  const int col0 = blockIdx.x * 128;
  const int wm = (wave >> 1) * 64, wn = (wave & 1) * 64;
  const int l15 = lane & 15, quad = lane >> 4, l7 = lane & 7;

  f32x4 acc[4][4];
  #pragma unroll
  for (int i = 0; i < 4; ++i)
    #pragma unroll
    for (int j = 0; j < 4; ++j) acc[i][j] = (f32x4){0.f,0.f,0.f,0.f};

  for (int kb = 0; kb < 1024; kb += 64) {
    #pragma unroll
    for (int p = 0; p < 4; ++p) {
      int chunk = p*256 + tid;
      int r = chunk >> 3, pc = chunk & 7;
      int kc = pc ^ (r & 7);
      gl_lds16(Abf + (size_t)(row0 + r)*1024 + (kb + kc*8), &As[chunk*8]);
    }
    #pragma unroll
    for (int p = 0; p < 4; ++p) {
      int chunk = p*256 + tid;
      int r = chunk >> 3, pc = chunk & 7;
      int kc = pc ^ (r & 7);
      gl_lds16(BT + (size_t)(col0 + r)*1024 + (kb + kc*8), &Bs[chunk*8]);
    }
    __syncthreads();
    #pragma unroll
    for (int kh = 0; kh < 2; ++kh) {
      const int kcb = kh * 4;
      bf16x8 af[4], bfr[4];
      #pragma unroll
      for (int mi = 0; mi < 4; ++mi)
        af[mi] = *(const bf16x8*)&As[(wm + mi*16 + l15)*64 + (((kcb + quad) ^ l7) << 3)];
      #pragma unroll
      for (int ni = 0; ni < 4; ++ni)
        bfr[ni] = *(const bf16x8*)&Bs[(wn + ni*16 + l15)*64 + (((kcb + quad) ^ l7) << 3)];
      #pragma unroll
      for (int mi = 0; mi < 4; ++mi)
        #pragma unroll
        for (int ni = 0; ni < 4; ++ni)
          acc[mi][ni] = __builtin_amdgcn_mfma_f32_16x16x32_bf16(
              af[mi], bfr[ni], acc[mi][ni], 0, 0, 0);
    }
    __syncthreads();
  }

  #pragma unroll
  for (int mi = 0; mi < 4; ++mi) {
    int grow_b = row0 + wm + mi*16 + quad*4;
    #pragma unroll
    for (int ni = 0; ni < 4; ++ni) {
      int gcol = col0 + wn + ni*16 + l15;
      #pragma unroll
      for (int j = 0; j < 4; ++j) {
        float v = acc[mi][ni][j];
        int grow = grow_b + j;
        if (MODE == 2) v = 2.f*v - ((grow == gcol) ? 1.f : 0.f);
        Cc[(size_t)grow * ncols + gcol] = f2bfb(v);
      }
    }
  }
}

// ---------------------------------------------------------------------------
// k_mmy: fused Y1=S@XST, Y2=L2@XST in one launch (by<8 -> Y1, else Y2).
// ---------------------------------------------------------------------------
__global__ __launch_bounds__(256) void k_mmy(
    const ushort_t* __restrict__ Sbf, const ushort_t* __restrict__ L2bf,
    const ushort_t* __restrict__ BT,
    ushort_t* __restrict__ Y1, ushort_t* __restrict__ Y2, int ncols)
{
  __shared__ ushort_t As[128*64];
  __shared__ ushort_t Bs[128*64];
  const int tid  = threadIdx.x;
  const int wave = tid >> 6, lane = tid & 63;
  const bool isY2 = blockIdx.y >= 8;
  const ushort_t* Abf = isY2 ? L2bf : Sbf;
  ushort_t* Cc = isY2 ? Y2 : Y1;
  const int row0 = (blockIdx.y & 7) * 128;
  const int col0 = blockIdx.x * 128;
  const int wm = (wave >> 1) * 64, wn = (wave & 1) * 64;
  const int l15 = lane & 15, quad = lane >> 4, l7 = lane & 7;

  f32x4 acc[4][4];
  #pragma unroll
  for (int i = 0; i < 4; ++i)
    #pragma unroll
    for (int j = 0; j < 4; ++j) acc[i][j] = (f32x4){0.f,0.f,0.f,0.f};

  for (int kb = 0; kb < 1024; kb += 64) {
    #pragma unroll
    for (int p = 0; p < 4; ++p) {
      int chunk = p*256 + tid;
      int r = chunk >> 3, pc = chunk & 7;
      int kc = pc ^ (r & 7);
      gl_lds16(Abf + (size_t)(row0 + r)*1024 + (kb + kc*8), &As[chunk*8]);
    }
    #pragma unroll
    for (int p = 0; p < 4; ++p) {
      int chunk = p*256 + tid;
      int r = chunk >> 3, pc = chunk & 7;
      int kc = pc ^ (r & 7);
      gl_lds16(BT + (size_t)(col0 + r)*1024 + (kb + kc*8), &Bs[chunk*8]);
    }
    __syncthreads();
    #pragma unroll
    for (int kh = 0; kh < 2; ++kh) {
      const int kcb = kh * 4;
      bf16x8 af[4], bfr[4];
      #pragma unroll
      for (int mi = 0; mi < 4; ++mi)
        af[mi] = *(const bf16x8*)&As[(wm + mi*16 + l15)*64 + (((kcb + quad) ^ l7) << 3)];
      #pragma unroll
      for (int ni = 0; ni < 4; ++ni)
        bfr[ni] = *(const bf16x8*)&Bs[(wn + ni*16 + l15)*64 + (((kcb + quad) ^ l7) << 3)];
      #pragma unroll
      for (int mi = 0; mi < 4; ++mi)
        #pragma unroll
        for (int ni = 0; ni < 4; ++ni)
          acc[mi][ni] = __builtin_amdgcn_mfma_f32_16x16x32_bf16(
              af[mi], bfr[ni], acc[mi][ni], 0, 0, 0);
    }
    __syncthreads();
  }

  #pragma unroll
  for (int mi = 0; mi < 4; ++mi) {
    int grow_b = row0 + wm + mi*16 + quad*4;
    #pragma unroll
    for (int ni = 0; ni < 4; ++ni) {
      int gcol = col0 + wn + ni*16 + l15;
      #pragma unroll
      for (int j = 0; j < 4; ++j)
        Cc[(size_t)(grow_b + j) * ncols + gcol] = f2bfb(acc[mi][ni][j]);
    }
  }
}

// ---------------------------------------------------------------------------
// k_attn_mfma R5: one block per (n,b).
//  = R3 structure (proven numerics) +
//   - rne2 pair-pack (software RNE, bit-identical rounding, fewer VALU)
//   - softmax __expf
//   - Pts staging removed: p2 loads the P B-frag directly from global
//     (quad<2 loads 16B, quad>=2 zero — same zero-pad semantics; rows >=24
//     masked-garbage exactly as R3's uninitialized Pts rows were)
// ---------------------------------------------------------------------------
#define SW 72
__global__ __launch_bounds__(256, 6) void k_attn_mfma(
    const float* __restrict__ x,
    const float* __restrict__ delay, const float* __restrict__ Mbuf,
    const float* __restrict__ Rbuf, const float* __restrict__ u,
    const ushort_t* __restrict__ P,
    const ushort_t* __restrict__ WBF,
    const float* __restrict__ b_de, const float* __restrict__ bq_t,
    const float* __restrict__ b_1,  const float* __restrict__ b_mii,
    const float* __restrict__ bk_t, const float* __restrict__ bv_t,
    const float* __restrict__ bq_s, const float* __restrict__ bk_s,
    const float* __restrict__ bv_s, const float* __restrict__ b_c1,
    ushort_t* __restrict__ XS)
{
  const int n = blockIdx.x, b = blockIdx.y;
  const int tid = threadIdx.x, wave = tid >> 6, lane = tid & 63;
  const int l15 = lane & 15, quad = lane >> 4;

  __shared__ __align__(16) char smem[24352];
  ushort_t* bufQ = (ushort_t*)(smem + 0);       // pool A: Qt[2-4], Qs[7-8]
  ushort_t* XDg  = (ushort_t*)(smem + 0);       //   alias: XDg[5-6] (34 rows)
  ushort_t* Bc   = (ushort_t*)(smem + 4896);    // pool B: x [stage-2]
  ushort_t* bufK = (ushort_t*)(smem + 4896);    //   alias: Kt[3-4], Ks[7-8]
  ushort_t* bufD = (ushort_t*)(smem + 9504);    // D[2-3], x1c[6-7]
  ushort_t* scb  = (ushort_t*)(smem + 9504);    //   alias: P bf16 [4-5],[8-9]
  ushort_t* Sts  = (ushort_t*)(smem + 14112);   // S [2-7]
  ushort_t* V2   = (ushort_t*)(smem + 18720);   // V [c][s] [3-5],[7-9]
  float* delay_s = (float*)(smem + 23840);
  float* urow    = (float*)(smem + 23968);
  float* Mrow    = (float*)(smem + 24096);

  // ---- staging ----
  for (int i = tid; i < 768; i += 256) {
    int ci = i / 24, t = i - ci*24;
    Bc[t*SW + ci] = f2bfb(x[(((size_t)b*CIN_ + ci)*N_ + n)*T_ + t]);
  }
  if (tid < 32)       urow[tid] = (tid < 24) ? u[((size_t)b*N_ + n)*T_ + tid] : 0.f;
  else if (tid < 64)  { int t = tid - 32; delay_s[t] = (t < 24) ? delay[n*T_ + t] : 0.f; }
  else if (tid < 128) Mrow[tid - 64] = Mbuf[n*COUT_ + (tid - 64)];
  __syncthreads();

  const int c0 = wave * 16;
  const float Rn = Rbuf[n];
  float x1r[2][4];   // x_input1 registers, p2 -> p5

  // ---- phase 2: D, Q_t, x_input1(regs), S ----
  {
    bf16x8 aD = *(const bf16x8*)(WBF + WB_DE   + (c0+l15)*32 + quad*8);
    bf16x8 aQ = *(const bf16x8*)(WBF + WB_QT   + (c0+l15)*32 + quad*8);
    bf16x8 a1w = *(const bf16x8*)(WBF + WB_1   + (c0+l15)*32 + quad*8);
    bf16x8 aS = *(const bf16x8*)(WBF + WB_MIIA + (c0+l15)*32 + quad*8);
    float4 bD4 = *(const float4*)&b_de [c0 + quad*4];
    float4 bQ4 = *(const float4*)&bq_t [c0 + quad*4];
    float4 b14 = *(const float4*)&b_1  [c0 + quad*4];
    float4 bS4 = *(const float4*)&b_mii[c0 + quad*4];
    float4 Mv4 = *(const float4*)&Mrow [c0 + quad*4];
    float bD[4] = {bD4.x,bD4.y,bD4.z,bD4.w};
    float bQ[4] = {bQ4.x,bQ4.y,bQ4.z,bQ4.w};
    float b1a[4] = {b14.x,b14.y,b14.z,b14.w};
    float bS[4] = {bS4.x,bS4.y,bS4.z,bS4.w};
    float Mv[4] = {Mv4.x,Mv4.y,Mv4.z,Mv4.w};
    #pragma unroll
    for (int nt = 0; nt < 2; ++nt) {
      int bt = nt*16 + l15;
      bf16x8 bx = *(const bf16x8*)&Bc[bt*SW + quad*8];
      bf16x8 bp = (bf16x8){0,0,0,0,0,0,0,0};
      if (quad < 2)
        bp = *(const bf16x8*)(P + (size_t)n*UE_COLS + (b*T_ + bt)*SD_ + quad*8);
      f32x4 z = {0.f,0.f,0.f,0.f};
      f32x4 accD = __builtin_amdgcn_mfma_f32_16x16x32_bf16(aD, bx, z, 0,0,0);
      f32x4 accQ = __builtin_amdgcn_mfma_f32_16x16x32_bf16(aQ, bx, z, 0,0,0);
      f32x4 acc1 = __builtin_amdgcn_mfma_f32_16x16x32_bf16(a1w, bx, z, 0,0,0);
      f32x4 accS = __builtin_amdgcn_mfma_f32_16x16x32_bf16(aS, bp, z, 0,0,0);
      float dl = delay_s[bt], ut = urow[bt];
      st4bf(&bufD[bt*SW + c0 + quad*4],
            (accD[0]+bD[0])*dl, (accD[1]+bD[1])*dl, (accD[2]+bD[2])*dl, (accD[3]+bD[3])*dl);
      st4bf(&bufQ[bt*SW + c0 + quad*4],
            accQ[0]+bQ[0], accQ[1]+bQ[1], accQ[2]+bQ[2], accQ[3]+bQ[3]);
      #pragma unroll
      for (int r = 0; r < 4; ++r) x1r[nt][r] = acc1[r] + b1a[r];
      st4bf(&Sts[bt*SW + c0 + quad*4],
            accS[0] + ut*Mv[0] + bS[0]*(1.f+Rn), accS[1] + ut*Mv[1] + bS[1]*(1.f+Rn),
            accS[2] + ut*Mv[2] + bS[2]*(1.f+Rn), accS[3] + ut*Mv[3] + bS[3]*(1.f+Rn));
    }
  }
  __syncthreads();

  // ---- phase 3: K_t, V_t from D; zero V2 cols 24..31 ----
  {
    for (int i = tid; i < 512; i += 256) V2[(i>>3)*40 + 24 + (i&7)] = 0;
    bf16x8 aK0 = *(const bf16x8*)(WBF + WB_KT + (c0+l15)*64 + quad*8);
    bf16x8 aK1 = *(const bf16x8*)(WBF + WB_KT + (c0+l15)*64 + 32 + quad*8);
    bf16x8 aV0 = *(const bf16x8*)(WBF + WB_VT + (c0+l15)*64 + quad*8);
    bf16x8 aV1 = *(const bf16x8*)(WBF + WB_VT + (c0+l15)*64 + 32 + quad*8);
    float4 bK4 = *(const float4*)&bk_t[c0 + quad*4];
    float4 bV4 = *(const float4*)&bv_t[c0 + quad*4];
    float bK[4] = {bK4.x,bK4.y,bK4.z,bK4.w};
    float bV[4] = {bV4.x,bV4.y,bV4.z,bV4.w};
    #pragma unroll
    for (int nt = 0; nt < 2; ++nt) {
      int bt = nt*16 + l15;
      bf16x8 b0 = *(const bf16x8*)&bufD[bt*SW + quad*8];
      bf16x8 b1v = *(const bf16x8*)&bufD[bt*SW + 32 + quad*8];
      f32x4 accK = {0.f,0.f,0.f,0.f}, accV = {0.f,0.f,0.f,0.f};
      accK = __builtin_amdgcn_mfma_f32_16x16x32_bf16(aK0, b0,  accK, 0,0,0);
      accK = __builtin_amdgcn_mfma_f32_16x16x32_bf16(aK1, b1v, accK, 0,0,0);
      accV = __builtin_amdgcn_mfma_f32_16x16x32_bf16(aV0, b0,  accV, 0,0,0);
      accV = __builtin_amdgcn_mfma_f32_16x16x32_bf16(aV1, b1v, accV, 0,0,0);
      st4bf(&bufK[bt*SW + c0 + quad*4],
            accK[0]+bK[0], accK[1]+bK[1], accK[2]+bK[2], accK[3]+bK[3]);
      if (bt < 24) {
        #pragma unroll
        for (int r = 0; r < 4; ++r)
          V2[(c0 + quad*4 + r)*40 + bt] = f2bfb(accV[r] + bV[r]);
      }
    }
  }
  __syncthreads();

  // ---- phase 4 + softmax 1 in-register (waves 0,1) -> scb (bufD region) ----
  if (wave < 2) {
    const int mt = wave * 16;
    bf16x8 a0 = *(const bf16x8*)&bufQ[(mt+l15)*SW + quad*8];
    bf16x8 a1f = *(const bf16x8*)&bufQ[(mt+l15)*SW + 32 + quad*8];
    bf16x8 k0a = *(const bf16x8*)&bufK[l15*SW + quad*8];
    bf16x8 k0b = *(const bf16x8*)&bufK[l15*SW + 32 + quad*8];
    bf16x8 k1a = *(const bf16x8*)&bufK[(16+l15)*SW + quad*8];
    bf16x8 k1b = *(const bf16x8*)&bufK[(16+l15)*SW + 32 + quad*8];
    f32x4 s0 = {0.f,0.f,0.f,0.f}, s1 = {0.f,0.f,0.f,0.f};
    s0 = __builtin_amdgcn_mfma_f32_16x16x32_bf16(a0, k0a, s0, 0,0,0);
    s0 = __builtin_amdgcn_mfma_f32_16x16x32_bf16(a1f, k0b, s0, 0,0,0);
    s1 = __builtin_amdgcn_mfma_f32_16x16x32_bf16(a0, k1a, s1, 0,0,0);
    s1 = __builtin_amdgcn_mfma_f32_16x16x32_bf16(a1f, k1b, s1, 0,0,0);
    #pragma unroll
    for (int r = 0; r < 4; ++r) {
      float v0 = 0.125f * s0[r];
      float v1 = (l15 < 8) ? 0.125f * s1[r] : -3.0e38f;
      float mx = fmaxf(v0, v1);
      mx = fmaxf(mx, __shfl_xor(mx, 1));
      mx = fmaxf(mx, __shfl_xor(mx, 2));
      mx = fmaxf(mx, __shfl_xor(mx, 4));
      mx = fmaxf(mx, __shfl_xor(mx, 8));
      float e0 = __expf(v0 - mx);
      float e1 = (l15 < 8) ? __expf(v1 - mx) : 0.f;
      float sm = e0 + e1;
      sm += __shfl_xor(sm, 1);
      sm += __shfl_xor(sm, 2);
      sm += __shfl_xor(sm, 4);
      sm += __shfl_xor(sm, 8);
      float inv = 1.f / sm;
      int t = mt + quad*4 + r;
      bool tv = (t < 24);
      scb[t*40 + l15]      = tv ? f2bfb(e0 * inv) : (ushort_t)0;
      scb[t*40 + 16 + l15] = (tv && l15 < 8) ? f2bfb(e1 * inv) : (ushort_t)0;
    }
  }
  __syncthreads();

  // ---- phase 5: XD[c][t] = V P^T (swapped operands) + x1(regs) -> XDg ----
  {
    for (int i = tid; i < 640; i += 256) {
      int r = i >> 6, cg = i & 63;
      int row = (r == 0) ? 0 : (24 + r);
      XDg[row*SW + cg] = 0;
    }
    bf16x8 aV = *(const bf16x8*)&V2[(c0 + l15)*40 + quad*8];
    #pragma unroll
    for (int nt = 0; nt < 2; ++nt) {
      bf16x8 bP = *(const bf16x8*)&scb[(nt*16 + l15)*40 + quad*8];
      f32x4 z = {0.f,0.f,0.f,0.f};
      f32x4 acc = __builtin_amdgcn_mfma_f32_16x16x32_bf16(aV, bP, z, 0,0,0);
      int t = nt*16 + l15;
      if (t < 24) {
        #pragma unroll
        for (int r = 0; r < 4; ++r)
          XDg[(1 + t)*SW + c0 + quad*4 + r] = f2bfb(acc[r] + x1r[nt][r]);
      }
    }
  }
  __syncthreads();

  // ---- phase 6: x1c = conv_t(XD) -> bufD ----
  {
    float4 bc4 = *(const float4*)&b_c1[c0 + quad*4];
    float bc[4] = {bc4.x,bc4.y,bc4.z,bc4.w};
    f32x4 acc0 = {0.f,0.f,0.f,0.f}, acc1v = {0.f,0.f,0.f,0.f};
    #pragma unroll
    for (int d = 0; d < 3; ++d) {
      const ushort_t* Ad = WBF + WB_C1A + d*4096;
      bf16x8 a0 = *(const bf16x8*)(Ad + (c0+l15)*64 + quad*8);
      bf16x8 a1f = *(const bf16x8*)(Ad + (c0+l15)*64 + 32 + quad*8);
      {
        int rr = 0*16 + l15 + d;
        bf16x8 b0 = *(const bf16x8*)&XDg[rr*SW + quad*8];
        bf16x8 b1f = *(const bf16x8*)&XDg[rr*SW + 32 + quad*8];
        acc0 = __builtin_amdgcn_mfma_f32_16x16x32_bf16(a0, b0, acc0, 0,0,0);
        acc0 = __builtin_amdgcn_mfma_f32_16x16x32_bf16(a1f, b1f, acc0, 0,0,0);
      }
      {
        int rr = 1*16 + l15 + d;
        bf16x8 b0 = *(const bf16x8*)&XDg[rr*SW + quad*8];
        bf16x8 b1f = *(const bf16x8*)&XDg[rr*SW + 32 + quad*8];
        acc1v = __builtin_amdgcn_mfma_f32_16x16x32_bf16(a0, b0, acc1v, 0,0,0);
        acc1v = __builtin_amdgcn_mfma_f32_16x16x32_bf16(a1f, b1f, acc1v, 0,0,0);
      }
    }
    st4bf(&bufD[(0*16 + l15)*SW + c0 + quad*4],
          acc0[0]+bc[0], acc0[1]+bc[1], acc0[2]+bc[2], acc0[3]+bc[3]);
    st4bf(&bufD[(1*16 + l15)*SW + c0 + quad*4],
          acc1v[0]+bc[0], acc1v[1]+bc[1], acc1v[2]+bc[2], acc1v[3]+bc[3]);
  }
  __syncthreads();

  // ---- phase 7: Q_s (from x1c=bufD), K_s, V_s (from S) ----
  {
    bf16x8 aq0 = *(const bf16x8*)(WBF + WB_QS + (c0+l15)*64 + quad*8);
    bf16x8 aq1 = *(const bf16x8*)(WBF + WB_QS + (c0+l15)*64 + 32 + quad*8);
    bf16x8 ak0 = *(const bf16x8*)(WBF + WB_KS + (c0+l15)*64 + quad*8);
    bf16x8 ak1 = *(const bf16x8*)(WBF + WB_KS + (c0+l15)*64 + 32 + quad*8);
    bf16x8 av0 = *(const bf16x8*)(WBF + WB_VS + (c0+l15)*64 + quad*8);
    bf16x8 av1 = *(const bf16x8*)(WBF + WB_VS + (c0+l15)*64 + 32 + quad*8);
    float4 bq4 = *(const float4*)&bq_s[c0 + quad*4];
    float4 bk4 = *(const float4*)&bk_s[c0 + quad*4];
    float4 bv4 = *(const float4*)&bv_s[c0 + quad*4];
    float bq[4] = {bq4.x,bq4.y,bq4.z,bq4.w};
    float bk[4] = {bk4.x,bk4.y,bk4.z,bk4.w};
    float bv[4] = {bv4.x,bv4.y,bv4.z,bv4.w};
    #pragma unroll
    for (int nt = 0; nt < 2; ++nt) {
      int bt = nt*16 + l15;
      bf16x8 bx0 = *(const bf16x8*)&bufD[bt*SW + quad*8];
      bf16x8 bx1 = *(const bf16x8*)&bufD[bt*SW + 32 + quad*8];
      bf16x8 bs0 = *(const bf16x8*)&Sts[bt*SW + quad*8];
      bf16x8 bs1 = *(const bf16x8*)&Sts[bt*SW + 32 + quad*8];
      f32x4 accQ = {0.f,0.f,0.f,0.f}, accK = {0.f,0.f,0.f,0.f}, accV = {0.f,0.f,0.f,0.f};
      accQ = __builtin_amdgcn_mfma_f32_16x16x32_bf16(aq0, bx0, accQ, 0,0,0);
      accQ = __builtin_amdgcn_mfma_f32_16x16x32_bf16(aq1, bx1, accQ, 0,0,0);
      accK = __builtin_amdgcn_mfma_f32_16x16x32_bf16(ak0, bs0, accK, 0,0,0);
      accK = __builtin_amdgcn_mfma_f32_16x16x32_bf16(ak1, bs1, accK, 0,0,0);
      accV = __builtin_amdgcn_mfma_f32_16x16x32_bf16(av0, bs0, accV, 0,0,0);
      accV = __builtin_amdgcn_mfma_f32_16x16x32_bf16(av1, bs1, accV, 0,0,0);
      st4bf(&bufQ[bt*SW + c0 + quad*4],
            accQ[0]+bq[0], accQ[1]+bq[1], accQ[2]+bq[2], accQ[3]+bq[3]);
      st4bf(&bufK[bt*SW + c0 + quad*4],
            accK[0]+bk[0], accK[1]+bk[1], accK[2]+bk[2], accK[3]+bk[3]);
      if (bt < 24) {
        #pragma unroll
        for (int r = 0; r < 4; ++r)
          V2[(c0 + quad*4 + r)*40 + bt] = f2bfb(accV[r] + bv[r]);
      }
    }
  }
  __syncthreads();

  // ---- phase 8 + softmax 2 in-register (waves 0,1) -> scb (bufD region) ----
  if (wave < 2) {
    const int mt = wave * 16;
    bf16x8 a0 = *(const bf16x8*)&bufQ[(mt+l15)*SW + quad*8];
    bf16x8 a1f = *(const bf16x8*)&bufQ[(mt+l15)*SW + 32 + quad*8];
    bf16x8 k0a = *(const bf16x8*)&bufK[l15*SW + quad*8];
    bf16x8 k0b = *(const bf16x8*)&bufK[l15*SW + 32 + quad*8];
    bf16x8 k1a = *(const bf16x8*)&bufK[(16+l15)*SW + quad*8];
    bf16x8 k1b = *(const bf16x8*)&bufK[(16+l15)*SW + 32 + quad*8];
    f32x4 s0 = {0.f,0.f,0.f,0.f}, s1 = {0.f,0.f,0.f,0.f};
    s0 = __builtin_amdgcn_mfma_f32_16x16x32_bf16(a0, k0a, s0, 0,0,0);
    s0 = __builtin_amdgcn_mfma_f32_16x16x32_bf16(a1f, k0b, s0, 0,0,0);
    s1 = __builtin_amdgcn_mfma_f32_16x16x32_bf16(a0, k1a, s1, 0,0,0);
    s1 = __builtin_amdgcn_mfma_f32_16x16x32_bf16(a1f, k1b, s1, 0,0,0);
    #pragma unroll
    for (int r = 0; r < 4; ++r) {
      float v0 = 0.125f * s0[r];
      float v1 = (l15 < 8) ? 0.125f * s1[r] : -3.0e38f;
      float mx = fmaxf(v0, v1);
      mx = fmaxf(mx, __shfl_xor(mx, 1));
      mx = fmaxf(mx, __shfl_xor(mx, 2));
      mx = fmaxf(mx, __shfl_xor(mx, 4));
      mx = fmaxf(mx, __shfl_xor(mx, 8));
      float e0 = __expf(v0 - mx);
      float e1 = (l15 < 8) ? __expf(v1 - mx) : 0.f;
      float sm = e0 + e1;
      sm += __shfl_xor(sm, 1);
      sm += __shfl_xor(sm, 2);
      sm += __shfl_xor(sm, 4);
      sm += __shfl_xor(sm, 8);
      float inv = 1.f / sm;
      int t = mt + quad*4 + r;
      bool tv = (t < 24);
      scb[t*40 + l15]      = tv ? f2bfb(e0 * inv) : (ushort_t)0;
      scb[t*40 + 16 + l15] = (tv && l15 < 8) ? f2bfb(e1 * inv) : (ushort_t)0;
    }
  }
  __syncthreads();

  // ---- phase 9: XS = A_s @ V_s -> global [n][b][c][t] ----
  {
    int nc = wave * 16;
    bf16x8 bv0 = *(const bf16x8*)&V2[(nc + l15)*40 + quad*8];
    #pragma unroll
    for (int mt = 0; mt < 2; ++mt) {
      bf16x8 af = *(const bf16x8*)&scb[(mt*16 + l15)*40 + quad*8];
      f32x4 z = {0.f,0.f,0.f,0.f};
      f32x4 acc = __builtin_amdgcn_mfma_f32_16x16x32_bf16(af, bv0, z, 0,0,0);
      int ccol = nc + l15;
      int t0 = mt*16 + quad*4;
      if (t0 < 24) {
        uint2 w;
        w.x = rne2(acc[0], acc[1]);
        w.y = rne2(acc[2], acc[3]);
        *(uint2*)(XS + (size_t)n*XS_COLS + (size_t)b*COUT_*T_ + ccol*T_ + t0) = w;
      }
    }
  }
}

// ---------------------------------------------------------------------------
// k_final: Chebyshev-gate GEMM on MFMA
// ---------------------------------------------------------------------------
#define ZW 200
__global__ __launch_bounds__(256) void k_final(
    const float* __restrict__ x,
    const ushort_t* __restrict__ XS, const ushort_t* __restrict__ Y1h,
    const ushort_t* __restrict__ Y2h,
    const ushort_t* __restrict__ WGBF,
    const float* __restrict__ W1T, const float* __restrict__ b_1,
    const float* __restrict__ b_g,
    int h, float* __restrict__ out)
{
  const int n = blockIdx.x, bb = blockIdx.y, tid = threadIdx.x;
  const int b = h * 8 + bb;
  const int wave = tid >> 6, lane = tid & 63;
  const int l15 = lane & 15, quad = lane >> 4;

  __shared__ __align__(16) ushort_t Zt[32*ZW];
  __shared__ float x1sh[COUT_*T_];
  __shared__ float xts[CIN_*T_];

  size_t baseg = (size_t)n * XS_COLS + (size_t)b * COUT_ * T_;
  size_t baseh = (size_t)n * HALF_COLS + (size_t)bb * COUT_ * T_;

  for (int i = tid; i < 8*ZW; i += 256) Zt[24*ZW + i] = 0;
  for (int i = tid; i < COUT_*T_; i += 256) {
    int c = i / T_, t = i - c*T_;
    ushort_t* zr = &Zt[t*ZW + 3*c];
    zr[0] = XS [baseg + i];
    zr[1] = Y1h[baseh + i];
    zr[2] = Y2h[baseh + i];
  }
  for (int i = tid; i < CIN_*T_; i += 256) {
    int ci = i / T_, t = i - ci*T_;
    xts[i] = x[(((size_t)b * CIN_ + ci) * N_ + n) * T_ + t];
  }
  __syncthreads();

  {
    const int c = tid >> 2, tq = tid & 3;
    float a[6];
    #pragma unroll
    for (int m = 0; m < 6; ++m) a[m] = b_1[c];
    for (int i = 0; i < CIN_; ++i) {
      float w = W1T[i*64 + c];
      #pragma unroll
      for (int m = 0; m < 6; ++m) a[m] += w * xts[i*T_ + tq + 4*m];
    }
    #pragma unroll
    for (int m = 0; m < 6; ++m) x1sh[c*T_ + tq + 4*m] = a[m];
  }

  f32x4 accF[2] = {{0.f,0.f,0.f,0.f},{0.f,0.f,0.f,0.f}};
  f32x4 accG[2] = {{0.f,0.f,0.f,0.f},{0.f,0.f,0.f,0.f}};
  const ushort_t* WF = WGBF + (size_t)(wave*16 + l15)*192 + quad*8;
  const ushort_t* WG = WF + 64*192;
  #pragma unroll
  for (int ks = 0; ks < 6; ++ks) {
    bf16x8 wf = *(const bf16x8*)(WF + ks*32);
    bf16x8 wg = *(const bf16x8*)(WG + ks*32);
    #pragma unroll
    for (int nt = 0; nt < 2; ++nt) {
      bf16x8 bz = *(const bf16x8*)&Zt[(nt*16 + l15)*ZW + ks*32 + quad*8];
      accF[nt] = __builtin_amdgcn_mfma_f32_16x16x32_bf16(wf, bz, accF[nt], 0,0,0);
      accG[nt] = __builtin_amdgcn_mfma_f32_16x16x32_bf16(wg, bz, accG[nt], 0,0,0);
    }
  }
  __syncthreads();

  {
    float4 bgF4 = *(const float4*)&b_g[wave*16 + quad*4];
    float4 bgG4 = *(const float4*)&b_g[64 + wave*16 + quad*4];
    float bgF[4] = {bgF4.x, bgF4.y, bgF4.z, bgF4.w};
    float bgG[4] = {bgG4.x, bgG4.y, bgG4.z, bgG4.w};
    #pragma unroll
    for (int nt = 0; nt < 2; ++nt) {
      int t = nt*16 + l15;
      if (t < 24) {
        #pragma unroll
        for (int r = 0; r < 4; ++r) {
          int c = wave*16 + quad*4 + r;
          float fv = accF[nt][r] + bgF[r] + x1sh[c*T_ + t];
          float gv = accG[nt][r] + bgG[r];
          out[(((size_t)b * COUT_ + c) * N_ + n) * T_ + t] = fv * sigm_(gv);
        }
      }
    }
  }
}

// ---------------------------------------------------------------------------
extern "C" void kernel_launch(void* const* d_in, const int* in_sizes, int n_in,
                              void* d_out, int out_size, void* d_ws, size_t ws_size,
                              hipStream_t stream) {
  const float* x        = (const float*)d_in[0];
  const float* supports = (const float*)d_in[1];
  const float* CD       = (const float*)d_in[2];
  const float* CS       = (const float*)d_in[3];
  const float* adj      = (const float*)d_in[4];
  const float* W_de  = (const float*)d_in[5];  const float* b_de  = (const float*)d_in[6];
  const float* Wd    = (const float*)d_in[7];
  const float* W_pro = (const float*)d_in[8];  const float* b_pro = (const float*)d_in[9];
  const float* W_mii = (const float*)d_in[10]; const float* b_mii = (const float*)d_in[11];
  const float* W_1   = (const float*)d_in[12]; const float* b_1   = (const float*)d_in[13];
  const float* Wq_t  = (const float*)d_in[14]; const float* bq_t  = (const float*)d_in[15];
  const float* Wk_t  = (const float*)d_in[16]; const float* bk_t  = (const float*)d_in[17];
  const float* Wv_t  = (const float*)d_in[18]; const float* bv_t  = (const float*)d_in[19];
  const float* W_c1  = (const float*)d_in[20]; const float* b_c1  = (const float*)d_in[21];
  const float* Wq_s  = (const float*)d_in[22]; const float* bq_s  = (const float*)d_in[23];
  const float* Wk_s  = (const float*)d_in[24]; const float* bk_s  = (const float*)d_in[25];
  const float* Wv_s  = (const float*)d_in[26]; const float* bv_s  = (const float*)d_in[27];
  const float* W_g   = (const float*)d_in[28]; const float* b_g   = (const float*)d_in[29];
  float* out = (float*)d_out;

  char* ws = (char*)d_ws;
  float*    delay = (float*)(ws + OFF_DELAY);
  float*    Mbuf  = (float*)(ws + OFF_M);
  float*    Rbuf  = (float*)(ws + OFF_R);
  float*    u     = (float*)(ws + OFF_U);
  float*    W1T   = (float*)(ws + OFF_W1T);
  ushort_t* WGBF  = (ushort_t*)(ws + OFF_WGBF);
  ushort_t* Sbf   = (ushort_t*)(ws + OFF_SBF);
  ushort_t* adjbf = (ushort_t*)(ws + OFF_ADJBF);
  ushort_t* STbf  = (ushort_t*)(ws + OFF_STBF);
  ushort_t* L2bf  = (ushort_t*)(ws + OFF_L2BF);
  ushort_t* Ue    = (ushort_t*)(ws + OFF_X1);
  ushort_t* P     = (ushort_t*)(ws + OFF_X1);   // overwrites Ue (dead)
  ushort_t* UeT   = (ushort_t*)(ws + OFF_X2);
  ushort_t* XST   = (ushort_t*)(ws + OFF_X2);   // overwrites UeT (dead)
  ushort_t* XS    = (ushort_t*)(ws + OFF_XS);
  ushort_t* Y1h   = (ushort_t*)(ws + OFF_Y1H);
  ushort_t* Y2h   = (ushort_t*)(ws + OFF_Y2H);
  ushort_t* WBF   = (ushort_t*)(ws + OFF_WBF);

  (void)in_sizes; (void)n_in; (void)out_size; (void)ws_size;

  // 1) conversions + weight prep
  k_prep<<<dim3((PREP_TOTAL + 255)/256), 256, 0, stream>>>(
      supports, adj, W_de, Wq_t, W_1, W_mii, Wk_t, Wv_t, Wq_s, Wk_s, Wv_s,
      W_c1, W_g, Sbf, adjbf, W1T, WGBF, WBF);
  // 2) delay / Mbuf / Rbuf
  k_pre<<<dim3((NT_ + N_*COUT_ + 8*N_ + 255)/256), 256, 0, stream>>>(
      CD, Wd, CS, W_mii, adj, delay, Mbuf, Rbuf);
  // 3) S^T via coalesced transpose
  k_tr<<<dim3(N_/32, N_/32), 256, 0, stream>>>(Sbf, STbf, N_, N_);
  // 4) L2 = 2*S@S - I
  k_mmx<2><<<dim3(8, 8), 256, 0, stream>>>(Sbf, STbf, L2bf, 1024);
  // 5) u + Ue
  k_u<<<dim3((BNT_ + 255)/256), 256, 0, stream>>>(x, W_pro, b_pro, CS, u, Ue);
  // 6) UeT
  k_tr<<<dim3(UE_COLS/32, N_/32), 256, 0, stream>>>(Ue, UeT, N_, UE_COLS);
  // 7) P = adj @ Ue
  k_mmx<0><<<dim3(UE_COLS/128, N_/128), 256, 0, stream>>>(adjbf, UeT, P, UE_COLS);
  // 8) MFMA attention pipeline -> XS
  k_attn_mfma<<<dim3(N_, B_), 256, 0, stream>>>(
      x, delay, Mbuf, Rbuf, u, P, WBF,
      b_de, bq_t, b_1, b_mii, bk_t, bv_t, bq_s, bk_s, bv_s, b_c1, XS);
  // 9) per half: transpose, fused Y1/Y2 GEMM, final
  for (int h = 0; h < 2; ++h) {
    k_tr<<<dim3(HALF_COLS/32, N_/32), 256, 0, stream>>>(
        XS + (size_t)h * HALF_COLS, XST, N_, XS_COLS);
    k_mmy<<<dim3(HALF_COLS/128, 16), 256, 0, stream>>>(
        Sbf, L2bf, XST, Y1h, Y2h, HALF_COLS);
    k_final<<<dim3(N_, 8), 256, 0, stream>>>(
        x, XS, Y1h, Y2h, WGBF, W1T, b_1, b_g, h, out);
  }
}

// Round 6
// 718.704 us; speedup vs baseline: 1.0810x; 1.0810x over previous
//
#include <hip/hip_runtime.h>
#include <cstdint>
#include <cstddef>

#define B_    16
#define CIN_  32
#define COUT_ 64
#define N_    1024
#define T_    24
#define SD_   16
#define DD_   16

#define NT_      (N_*T_)          // 24576
#define BNT_     (B_*N_*T_)       // 393216
#define UE_COLS  (B_*T_*SD_)      // 6144
#define XS_COLS  (B_*COUT_*T_)    // 24576
#define HALF_COLS (XS_COLS/2)     // 12288

typedef unsigned short ushort_t;
using bf16x8 = __attribute__((ext_vector_type(8))) short;
using f32x4  = __attribute__((ext_vector_type(4))) float;

// ---- workspace byte offsets ----
#define OFF_DELAY 0ul
#define OFF_M     98304ul
#define OFF_R     360448ul
#define OFF_U     364544ul
#define OFF_W1T   1953792ul
#define OFF_WGBF  2048000ul              // bf16 W_g copy (24576 elems = 49152 B)
#define OFF_SBF   2195456ul
#define OFF_ADJBF 4292608ul
#define OFF_STBF  6389760ul
#define OFF_L2BF  8486912ul
#define OFF_X1    10584064ul             // Ue then P (bf16 1024*6144)
#define OFF_X2    23166976ul             // UeT then XST_h
#define OFF_XS    48332800ul             // bf16 1024*24576
#define OFF_Y1H   98664448ul             // bf16 1024*12288
#define OFF_Y2H   123830272ul            // bf16 1024*12288
#define OFF_WBF   148996096ul            // bf16 weights, 40960 elems = 81920 B

// bf16 weight sub-offsets (element index within WBF)
#define WB_DE   0
#define WB_QT   2048
#define WB_1    4096
#define WB_MIIA 6144
#define WB_KT   8192
#define WB_VT   12288
#define WB_QS   16384
#define WB_KS   20480
#define WB_VS   24576
#define WB_C1A  28672   // [3][64][64]
#define WB_TOTAL 40960

__device__ __forceinline__ float bfb2f(ushort_t h) {
  union { unsigned u; float f; } v; v.u = ((unsigned)h) << 16; return v.f;
}
// software round-to-nearest-even f32->bf16 (R4's HW v_cvt_pk_bf16_f32 asm
// FAILED numerics — biased rounding accumulated to 3x threshold; keep RNE)
__device__ __forceinline__ ushort_t f2bfb(float f) {
  union { float f; unsigned u; } v; v.f = f;
  unsigned u = v.u;
  return (ushort_t)((u + 0x7fffu + ((u >> 16) & 1u)) >> 16);
}
// RNE pack of two f32 into one u32 (lo = low 16 bits), bit-identical to
// f2bfb pair, fewer VALU ops.
__device__ __forceinline__ unsigned rne2(float lo, float hi) {
  union { float f; unsigned u; } a, b;
  a.f = lo; b.f = hi;
  unsigned ua = (a.u + 0x7fffu + ((a.u >> 16) & 1u)) >> 16;
  unsigned ub = (b.u + 0x7fffu + ((b.u >> 16) & 1u)) & 0xffff0000u;
  return ua | ub;
}
__device__ __forceinline__ float sigm_(float z) { return 1.f / (1.f + __expf(-z)); }

__device__ __forceinline__ void gl_lds16(const ushort_t* g, ushort_t* l) {
  __builtin_amdgcn_global_load_lds(
      (const __attribute__((address_space(1))) unsigned int*)g,
      (__attribute__((address_space(3))) unsigned int*)l, 16, 0, 0);
}

__device__ __forceinline__ void st4bf(ushort_t* p, float v0, float v1, float v2, float v3) {
  uint2 w;
  w.x = rne2(v0, v1);
  w.y = rne2(v2, v3);
  *(uint2*)p = w;
}

// ---------------------------------------------------------------------------
// k_prep: bf16 supports/adj, f32 W1T (legacy, unused), bf16 W_g copy, bf16
// row-major weight copies for k_attn/k_final.
// ---------------------------------------------------------------------------
__global__ __launch_bounds__(256) void k_prep(
    const float* __restrict__ supports, const float* __restrict__ adj,
    const float* __restrict__ W_de, const float* __restrict__ Wq_t,
    const float* __restrict__ W_1, const float* __restrict__ W_mii,
    const float* __restrict__ Wk_t, const float* __restrict__ Wv_t,
    const float* __restrict__ Wq_s, const float* __restrict__ Wk_s,
    const float* __restrict__ Wv_s, const float* __restrict__ W_c1,
    const float* __restrict__ W_g,
    ushort_t* __restrict__ Sbf, ushort_t* __restrict__ adjbf,
    float* __restrict__ W1T, ushort_t* __restrict__ WGBF,
    ushort_t* __restrict__ WBF)
{
  int idx = blockIdx.x * 256 + threadIdx.x;
  if (idx < N_*N_) {
    Sbf[idx]   = f2bfb(supports[idx]);
    adjbf[idx] = f2bfb(adj[idx]);
  }
  int j = idx - N_*N_;
  if (j < 0) return;
  if (j < 2048) { int k = j>>6, c = j&63; W1T[j] = W_1[c*32 + k]; return; }
  j -= 2048;
  if (j < 24576) { WGBF[j] = f2bfb(W_g[j]); return; }
  j -= 24576;
  if (j < 2048) { WBF[WB_DE + j] = f2bfb(W_de[j]); return; }
  j -= 2048;
  if (j < 2048) { WBF[WB_QT + j] = f2bfb(Wq_t[j]); return; }
  j -= 2048;
  if (j < 2048) { WBF[WB_1 + j] = f2bfb(W_1[j]); return; }
  j -= 2048;
  if (j < 2048) { int c = j>>5, k = j&31;
                  WBF[WB_MIIA + j] = (k < 16) ? f2bfb(W_mii[c*16 + k]) : (ushort_t)0; return; }
  j -= 2048;
  if (j < 4096) { WBF[WB_KT + j] = f2bfb(Wk_t[j]); return; }
  j -= 4096;
  if (j < 4096) { WBF[WB_VT + j] = f2bfb(Wv_t[j]); return; }
  j -= 4096;
  if (j < 4096) { WBF[WB_QS + j] = f2bfb(Wq_s[j]); return; }
  j -= 4096;
  if (j < 4096) { WBF[WB_KS + j] = f2bfb(Wk_s[j]); return; }
  j -= 4096;
  if (j < 4096) { WBF[WB_VS + j] = f2bfb(Wv_s[j]); return; }
  j -= 4096;
  if (j < 12288) { int d = j >> 12, r = j & 4095, c = r >> 6, jj = r & 63;
                   WBF[WB_C1A + j] = f2bfb(W_c1[(c*64 + jj)*3 + d]); return; }
}
#define PREP_TOTAL (N_*N_ + 2048 + 24576 + WB_TOTAL)

// ---------------------------------------------------------------------------
// k_pre: delay, Mbuf, Rbuf
// ---------------------------------------------------------------------------
__global__ __launch_bounds__(256) void k_pre(
    const float* __restrict__ CD, const float* __restrict__ Wd,
    const float* __restrict__ CS, const float* __restrict__ W_mii,
    const float* __restrict__ adj,
    float* __restrict__ delay, float* __restrict__ Mbuf, float* __restrict__ Rbuf)
{
  int idx = blockIdx.x * 256 + threadIdx.x;
  if (idx < NT_) {
    int n = idx / T_, t = idx % T_;
    float z = 0.f;
    #pragma unroll
    for (int d = 0; d < DD_; ++d) z += CD[n*DD_ + d] * Wd[d*T_ + t];
    delay[idx] = sigm_(tanhf(z));
  }
  int i2 = idx - NT_;
  if (i2 >= 0 && i2 < N_*COUT_) {
    int n = i2 / COUT_, c = i2 % COUT_;
    float z = 0.f;
    #pragma unroll
    for (int e = 0; e < SD_; ++e) z += CS[n*SD_ + e] * W_mii[c*SD_ + e];
    Mbuf[i2] = z;
  }
  int i3 = idx - NT_ - N_*COUT_;
  if (i3 >= 0 && i3 < 8*N_) {
    int n = i3 >> 3, jl = i3 & 7;
    const float* row = adj + (size_t)n * N_;
    float s = 0.f;
    for (int m = jl; m < N_; m += 8) s += row[m];
    s += __shfl_xor(s, 1);
    s += __shfl_xor(s, 2);
    s += __shfl_xor(s, 4);
    if (jl == 0) Rbuf[n] = s;
  }
}

// ---------------------------------------------------------------------------
// k_u: u + Ue (packed bf16 stores)
// ---------------------------------------------------------------------------
__global__ __launch_bounds__(256) void k_u(
    const float* __restrict__ x, const float* __restrict__ W_pro,
    const float* __restrict__ b_pro, const float* __restrict__ CS,
    float* __restrict__ u, ushort_t* __restrict__ Ue)
{
  int idx = blockIdx.x * 256 + threadIdx.x;
  if (idx >= BNT_) return;
  int t = idx % T_;
  int n = (idx / T_) % N_;
  int b = idx / (T_ * N_);
  const float* xp = x + ((size_t)b * CIN_ * N_ + n) * T_ + t;
  float z = b_pro[0];
  #pragma unroll
  for (int i = 0; i < CIN_; ++i) z += W_pro[i] * xp[(size_t)i * NT_];
  u[idx] = z;
  ushort_t* up = Ue + (size_t)n * UE_COLS + (b * T_ + t) * SD_;
  unsigned w[8];
  #pragma unroll
  for (int e = 0; e < 8; ++e)
    w[e] = rne2(z * CS[n*SD_ + 2*e], z * CS[n*SD_ + 2*e + 1]);
  ((uint4*)up)[0] = make_uint4(w[0], w[1], w[2], w[3]);
  ((uint4*)up)[1] = make_uint4(w[4], w[5], w[6], w[7]);
}

// ---------------------------------------------------------------------------
// k_tr: bf16 transpose dst[c*R + r] = src[r*sstride + c]
// ---------------------------------------------------------------------------
__global__ __launch_bounds__(256) void k_tr(
    const ushort_t* __restrict__ src, ushort_t* __restrict__ dst,
    int R, int sstride)
{
  __shared__ ushort_t tb[32][33];
  const int tid = threadIdx.x;
  const int tx = tid & 31, ty = tid >> 5;
  const int c0 = blockIdx.x * 32, r0 = blockIdx.y * 32;
  #pragma unroll
  for (int p = 0; p < 4; ++p) {
    int r = r0 + ty + p*8;
    tb[ty + p*8][tx] = src[(size_t)r * sstride + c0 + tx];
  }
  __syncthreads();
  #pragma unroll
  for (int p = 0; p < 4; ++p) {
    int c = c0 + ty + p*8;
    dst[(size_t)c * R + r0 + tx] = tb[tx][ty + p*8];
  }
}

// ---------------------------------------------------------------------------
// k_mmx: MFMA GEMM
// ---------------------------------------------------------------------------
template<int MODE>
__global__ __launch_bounds__(256) void k_mmx(
    const ushort_t* __restrict__ Abf, const ushort_t* __restrict__ BT,
    ushort_t* __restrict__ Cc, int ncols)
{
  __shared__ ushort_t As[128*64];
  __shared__ ushort_t Bs[128*64];
  const int tid  = threadIdx.x;
  const int wave = tid >> 6, lane = tid & 63;
  const int row0 = blockIdx.y * 128;
  const int col0 = blockIdx.x * 128;
  const int wm = (wave >> 1) * 64, wn = (wave & 1) * 64;
  const int l15 = lane & 15, quad = lane >> 4, l7 = lane & 7;

  f32x4 acc[4][4];
  #pragma unroll
  for (int i = 0; i < 4; ++i)
    #pragma unroll
    for (int j = 0; j < 4; ++j) acc[i][j] = (f32x4){0.f,0.f,0.f,0.f};

  for (int kb = 0; kb < 1024; kb += 64) {
    #pragma unroll
    for (int p = 0; p < 4; ++p) {
      int chunk = p*256 + tid;
      int r = chunk >> 3, pc = chunk & 7;
      int kc = pc ^ (r & 7);
      gl_lds16(Abf + (size_t)(row0 + r)*1024 + (kb + kc*8), &As[chunk*8]);
    }
    #pragma unroll
    for (int p = 0; p < 4; ++p) {
      int chunk = p*256 + tid;
      int r = chunk >> 3, pc = chunk & 7;
      int kc = pc ^ (r & 7);
      gl_lds16(BT + (size_t)(col0 + r)*1024 + (kb + kc*8), &Bs[chunk*8]);
    }
    __syncthreads();
    #pragma unroll
    for (int kh = 0; kh < 2; ++kh) {
      const int kcb = kh * 4;
      bf16x8 af[4], bfr[4];
      #pragma unroll
      for (int mi = 0; mi < 4; ++mi)
        af[mi] = *(const bf16x8*)&As[(wm + mi*16 + l15)*64 + (((kcb + quad) ^ l7) << 3)];
      #pragma unroll
      for (int ni = 0; ni < 4; ++ni)
        bfr[ni] = *(const bf16x8*)&Bs[(wn + ni*16 + l15)*64 + (((kcb + quad) ^ l7) << 3)];
      #pragma unroll
      for (int mi = 0; mi < 4; ++mi)
        #pragma unroll
        for (int ni = 0; ni < 4; ++ni)
          acc[mi][ni] = __builtin_amdgcn_mfma_f32_16x16x32_bf16(
              af[mi], bfr[ni], acc[mi][ni], 0, 0, 0);
    }
    __syncthreads();
  }

  #pragma unroll
  for (int mi = 0; mi < 4; ++mi) {
    int grow_b = row0 + wm + mi*16 + quad*4;
    #pragma unroll
    for (int ni = 0; ni < 4; ++ni) {
      int gcol = col0 + wn + ni*16 + l15;
      #pragma unroll
      for (int j = 0; j < 4; ++j) {
        float v = acc[mi][ni][j];
        int grow = grow_b + j;
        if (MODE == 2) v = 2.f*v - ((grow == gcol) ? 1.f : 0.f);
        Cc[(size_t)grow * ncols + gcol] = f2bfb(v);
      }
    }
  }
}

// ---------------------------------------------------------------------------
// k_mmy: fused Y1=S@XST, Y2=L2@XST in one launch (by<8 -> Y1, else Y2).
// ---------------------------------------------------------------------------
__global__ __launch_bounds__(256) void k_mmy(
    const ushort_t* __restrict__ Sbf, const ushort_t* __restrict__ L2bf,
    const ushort_t* __restrict__ BT,
    ushort_t* __restrict__ Y1, ushort_t* __restrict__ Y2, int ncols)
{
  __shared__ ushort_t As[128*64];
  __shared__ ushort_t Bs[128*64];
  const int tid  = threadIdx.x;
  const int wave = tid >> 6, lane = tid & 63;
  const bool isY2 = blockIdx.y >= 8;
  const ushort_t* Abf = isY2 ? L2bf : Sbf;
  ushort_t* Cc = isY2 ? Y2 : Y1;
  const int row0 = (blockIdx.y & 7) * 128;
  const int col0 = blockIdx.x * 128;
  const int wm = (wave >> 1) * 64, wn = (wave & 1) * 64;
  const int l15 = lane & 15, quad = lane >> 4, l7 = lane & 7;

  f32x4 acc[4][4];
  #pragma unroll
  for (int i = 0; i < 4; ++i)
    #pragma unroll
    for (int j = 0; j < 4; ++j) acc[i][j] = (f32x4){0.f,0.f,0.f,0.f};

  for (int kb = 0; kb < 1024; kb += 64) {
    #pragma unroll
    for (int p = 0; p < 4; ++p) {
      int chunk = p*256 + tid;
      int r = chunk >> 3, pc = chunk & 7;
      int kc = pc ^ (r & 7);
      gl_lds16(Abf + (size_t)(row0 + r)*1024 + (kb + kc*8), &As[chunk*8]);
    }
    #pragma unroll
    for (int p = 0; p < 4; ++p) {
      int chunk = p*256 + tid;
      int r = chunk >> 3, pc = chunk & 7;
      int kc = pc ^ (r & 7);
      gl_lds16(BT + (size_t)(col0 + r)*1024 + (kb + kc*8), &Bs[chunk*8]);
    }
    __syncthreads();
    #pragma unroll
    for (int kh = 0; kh < 2; ++kh) {
      const int kcb = kh * 4;
      bf16x8 af[4], bfr[4];
      #pragma unroll
      for (int mi = 0; mi < 4; ++mi)
        af[mi] = *(const bf16x8*)&As[(wm + mi*16 + l15)*64 + (((kcb + quad) ^ l7) << 3)];
      #pragma unroll
      for (int ni = 0; ni < 4; ++ni)
        bfr[ni] = *(const bf16x8*)&Bs[(wn + ni*16 + l15)*64 + (((kcb + quad) ^ l7) << 3)];
      #pragma unroll
      for (int mi = 0; mi < 4; ++mi)
        #pragma unroll
        for (int ni = 0; ni < 4; ++ni)
          acc[mi][ni] = __builtin_amdgcn_mfma_f32_16x16x32_bf16(
              af[mi], bfr[ni], acc[mi][ni], 0, 0, 0);
    }
    __syncthreads();
  }

  #pragma unroll
  for (int mi = 0; mi < 4; ++mi) {
    int grow_b = row0 + wm + mi*16 + quad*4;
    #pragma unroll
    for (int ni = 0; ni < 4; ++ni) {
      int gcol = col0 + wn + ni*16 + l15;
      #pragma unroll
      for (int j = 0; j < 4; ++j)
        Cc[(size_t)(grow_b + j) * ncols + gcol] = f2bfb(acc[mi][ni][j]);
    }
  }
}

// ---------------------------------------------------------------------------
// k_attn_mfma R6: R3 structure + rne2 + __expf; P staged via LDS again
// (R5's direct-global P load doubled WRITE_SIZE via L2 thrash — reverted).
// ---------------------------------------------------------------------------
#define SW 72
__global__ __launch_bounds__(256, 6) void k_attn_mfma(
    const float* __restrict__ x,
    const float* __restrict__ delay, const float* __restrict__ Mbuf,
    const float* __restrict__ Rbuf, const float* __restrict__ u,
    const ushort_t* __restrict__ P,
    const ushort_t* __restrict__ WBF,
    const float* __restrict__ b_de, const float* __restrict__ bq_t,
    const float* __restrict__ b_1,  const float* __restrict__ b_mii,
    const float* __restrict__ bk_t, const float* __restrict__ bv_t,
    const float* __restrict__ bq_s, const float* __restrict__ bk_s,
    const float* __restrict__ bv_s, const float* __restrict__ b_c1,
    ushort_t* __restrict__ XS)
{
  const int n = blockIdx.x, b = blockIdx.y;
  const int tid = threadIdx.x, wave = tid >> 6, lane = tid & 63;
  const int l15 = lane & 15, quad = lane >> 4;

  __shared__ __align__(16) char smem[24352];
  ushort_t* bufQ = (ushort_t*)(smem + 0);       // pool A: Qt[2-4], Qs[7-8]
  ushort_t* XDg  = (ushort_t*)(smem + 0);       //   alias: XDg[5-6] (34 rows)
  ushort_t* Bc   = (ushort_t*)(smem + 4896);    // pool B: x [stage-2]
  ushort_t* bufK = (ushort_t*)(smem + 4896);    //   alias: Kt[3-4], Ks[7-8]
  ushort_t* bufD = (ushort_t*)(smem + 9504);    // D[2-3], x1c[6-7]
  ushort_t* scb  = (ushort_t*)(smem + 9504);    //   alias: P bf16 [4-5],[8-9]
  ushort_t* Sts  = (ushort_t*)(smem + 14112);   // S [2-7]
  ushort_t* V2   = (ushort_t*)(smem + 18720);   // V [c][s] [3-5],[7-9]
  ushort_t* Pts  = (ushort_t*)(smem + 18720);   //   alias: P^T staging [st-2]
  float* delay_s = (float*)(smem + 23840);
  float* urow    = (float*)(smem + 23968);
  float* Mrow    = (float*)(smem + 24096);

  // ---- staging ----
  for (int i = tid; i < 768; i += 256) {
    int ci = i / 24, t = i - ci*24;
    Bc[t*SW + ci] = f2bfb(x[(((size_t)b*CIN_ + ci)*N_ + n)*T_ + t]);
  }
  for (int i = tid; i < 768; i += 256) {
    int t = i >> 5, e = i & 31;
    Pts[t*40 + e] = (e < 16) ? P[(size_t)n*UE_COLS + (b*T_ + t)*SD_ + e] : (ushort_t)0;
  }
  if (tid < 32)       urow[tid] = (tid < 24) ? u[((size_t)b*N_ + n)*T_ + tid] : 0.f;
  else if (tid < 64)  { int t = tid - 32; delay_s[t] = (t < 24) ? delay[n*T_ + t] : 0.f; }
  else if (tid < 128) Mrow[tid - 64] = Mbuf[n*COUT_ + (tid - 64)];
  __syncthreads();

  const int c0 = wave * 16;
  const float Rn = Rbuf[n];
  float x1r[2][4];   // x_input1 registers, p2 -> p5

  // ---- phase 2: D, Q_t, x_input1(regs), S ----
  {
    bf16x8 aD = *(const bf16x8*)(WBF + WB_DE   + (c0+l15)*32 + quad*8);
    bf16x8 aQ = *(const bf16x8*)(WBF + WB_QT   + (c0+l15)*32 + quad*8);
    bf16x8 a1w = *(const bf16x8*)(WBF + WB_1   + (c0+l15)*32 + quad*8);
    bf16x8 aS = *(const bf16x8*)(WBF + WB_MIIA + (c0+l15)*32 + quad*8);
    float4 bD4 = *(const float4*)&b_de [c0 + quad*4];
    float4 bQ4 = *(const float4*)&bq_t [c0 + quad*4];
    float4 b14 = *(const float4*)&b_1  [c0 + quad*4];
    float4 bS4 = *(const float4*)&b_mii[c0 + quad*4];
    float4 Mv4 = *(const float4*)&Mrow [c0 + quad*4];
    float bD[4] = {bD4.x,bD4.y,bD4.z,bD4.w};
    float bQ[4] = {bQ4.x,bQ4.y,bQ4.z,bQ4.w};
    float b1a[4] = {b14.x,b14.y,b14.z,b14.w};
    float bS[4] = {bS4.x,bS4.y,bS4.z,bS4.w};
    float Mv[4] = {Mv4.x,Mv4.y,Mv4.z,Mv4.w};
    #pragma unroll
    for (int nt = 0; nt < 2; ++nt) {
      int bt = nt*16 + l15;
      bf16x8 bx = *(const bf16x8*)&Bc[bt*SW + quad*8];
      bf16x8 bp = *(const bf16x8*)&Pts[bt*40 + quad*8];
      f32x4 z = {0.f,0.f,0.f,0.f};
      f32x4 accD = __builtin_amdgcn_mfma_f32_16x16x32_bf16(aD, bx, z, 0,0,0);
      f32x4 accQ = __builtin_amdgcn_mfma_f32_16x16x32_bf16(aQ, bx, z, 0,0,0);
      f32x4 acc1 = __builtin_amdgcn_mfma_f32_16x16x32_bf16(a1w, bx, z, 0,0,0);
      f32x4 accS = __builtin_amdgcn_mfma_f32_16x16x32_bf16(aS, bp, z, 0,0,0);
      float dl = delay_s[bt], ut = urow[bt];
      st4bf(&bufD[bt*SW + c0 + quad*4],
            (accD[0]+bD[0])*dl, (accD[1]+bD[1])*dl, (accD[2]+bD[2])*dl, (accD[3]+bD[3])*dl);
      st4bf(&bufQ[bt*SW + c0 + quad*4],
            accQ[0]+bQ[0], accQ[1]+bQ[1], accQ[2]+bQ[2], accQ[3]+bQ[3]);
      #pragma unroll
      for (int r = 0; r < 4; ++r) x1r[nt][r] = acc1[r] + b1a[r];
      st4bf(&Sts[bt*SW + c0 + quad*4],
            accS[0] + ut*Mv[0] + bS[0]*(1.f+Rn), accS[1] + ut*Mv[1] + bS[1]*(1.f+Rn),
            accS[2] + ut*Mv[2] + bS[2]*(1.f+Rn), accS[3] + ut*Mv[3] + bS[3]*(1.f+Rn));
    }
  }
  __syncthreads();

  // ---- phase 3: K_t, V_t from D; re-zero V2 cols 24..31 (Pts dead) ----
  {
    for (int i = tid; i < 512; i += 256) V2[(i>>3)*40 + 24 + (i&7)] = 0;
    bf16x8 aK0 = *(const bf16x8*)(WBF + WB_KT + (c0+l15)*64 + quad*8);
    bf16x8 aK1 = *(const bf16x8*)(WBF + WB_KT + (c0+l15)*64 + 32 + quad*8);
    bf16x8 aV0 = *(const bf16x8*)(WBF + WB_VT + (c0+l15)*64 + quad*8);
    bf16x8 aV1 = *(const bf16x8*)(WBF + WB_VT + (c0+l15)*64 + 32 + quad*8);
    float4 bK4 = *(const float4*)&bk_t[c0 + quad*4];
    float4 bV4 = *(const float4*)&bv_t[c0 + quad*4];
    float bK[4] = {bK4.x,bK4.y,bK4.z,bK4.w};
    float bV[4] = {bV4.x,bV4.y,bV4.z,bV4.w};
    #pragma unroll
    for (int nt = 0; nt < 2; ++nt) {
      int bt = nt*16 + l15;
      bf16x8 b0 = *(const bf16x8*)&bufD[bt*SW + quad*8];
      bf16x8 b1v = *(const bf16x8*)&bufD[bt*SW + 32 + quad*8];
      f32x4 accK = {0.f,0.f,0.f,0.f}, accV = {0.f,0.f,0.f,0.f};
      accK = __builtin_amdgcn_mfma_f32_16x16x32_bf16(aK0, b0,  accK, 0,0,0);
      accK = __builtin_amdgcn_mfma_f32_16x16x32_bf16(aK1, b1v, accK, 0,0,0);
      accV = __builtin_amdgcn_mfma_f32_16x16x32_bf16(aV0, b0,  accV, 0,0,0);
      accV = __builtin_amdgcn_mfma_f32_16x16x32_bf16(aV1, b1v, accV, 0,0,0);
      st4bf(&bufK[bt*SW + c0 + quad*4],
            accK[0]+bK[0], accK[1]+bK[1], accK[2]+bK[2], accK[3]+bK[3]);
      if (bt < 24) {
        #pragma unroll
        for (int r = 0; r < 4; ++r)
          V2[(c0 + quad*4 + r)*40 + bt] = f2bfb(accV[r] + bV[r]);
      }
    }
  }
  __syncthreads();

  // ---- phase 4 + softmax 1 in-register (waves 0,1) -> scb (bufD region) ----
  if (wave < 2) {
    const int mt = wave * 16;
    bf16x8 a0 = *(const bf16x8*)&bufQ[(mt+l15)*SW + quad*8];
    bf16x8 a1f = *(const bf16x8*)&bufQ[(mt+l15)*SW + 32 + quad*8];
    bf16x8 k0a = *(const bf16x8*)&bufK[l15*SW + quad*8];
    bf16x8 k0b = *(const bf16x8*)&bufK[l15*SW + 32 + quad*8];
    bf16x8 k1a = *(const bf16x8*)&bufK[(16+l15)*SW + quad*8];
    bf16x8 k1b = *(const bf16x8*)&bufK[(16+l15)*SW + 32 + quad*8];
    f32x4 s0 = {0.f,0.f,0.f,0.f}, s1 = {0.f,0.f,0.f,0.f};
    s0 = __builtin_amdgcn_mfma_f32_16x16x32_bf16(a0, k0a, s0, 0,0,0);
    s0 = __builtin_amdgcn_mfma_f32_16x16x32_bf16(a1f, k0b, s0, 0,0,0);
    s1 = __builtin_amdgcn_mfma_f32_16x16x32_bf16(a0, k1a, s1, 0,0,0);
    s1 = __builtin_amdgcn_mfma_f32_16x16x32_bf16(a1f, k1b, s1, 0,0,0);
    #pragma unroll
    for (int r = 0; r < 4; ++r) {
      float v0 = 0.125f * s0[r];
      float v1 = (l15 < 8) ? 0.125f * s1[r] : -3.0e38f;
      float mx = fmaxf(v0, v1);
      mx = fmaxf(mx, __shfl_xor(mx, 1));
      mx = fmaxf(mx, __shfl_xor(mx, 2));
      mx = fmaxf(mx, __shfl_xor(mx, 4));
      mx = fmaxf(mx, __shfl_xor(mx, 8));
      float e0 = __expf(v0 - mx);
      float e1 = (l15 < 8) ? __expf(v1 - mx) : 0.f;
      float sm = e0 + e1;
      sm += __shfl_xor(sm, 1);
      sm += __shfl_xor(sm, 2);
      sm += __shfl_xor(sm, 4);
      sm += __shfl_xor(sm, 8);
      float inv = 1.f / sm;
      int t = mt + quad*4 + r;
      bool tv = (t < 24);
      scb[t*40 + l15]      = tv ? f2bfb(e0 * inv) : (ushort_t)0;
      scb[t*40 + 16 + l15] = (tv && l15 < 8) ? f2bfb(e1 * inv) : (ushort_t)0;
    }
  }
  __syncthreads();

  // ---- phase 5: XD[c][t] = V P^T (swapped operands) + x1(regs) -> XDg ----
  {
    for (int i = tid; i < 640; i += 256) {
      int r = i >> 6, cg = i & 63;
      int row = (r == 0) ? 0 : (24 + r);
      XDg[row*SW + cg] = 0;
    }
    bf16x8 aV = *(const bf16x8*)&V2[(c0 + l15)*40 + quad*8];
    #pragma unroll
    for (int nt = 0; nt < 2; ++nt) {
      bf16x8 bP = *(const bf16x8*)&scb[(nt*16 + l15)*40 + quad*8];
      f32x4 z = {0.f,0.f,0.f,0.f};
      f32x4 acc = __builtin_amdgcn_mfma_f32_16x16x32_bf16(aV, bP, z, 0,0,0);
      int t = nt*16 + l15;
      if (t < 24) {
        #pragma unroll
        for (int r = 0; r < 4; ++r)
          XDg[(1 + t)*SW + c0 + quad*4 + r] = f2bfb(acc[r] + x1r[nt][r]);
      }
    }
  }
  __syncthreads();

  // ---- phase 6: x1c = conv_t(XD) -> bufD ----
  {
    float4 bc4 = *(const float4*)&b_c1[c0 + quad*4];
    float bc[4] = {bc4.x,bc4.y,bc4.z,bc4.w};
    f32x4 acc0 = {0.f,0.f,0.f,0.f}, acc1v = {0.f,0.f,0.f,0.f};
    #pragma unroll
    for (int d = 0; d < 3; ++d) {
      const ushort_t* Ad = WBF + WB_C1A + d*4096;
      bf16x8 a0 = *(const bf16x8*)(Ad + (c0+l15)*64 + quad*8);
      bf16x8 a1f = *(const bf16x8*)(Ad + (c0+l15)*64 + 32 + quad*8);
      {
        int rr = 0*16 + l15 + d;
        bf16x8 b0 = *(const bf16x8*)&XDg[rr*SW + quad*8];
        bf16x8 b1f = *(const bf16x8*)&XDg[rr*SW + 32 + quad*8];
        acc0 = __builtin_amdgcn_mfma_f32_16x16x32_bf16(a0, b0, acc0, 0,0,0);
        acc0 = __builtin_amdgcn_mfma_f32_16x16x32_bf16(a1f, b1f, acc0, 0,0,0);
      }
      {
        int rr = 1*16 + l15 + d;
        bf16x8 b0 = *(const bf16x8*)&XDg[rr*SW + quad*8];
        bf16x8 b1f = *(const bf16x8*)&XDg[rr*SW + 32 + quad*8];
        acc1v = __builtin_amdgcn_mfma_f32_16x16x32_bf16(a0, b0, acc1v, 0,0,0);
        acc1v = __builtin_amdgcn_mfma_f32_16x16x32_bf16(a1f, b1f, acc1v, 0,0,0);
      }
    }
    st4bf(&bufD[(0*16 + l15)*SW + c0 + quad*4],
          acc0[0]+bc[0], acc0[1]+bc[1], acc0[2]+bc[2], acc0[3]+bc[3]);
    st4bf(&bufD[(1*16 + l15)*SW + c0 + quad*4],
          acc1v[0]+bc[0], acc1v[1]+bc[1], acc1v[2]+bc[2], acc1v[3]+bc[3]);
  }
  __syncthreads();

  // ---- phase 7: Q_s (from x1c=bufD), K_s, V_s (from S) ----
  {
    bf16x8 aq0 = *(const bf16x8*)(WBF + WB_QS + (c0+l15)*64 + quad*8);
    bf16x8 aq1 = *(const bf16x8*)(WBF + WB_QS + (c0+l15)*64 + 32 + quad*8);
    bf16x8 ak0 = *(const bf16x8*)(WBF + WB_KS + (c0+l15)*64 + quad*8);
    bf16x8 ak1 = *(const bf16x8*)(WBF + WB_KS + (c0+l15)*64 + 32 + quad*8);
    bf16x8 av0 = *(const bf16x8*)(WBF + WB_VS + (c0+l15)*64 + quad*8);
    bf16x8 av1 = *(const bf16x8*)(WBF + WB_VS + (c0+l15)*64 + 32 + quad*8);
    float4 bq4 = *(const float4*)&bq_s[c0 + quad*4];
    float4 bk4 = *(const float4*)&bk_s[c0 + quad*4];
    float4 bv4 = *(const float4*)&bv_s[c0 + quad*4];
    float bq[4] = {bq4.x,bq4.y,bq4.z,bq4.w};
    float bk[4] = {bk4.x,bk4.y,bk4.z,bk4.w};
    float bv[4] = {bv4.x,bv4.y,bv4.z,bv4.w};
    #pragma unroll
    for (int nt = 0; nt < 2; ++nt) {
      int bt = nt*16 + l15;
      bf16x8 bx0 = *(const bf16x8*)&bufD[bt*SW + quad*8];
      bf16x8 bx1 = *(const bf16x8*)&bufD[bt*SW + 32 + quad*8];
      bf16x8 bs0 = *(const bf16x8*)&Sts[bt*SW + quad*8];
      bf16x8 bs1 = *(const bf16x8*)&Sts[bt*SW + 32 + quad*8];
      f32x4 accQ = {0.f,0.f,0.f,0.f}, accK = {0.f,0.f,0.f,0.f}, accV = {0.f,0.f,0.f,0.f};
      accQ = __builtin_amdgcn_mfma_f32_16x16x32_bf16(aq0, bx0, accQ, 0,0,0);
      accQ = __builtin_amdgcn_mfma_f32_16x16x32_bf16(aq1, bx1, accQ, 0,0,0);
      accK = __builtin_amdgcn_mfma_f32_16x16x32_bf16(ak0, bs0, accK, 0,0,0);
      accK = __builtin_amdgcn_mfma_f32_16x16x32_bf16(ak1, bs1, accK, 0,0,0);
      accV = __builtin_amdgcn_mfma_f32_16x16x32_bf16(av0, bs0, accV, 0,0,0);
      accV = __builtin_amdgcn_mfma_f32_16x16x32_bf16(av1, bs1, accV, 0,0,0);
      st4bf(&bufQ[bt*SW + c0 + quad*4],
            accQ[0]+bq[0], accQ[1]+bq[1], accQ[2]+bq[2], accQ[3]+bq[3]);
      st4bf(&bufK[bt*SW + c0 + quad*4],
            accK[0]+bk[0], accK[1]+bk[1], accK[2]+bk[2], accK[3]+bk[3]);
      if (bt < 24) {
        #pragma unroll
        for (int r = 0; r < 4; ++r)
          V2[(c0 + quad*4 + r)*40 + bt] = f2bfb(accV[r] + bv[r]);
      }
    }
  }
  __syncthreads();

  // ---- phase 8 + softmax 2 in-register (waves 0,1) -> scb (bufD region) ----
  if (wave < 2) {
    const int mt = wave * 16;
    bf16x8 a0 = *(const bf16x8*)&bufQ[(mt+l15)*SW + quad*8];
    bf16x8 a1f = *(const bf16x8*)&bufQ[(mt+l15)*SW + 32 + quad*8];
    bf16x8 k0a = *(const bf16x8*)&bufK[l15*SW + quad*8];
    bf16x8 k0b = *(const bf16x8*)&bufK[l15*SW + 32 + quad*8];
    bf16x8 k1a = *(const bf16x8*)&bufK[(16+l15)*SW + quad*8];
    bf16x8 k1b = *(const bf16x8*)&bufK[(16+l15)*SW + 32 + quad*8];
    f32x4 s0 = {0.f,0.f,0.f,0.f}, s1 = {0.f,0.f,0.f,0.f};
    s0 = __builtin_amdgcn_mfma_f32_16x16x32_bf16(a0, k0a, s0, 0,0,0);
    s0 = __builtin_amdgcn_mfma_f32_16x16x32_bf16(a1f, k0b, s0, 0,0,0);
    s1 = __builtin_amdgcn_mfma_f32_16x16x32_bf16(a0, k1a, s1, 0,0,0);
    s1 = __builtin_amdgcn_mfma_f32_16x16x32_bf16(a1f, k1b, s1, 0,0,0);
    #pragma unroll
    for (int r = 0; r < 4; ++r) {
      float v0 = 0.125f * s0[r];
      float v1 = (l15 < 8) ? 0.125f * s1[r] : -3.0e38f;
      float mx = fmaxf(v0, v1);
      mx = fmaxf(mx, __shfl_xor(mx, 1));
      mx = fmaxf(mx, __shfl_xor(mx, 2));
      mx = fmaxf(mx, __shfl_xor(mx, 4));
      mx = fmaxf(mx, __shfl_xor(mx, 8));
      float e0 = __expf(v0 - mx);
      float e1 = (l15 < 8) ? __expf(v1 - mx) : 0.f;
      float sm = e0 + e1;
      sm += __shfl_xor(sm, 1);
      sm += __shfl_xor(sm, 2);
      sm += __shfl_xor(sm, 4);
      sm += __shfl_xor(sm, 8);
      float inv = 1.f / sm;
      int t = mt + quad*4 + r;
      bool tv = (t < 24);
      scb[t*40 + l15]      = tv ? f2bfb(e0 * inv) : (ushort_t)0;
      scb[t*40 + 16 + l15] = (tv && l15 < 8) ? f2bfb(e1 * inv) : (ushort_t)0;
    }
  }
  __syncthreads();

  // ---- phase 9: XS = A_s @ V_s -> global [n][b][c][t] ----
  {
    int nc = wave * 16;
    bf16x8 bv0 = *(const bf16x8*)&V2[(nc + l15)*40 + quad*8];
    #pragma unroll
    for (int mt = 0; mt < 2; ++mt) {
      bf16x8 af = *(const bf16x8*)&scb[(mt*16 + l15)*40 + quad*8];
      f32x4 z = {0.f,0.f,0.f,0.f};
      f32x4 acc = __builtin_amdgcn_mfma_f32_16x16x32_bf16(af, bv0, z, 0,0,0);
      int ccol = nc + l15;
      int t0 = mt*16 + quad*4;
      if (t0 < 24) {
        uint2 w;
        w.x = rne2(acc[0], acc[1]);
        w.y = rne2(acc[2], acc[3]);
        *(uint2*)(XS + (size_t)n*XS_COLS + (size_t)b*COUT_*T_ + ccol*T_ + t0) = w;
      }
    }
  }
}

// ---------------------------------------------------------------------------
// k_final R6: Chebyshev-gate GEMM on MFMA; x_input1 now ALSO on MFMA
// (W_1 bf16 from WBF; acc layout [c=quad*4+r][t=l15] matches accF register-
// for-register -> residual add is a register add; x1sh/xts/2nd barrier gone;
// LDS 22016 -> 15424 B).
// ---------------------------------------------------------------------------
#define ZW 200
__global__ __launch_bounds__(256) void k_final(
    const float* __restrict__ x,
    const ushort_t* __restrict__ XS, const ushort_t* __restrict__ Y1h,
    const ushort_t* __restrict__ Y2h,
    const ushort_t* __restrict__ WGBF, const ushort_t* __restrict__ WBF,
    const float* __restrict__ b_1, const float* __restrict__ b_g,
    int h, float* __restrict__ out)
{
  const int n = blockIdx.x, bb = blockIdx.y, tid = threadIdx.x;
  const int b = h * 8 + bb;
  const int wave = tid >> 6, lane = tid & 63;
  const int l15 = lane & 15, quad = lane >> 4;

  __shared__ __align__(16) ushort_t Zt[32*ZW];   // 12800 B
  __shared__ __align__(16) ushort_t xb[32*40];   // 2560 B, [t][ci] bf16 x-tile

  size_t baseg = (size_t)n * XS_COLS + (size_t)b * COUT_ * T_;
  size_t baseh = (size_t)n * HALF_COLS + (size_t)bb * COUT_ * T_;

  for (int i = tid; i < 8*ZW; i += 256) Zt[24*ZW + i] = 0;
  for (int i = tid; i < COUT_*T_; i += 256) {
    int c = i / T_, t = i - c*T_;
    ushort_t* zr = &Zt[t*ZW + 3*c];
    zr[0] = XS [baseg + i];
    zr[1] = Y1h[baseh + i];
    zr[2] = Y2h[baseh + i];
  }
  for (int i = tid; i < CIN_*T_; i += 256) {
    int ci = i / T_, t = i - ci*T_;
    xb[t*40 + ci] = f2bfb(x[(((size_t)b * CIN_ + ci) * N_ + n) * T_ + t]);
  }
  // rows t=24..31 of xb left stale: B-row t only affects outputs with that t,
  // and all t>=24 outputs are guarded off (same argument as k_attn pools).
  __syncthreads();

  f32x4 accF[2] = {{0.f,0.f,0.f,0.f},{0.f,0.f,0.f,0.f}};
  f32x4 accG[2] = {{0.f,0.f,0.f,0.f},{0.f,0.f,0.f,0.f}};
  f32x4 accX[2] = {{0.f,0.f,0.f,0.f},{0.f,0.f,0.f,0.f}};
  const ushort_t* WF = WGBF + (size_t)(wave*16 + l15)*192 + quad*8;
  const ushort_t* WG = WF + 64*192;
  bf16x8 aW1 = *(const bf16x8*)(WBF + WB_1 + (wave*16 + l15)*32 + quad*8);
  #pragma unroll
  for (int nt = 0; nt < 2; ++nt) {
    bf16x8 bx = *(const bf16x8*)&xb[(nt*16 + l15)*40 + quad*8];
    accX[nt] = __builtin_amdgcn_mfma_f32_16x16x32_bf16(aW1, bx, accX[nt], 0,0,0);
  }
  #pragma unroll
  for (int ks = 0; ks < 6; ++ks) {
    bf16x8 wf = *(const bf16x8*)(WF + ks*32);
    bf16x8 wg = *(const bf16x8*)(WG + ks*32);
    #pragma unroll
    for (int nt = 0; nt < 2; ++nt) {
      bf16x8 bz = *(const bf16x8*)&Zt[(nt*16 + l15)*ZW + ks*32 + quad*8];
      accF[nt] = __builtin_amdgcn_mfma_f32_16x16x32_bf16(wf, bz, accF[nt], 0,0,0);
      accG[nt] = __builtin_amdgcn_mfma_f32_16x16x32_bf16(wg, bz, accG[nt], 0,0,0);
    }
  }

  {
    float4 bgF4 = *(const float4*)&b_g[wave*16 + quad*4];
    float4 bgG4 = *(const float4*)&b_g[64 + wave*16 + quad*4];
    float4 b14  = *(const float4*)&b_1[wave*16 + quad*4];
    float bgF[4] = {bgF4.x, bgF4.y, bgF4.z, bgF4.w};
    float bgG[4] = {bgG4.x, bgG4.y, bgG4.z, bgG4.w};
    float b1a[4] = {b14.x, b14.y, b14.z, b14.w};
    #pragma unroll
    for (int nt = 0; nt < 2; ++nt) {
      int t = nt*16 + l15;
      if (t < 24) {
        #pragma unroll
        for (int r = 0; r < 4; ++r) {
          int c = wave*16 + quad*4 + r;
          float fv = accF[nt][r] + bgF[r] + accX[nt][r] + b1a[r];
          float gv = accG[nt][r] + bgG[r];
          out[(((size_t)b * COUT_ + c) * N_ + n) * T_ + t] = fv * sigm_(gv);
        }
      }
    }
  }
}

// ---------------------------------------------------------------------------
extern "C" void kernel_launch(void* const* d_in, const int* in_sizes, int n_in,
                              void* d_out, int out_size, void* d_ws, size_t ws_size,
                              hipStream_t stream) {
  const float* x        = (const float*)d_in[0];
  const float* supports = (const float*)d_in[1];
  const float* CD       = (const float*)d_in[2];
  const float* CS       = (const float*)d_in[3];
  const float* adj      = (const float*)d_in[4];
  const float* W_de  = (const float*)d_in[5];  const float* b_de  = (const float*)d_in[6];
  const float* Wd    = (const float*)d_in[7];
  const float* W_pro = (const float*)d_in[8];  const float* b_pro = (const float*)d_in[9];
  const float* W_mii = (const float*)d_in[10]; const float* b_mii = (const float*)d_in[11];
  const float* W_1   = (const float*)d_in[12]; const float* b_1   = (const float*)d_in[13];
  const float* Wq_t  = (const float*)d_in[14]; const float* bq_t  = (const float*)d_in[15];
  const float* Wk_t  = (const float*)d_in[16]; const float* bk_t  = (const float*)d_in[17];
  const float* Wv_t  = (const float*)d_in[18]; const float* bv_t  = (const float*)d_in[19];
  const float* W_c1  = (const float*)d_in[20]; const float* b_c1  = (const float*)d_in[21];
  const float* Wq_s  = (const float*)d_in[22]; const float* bq_s  = (const float*)d_in[23];
  const float* Wk_s  = (const float*)d_in[24]; const float* bk_s  = (const float*)d_in[25];
  const float* Wv_s  = (const float*)d_in[26]; const float* bv_s  = (const float*)d_in[27];
  const float* W_g   = (const float*)d_in[28]; const float* b_g   = (const float*)d_in[29];
  float* out = (float*)d_out;

  char* ws = (char*)d_ws;
  float*    delay = (float*)(ws + OFF_DELAY);
  float*    Mbuf  = (float*)(ws + OFF_M);
  float*    Rbuf  = (float*)(ws + OFF_R);
  float*    u     = (float*)(ws + OFF_U);
  float*    W1T   = (float*)(ws + OFF_W1T);
  ushort_t* WGBF  = (ushort_t*)(ws + OFF_WGBF);
  ushort_t* Sbf   = (ushort_t*)(ws + OFF_SBF);
  ushort_t* adjbf = (ushort_t*)(ws + OFF_ADJBF);
  ushort_t* STbf  = (ushort_t*)(ws + OFF_STBF);
  ushort_t* L2bf  = (ushort_t*)(ws + OFF_L2BF);
  ushort_t* Ue    = (ushort_t*)(ws + OFF_X1);
  ushort_t* P     = (ushort_t*)(ws + OFF_X1);   // overwrites Ue (dead)
  ushort_t* UeT   = (ushort_t*)(ws + OFF_X2);
  ushort_t* XST   = (ushort_t*)(ws + OFF_X2);   // overwrites UeT (dead)
  ushort_t* XS    = (ushort_t*)(ws + OFF_XS);
  ushort_t* Y1h   = (ushort_t*)(ws + OFF_Y1H);
  ushort_t* Y2h   = (ushort_t*)(ws + OFF_Y2H);
  ushort_t* WBF   = (ushort_t*)(ws + OFF_WBF);

  (void)in_sizes; (void)n_in; (void)out_size; (void)ws_size;

  // 1) conversions + weight prep
  k_prep<<<dim3((PREP_TOTAL + 255)/256), 256, 0, stream>>>(
      supports, adj, W_de, Wq_t, W_1, W_mii, Wk_t, Wv_t, Wq_s, Wk_s, Wv_s,
      W_c1, W_g, Sbf, adjbf, W1T, WGBF, WBF);
  // 2) delay / Mbuf / Rbuf
  k_pre<<<dim3((NT_ + N_*COUT_ + 8*N_ + 255)/256), 256, 0, stream>>>(
      CD, Wd, CS, W_mii, adj, delay, Mbuf, Rbuf);
  // 3) S^T via coalesced transpose
  k_tr<<<dim3(N_/32, N_/32), 256, 0, stream>>>(Sbf, STbf, N_, N_);
  // 4) L2 = 2*S@S - I
  k_mmx<2><<<dim3(8, 8), 256, 0, stream>>>(Sbf, STbf, L2bf, 1024);
  // 5) u + Ue
  k_u<<<dim3((BNT_ + 255)/256), 256, 0, stream>>>(x, W_pro, b_pro, CS, u, Ue);
  // 6) UeT
  k_tr<<<dim3(UE_COLS/32, N_/32), 256, 0, stream>>>(Ue, UeT, N_, UE_COLS);
  // 7) P = adj @ Ue
  k_mmx<0><<<dim3(UE_COLS/128, N_/128), 256, 0, stream>>>(adjbf, UeT, P, UE_COLS);
  // 8) MFMA attention pipeline -> XS
  k_attn_mfma<<<dim3(N_, B_), 256, 0, stream>>>(
      x, delay, Mbuf, Rbuf, u, P, WBF,
      b_de, bq_t, b_1, b_mii, bk_t, bv_t, bq_s, bk_s, bv_s, b_c1, XS);
  // 9) per half: transpose, fused Y1/Y2 GEMM, final
  for (int h = 0; h < 2; ++h) {
    k_tr<<<dim3(HALF_COLS/32, N_/32), 256, 0, stream>>>(
        XS + (size_t)h * HALF_COLS, XST, N_, XS_COLS);
    k_mmy<<<dim3(HALF_COLS/128, 16), 256, 0, stream>>>(
        Sbf, L2bf, XST, Y1h, Y2h, HALF_COLS);
    k_final<<<dim3(N_, 8), 256, 0, stream>>>(
        x, XS, Y1h, Y2h, WGBF, WBF, b_1, b_g, h, out);
  }
}

// Round 8
// 712.570 us; speedup vs baseline: 1.0903x; 1.0086x over previous
//
#include <hip/hip_runtime.h>
#include <cstdint>
#include <cstddef>

#define B_    16
#define CIN_  32
#define COUT_ 64
#define N_    1024
#define T_    24
#define SD_   16
#define DD_   16

#define NT_      (N_*T_)          // 24576
#define BNT_     (B_*N_*T_)       // 393216
#define UE_COLS  (B_*T_*SD_)      // 6144
#define XS_COLS  (B_*COUT_*T_)    // 24576
#define HALF_COLS (XS_COLS/2)     // 12288

typedef unsigned short ushort_t;
using bf16x8 = __attribute__((ext_vector_type(8))) short;
using f32x4  = __attribute__((ext_vector_type(4))) float;

// ---- workspace byte offsets ----
#define OFF_DELAY 0ul
#define OFF_M     98304ul
#define OFF_R     360448ul
#define OFF_U     364544ul
#define OFF_W1T   1953792ul
#define OFF_WGBF  2048000ul              // bf16 W_g copy (24576 elems = 49152 B)
#define OFF_SBF   2195456ul
#define OFF_ADJBF 4292608ul
#define OFF_STBF  6389760ul
#define OFF_L2BF  8486912ul
#define OFF_X1    10584064ul             // Ue then P (bf16 1024*6144)
#define OFF_X2    23166976ul             // xbf (25165824 B exactly) then XST_h
#define OFF_XS    48332800ul             // bf16 1024*24576
#define OFF_Y1H   98664448ul             // UeT (step 6-7), then Y1h (step 9)
#define OFF_Y2H   123830272ul            // bf16 1024*12288
#define OFF_WBF   148996096ul            // bf16 weights, 40960 elems = 81920 B

// bf16 weight sub-offsets (element index within WBF)
#define WB_DE   0
#define WB_QT   2048
#define WB_1    4096
#define WB_MIIA 6144
#define WB_KT   8192
#define WB_VT   12288
#define WB_QS   16384
#define WB_KS   20480
#define WB_VS   24576
#define WB_C1A  28672   // [3][64][64]
#define WB_TOTAL 40960

__device__ __forceinline__ float bfb2f(ushort_t h) {
  union { unsigned u; float f; } v; v.u = ((unsigned)h) << 16; return v.f;
}
// software round-to-nearest-even f32->bf16 (R4's HW v_cvt_pk_bf16_f32 asm
// FAILED numerics — biased rounding accumulated to 3x threshold; keep RNE)
__device__ __forceinline__ ushort_t f2bfb(float f) {
  union { float f; unsigned u; } v; v.f = f;
  unsigned u = v.u;
  return (ushort_t)((u + 0x7fffu + ((u >> 16) & 1u)) >> 16);
}
// RNE pack of two f32 into one u32 (lo = low 16 bits), bit-identical to
// f2bfb pair, fewer VALU ops.
__device__ __forceinline__ unsigned rne2(float lo, float hi) {
  union { float f; unsigned u; } a, b;
  a.f = lo; b.f = hi;
  unsigned ua = (a.u + 0x7fffu + ((a.u >> 16) & 1u)) >> 16;
  unsigned ub = (b.u + 0x7fffu + ((b.u >> 16) & 1u)) & 0xffff0000u;
  return ua | ub;
}
__device__ __forceinline__ float sigm_(float z) { return 1.f / (1.f + __expf(-z)); }

__device__ __forceinline__ void gl_lds16(const ushort_t* g, ushort_t* l) {
  __builtin_amdgcn_global_load_lds(
      (const __attribute__((address_space(1))) unsigned int*)g,
      (__attribute__((address_space(3))) unsigned int*)l, 16, 0, 0);
}

__device__ __forceinline__ void st4bf(ushort_t* p, float v0, float v1, float v2, float v3) {
  uint2 w;
  w.x = rne2(v0, v1);
  w.y = rne2(v2, v3);
  *(uint2*)p = w;
}

// ---------------------------------------------------------------------------
// k_prep: bf16 supports/adj, bf16 W_g copy, bf16 row-major weight copies.
// ---------------------------------------------------------------------------
__global__ __launch_bounds__(256) void k_prep(
    const float* __restrict__ supports, const float* __restrict__ adj,
    const float* __restrict__ W_de, const float* __restrict__ Wq_t,
    const float* __restrict__ W_1, const float* __restrict__ W_mii,
    const float* __restrict__ Wk_t, const float* __restrict__ Wv_t,
    const float* __restrict__ Wq_s, const float* __restrict__ Wk_s,
    const float* __restrict__ Wv_s, const float* __restrict__ W_c1,
    const float* __restrict__ W_g,
    ushort_t* __restrict__ Sbf, ushort_t* __restrict__ adjbf,
    float* __restrict__ W1T, ushort_t* __restrict__ WGBF,
    ushort_t* __restrict__ WBF)
{
  int idx = blockIdx.x * 256 + threadIdx.x;
  if (idx < N_*N_) {
    Sbf[idx]   = f2bfb(supports[idx]);
    adjbf[idx] = f2bfb(adj[idx]);
  }
  int j = idx - N_*N_;
  if (j < 0) return;
  if (j < 2048) { int k = j>>6, c = j&63; W1T[j] = W_1[c*32 + k]; return; }
  j -= 2048;
  if (j < 24576) { WGBF[j] = f2bfb(W_g[j]); return; }
  j -= 24576;
  if (j < 2048) { WBF[WB_DE + j] = f2bfb(W_de[j]); return; }
  j -= 2048;
  if (j < 2048) { WBF[WB_QT + j] = f2bfb(Wq_t[j]); return; }
  j -= 2048;
  if (j < 2048) { WBF[WB_1 + j] = f2bfb(W_1[j]); return; }
  j -= 2048;
  if (j < 2048) { int c = j>>5, k = j&31;
                  WBF[WB_MIIA + j] = (k < 16) ? f2bfb(W_mii[c*16 + k]) : (ushort_t)0; return; }
  j -= 2048;
  if (j < 4096) { WBF[WB_KT + j] = f2bfb(Wk_t[j]); return; }
  j -= 4096;
  if (j < 4096) { WBF[WB_VT + j] = f2bfb(Wv_t[j]); return; }
  j -= 4096;
  if (j < 4096) { WBF[WB_QS + j] = f2bfb(Wq_s[j]); return; }
  j -= 4096;
  if (j < 4096) { WBF[WB_KS + j] = f2bfb(Wk_s[j]); return; }
  j -= 4096;
  if (j < 4096) { WBF[WB_VS + j] = f2bfb(Wv_s[j]); return; }
  j -= 4096;
  if (j < 12288) { int d = j >> 12, r = j & 4095, c = r >> 6, jj = r & 63;
                   WBF[WB_C1A + j] = f2bfb(W_c1[(c*64 + jj)*3 + d]); return; }
}
#define PREP_TOTAL (N_*N_ + 2048 + 24576 + WB_TOTAL)

// ---------------------------------------------------------------------------
// k_pre: delay, Mbuf, Rbuf
// ---------------------------------------------------------------------------
__global__ __launch_bounds__(256) void k_pre(
    const float* __restrict__ CD, const float* __restrict__ Wd,
    const float* __restrict__ CS, const float* __restrict__ W_mii,
    const float* __restrict__ adj,
    float* __restrict__ delay, float* __restrict__ Mbuf, float* __restrict__ Rbuf)
{
  int idx = blockIdx.x * 256 + threadIdx.x;
  if (idx < NT_) {
    int n = idx / T_, t = idx % T_;
    float z = 0.f;
    #pragma unroll
    for (int d = 0; d < DD_; ++d) z += CD[n*DD_ + d] * Wd[d*T_ + t];
    delay[idx] = sigm_(tanhf(z));
  }
  int i2 = idx - NT_;
  if (i2 >= 0 && i2 < N_*COUT_) {
    int n = i2 / COUT_, c = i2 % COUT_;
    float z = 0.f;
    #pragma unroll
    for (int e = 0; e < SD_; ++e) z += CS[n*SD_ + e] * W_mii[c*SD_ + e];
    Mbuf[i2] = z;
  }
  int i3 = idx - NT_ - N_*COUT_;
  if (i3 >= 0 && i3 < 8*N_) {
    int n = i3 >> 3, jl = i3 & 7;
    const float* row = adj + (size_t)n * N_;
    float s = 0.f;
    for (int m = jl; m < N_; m += 8) s += row[m];
    s += __shfl_xor(s, 1);
    s += __shfl_xor(s, 2);
    s += __shfl_xor(s, 4);
    if (jl == 0) Rbuf[n] = s;
  }
}

// ---------------------------------------------------------------------------
// k_u: u + Ue + xbf (bf16 transposed x copy: row (b*N+n)*T+t, 32 channels)
// ---------------------------------------------------------------------------
__global__ __launch_bounds__(256) void k_u(
    const float* __restrict__ x, const float* __restrict__ W_pro,
    const float* __restrict__ b_pro, const float* __restrict__ CS,
    float* __restrict__ u, ushort_t* __restrict__ Ue,
    ushort_t* __restrict__ xbf)
{
  int idx = blockIdx.x * 256 + threadIdx.x;
  if (idx >= BNT_) return;
  int t = idx % T_;
  int n = (idx / T_) % N_;
  int b = idx / (T_ * N_);
  const float* xp = x + ((size_t)b * CIN_ * N_ + n) * T_ + t;
  float xv[CIN_];
  float z = b_pro[0];
  #pragma unroll
  for (int i = 0; i < CIN_; ++i) { xv[i] = xp[(size_t)i * NT_]; z += W_pro[i] * xv[i]; }
  u[idx] = z;
  ushort_t* up = Ue + (size_t)n * UE_COLS + (b * T_ + t) * SD_;
  unsigned w[8];
  #pragma unroll
  for (int e = 0; e < 8; ++e)
    w[e] = rne2(z * CS[n*SD_ + 2*e], z * CS[n*SD_ + 2*e + 1]);
  ((uint4*)up)[0] = make_uint4(w[0], w[1], w[2], w[3]);
  ((uint4*)up)[1] = make_uint4(w[4], w[5], w[6], w[7]);
  ushort_t* xr = xbf + (size_t)idx * 32;
  unsigned q[16];
  #pragma unroll
  for (int e = 0; e < 16; ++e)
    q[e] = rne2(xv[2*e], xv[2*e + 1]);
  ((uint4*)xr)[0] = make_uint4(q[0],  q[1],  q[2],  q[3]);
  ((uint4*)xr)[1] = make_uint4(q[4],  q[5],  q[6],  q[7]);
  ((uint4*)xr)[2] = make_uint4(q[8],  q[9],  q[10], q[11]);
  ((uint4*)xr)[3] = make_uint4(q[12], q[13], q[14], q[15]);
}

// ---------------------------------------------------------------------------
// k_tr: bf16 transpose dst[c*R + r] = src[r*sstride + c]
// ---------------------------------------------------------------------------
__global__ __launch_bounds__(256) void k_tr(
    const ushort_t* __restrict__ src, ushort_t* __restrict__ dst,
    int R, int sstride)
{
  __shared__ ushort_t tb[32][33];
  const int tid = threadIdx.x;
  const int tx = tid & 31, ty = tid >> 5;
  const int c0 = blockIdx.x * 32, r0 = blockIdx.y * 32;
  #pragma unroll
  for (int p = 0; p < 4; ++p) {
    int r = r0 + ty + p*8;
    tb[ty + p*8][tx] = src[(size_t)r * sstride + c0 + tx];
  }
  __syncthreads();
  #pragma unroll
  for (int p = 0; p < 4; ++p) {
    int c = c0 + ty + p*8;
    dst[(size_t)c * R + r0 + tx] = tb[tx][ty + p*8];
  }
}

// ---------------------------------------------------------------------------
// k_mmx: MFMA GEMM
// ---------------------------------------------------------------------------
template<int MODE>
__global__ __launch_bounds__(256) void k_mmx(
    const ushort_t* __restrict__ Abf, const ushort_t* __restrict__ BT,
    ushort_t* __restrict__ Cc, int ncols)
{
  __shared__ ushort_t As[128*64];
  __shared__ ushort_t Bs[128*64];
  const int tid  = threadIdx.x;
  const int wave = tid >> 6, lane = tid & 63;
  const int row0 = blockIdx.y * 128;
  const int col0 = blockIdx.x * 128;
  const int wm = (wave >> 1) * 64, wn = (wave & 1) * 64;
  const int l15 = lane & 15, quad = lane >> 4, l7 = lane & 7;

  f32x4 acc[4][4];
  #pragma unroll
  for (int i = 0; i < 4; ++i)
    #pragma unroll
    for (int j = 0; j < 4; ++j) acc[i][j] = (f32x4){0.f,0.f,0.f,0.f};

  for (int kb = 0; kb < 1024; kb += 64) {
    #pragma unroll
    for (int p = 0; p < 4; ++p) {
      int chunk = p*256 + tid;
      int r = chunk >> 3, pc = chunk & 7;
      int kc = pc ^ (r & 7);
      gl_lds16(Abf + (size_t)(row0 + r)*1024 + (kb + kc*8), &As[chunk*8]);
    }
    #pragma unroll
    for (int p = 0; p < 4; ++p) {
      int chunk = p*256 + tid;
      int r = chunk >> 3, pc = chunk & 7;
      int kc = pc ^ (r & 7);
      gl_lds16(BT + (size_t)(col0 + r)*1024 + (kb + kc*8), &Bs[chunk*8]);
    }
    __syncthreads();
    #pragma unroll
    for (int kh = 0; kh < 2; ++kh) {
      const int kcb = kh * 4;
      bf16x8 af[4], bfr[4];
      #pragma unroll
      for (int mi = 0; mi < 4; ++mi)
        af[mi] = *(const bf16x8*)&As[(wm + mi*16 + l15)*64 + (((kcb + quad) ^ l7) << 3)];
      #pragma unroll
      for (int ni = 0; ni < 4; ++ni)
        bfr[ni] = *(const bf16x8*)&Bs[(wn + ni*16 + l15)*64 + (((kcb + quad) ^ l7) << 3)];
      #pragma unroll
      for (int mi = 0; mi < 4; ++mi)
        #pragma unroll
        for (int ni = 0; ni < 4; ++ni)
          acc[mi][ni] = __builtin_amdgcn_mfma_f32_16x16x32_bf16(
              af[mi], bfr[ni], acc[mi][ni], 0, 0, 0);
    }
    __syncthreads();
  }

  #pragma unroll
  for (int mi = 0; mi < 4; ++mi) {
    int grow_b = row0 + wm + mi*16 + quad*4;
    #pragma unroll
    for (int ni = 0; ni < 4; ++ni) {
      int gcol = col0 + wn + ni*16 + l15;
      #pragma unroll
      for (int j = 0; j < 4; ++j) {
        float v = acc[mi][ni][j];
        int grow = grow_b + j;
        if (MODE == 2) v = 2.f*v - ((grow == gcol) ? 1.f : 0.f);
        Cc[(size_t)grow * ncols + gcol] = f2bfb(v);
      }
    }
  }
}

// ---------------------------------------------------------------------------
// k_mmy: fused Y1=S@XST, Y2=L2@XST in one launch (by<8 -> Y1, else Y2).
// ---------------------------------------------------------------------------
__global__ __launch_bounds__(256) void k_mmy(
    const ushort_t* __restrict__ Sbf, const ushort_t* __restrict__ L2bf,
    const ushort_t* __restrict__ BT,
    ushort_t* __restrict__ Y1, ushort_t* __restrict__ Y2, int ncols)
{
  __shared__ ushort_t As[128*64];
  __shared__ ushort_t Bs[128*64];
  const int tid  = threadIdx.x;
  const int wave = tid >> 6, lane = tid & 63;
  const bool isY2 = blockIdx.y >= 8;
  const ushort_t* Abf = isY2 ? L2bf : Sbf;
  ushort_t* Cc = isY2 ? Y2 : Y1;
  const int row0 = (blockIdx.y & 7) * 128;
  const int col0 = blockIdx.x * 128;
  const int wm = (wave >> 1) * 64, wn = (wave & 1) * 64;
  const int l15 = lane & 15, quad = lane >> 4, l7 = lane & 7;

  f32x4 acc[4][4];
  #pragma unroll
  for (int i = 0; i < 4; ++i)
    #pragma unroll
    for (int j = 0; j < 4; ++j) acc[i][j] = (f32x4){0.f,0.f,0.f,0.f};

  for (int kb = 0; kb < 1024; kb += 64) {
    #pragma unroll
    for (int p = 0; p < 4; ++p) {
      int chunk = p*256 + tid;
      int r = chunk >> 3, pc = chunk & 7;
      int kc = pc ^ (r & 7);
      gl_lds16(Abf + (size_t)(row0 + r)*1024 + (kb + kc*8), &As[chunk*8]);
    }
    #pragma unroll
    for (int p = 0; p < 4; ++p) {
      int chunk = p*256 + tid;
      int r = chunk >> 3, pc = chunk & 7;
      int kc = pc ^ (r & 7);
      gl_lds16(BT + (size_t)(col0 + r)*1024 + (kb + kc*8), &Bs[chunk*8]);
    }
    __syncthreads();
    #pragma unroll
    for (int kh = 0; kh < 2; ++kh) {
      const int kcb = kh * 4;
      bf16x8 af[4], bfr[4];
      #pragma unroll
      for (int mi = 0; mi < 4; ++mi)
        af[mi] = *(const bf16x8*)&As[(wm + mi*16 + l15)*64 + (((kcb + quad) ^ l7) << 3)];
      #pragma unroll
      for (int ni = 0; ni < 4; ++ni)
        bfr[ni] = *(const bf16x8*)&Bs[(wn + ni*16 + l15)*64 + (((kcb + quad) ^ l7) << 3)];
      #pragma unroll
      for (int mi = 0; mi < 4; ++mi)
        #pragma unroll
        for (int ni = 0; ni < 4; ++ni)
          acc[mi][ni] = __builtin_amdgcn_mfma_f32_16x16x32_bf16(
              af[mi], bfr[ni], acc[mi][ni], 0, 0, 0);
    }
    __syncthreads();
  }

  #pragma unroll
  for (int mi = 0; mi < 4; ++mi) {
    int grow_b = row0 + wm + mi*16 + quad*4;
    #pragma unroll
    for (int ni = 0; ni < 4; ++ni) {
      int gcol = col0 + wn + ni*16 + l15;
      #pragma unroll
      for (int j = 0; j < 4; ++j)
        Cc[(size_t)(grow_b + j) * ncols + gcol] = f2bfb(acc[mi][ni][j]);
    }
  }
}

// ---------------------------------------------------------------------------
// k_attn_mfma R8: R7 staging fixed for gl_lds16 wave-uniform-base semantics
// (m104): every gl_lds16 call's active lanes must be contiguous FROM LANE 0
// (write lands at base + lane_id*16). R7 split wave 1 mid-wave -> Pts
// written at +512B offset -> garbage/NaN. New assignment:
//   wave 0            : Bc chunks 0-63
//   wave 1 lanes 0-31 : Bc chunks 64-95      | lanes 32-63: urow
//   wave 2 lanes 0-47 : Pts chunks 0-47      | lanes 48-63: delay_s (2 each)
//   wave 3            : Mrow
// ---------------------------------------------------------------------------
#define SW 72
__global__ __launch_bounds__(256, 6) void k_attn_mfma(
    const ushort_t* __restrict__ xbf,
    const float* __restrict__ delay, const float* __restrict__ Mbuf,
    const float* __restrict__ Rbuf, const float* __restrict__ u,
    const ushort_t* __restrict__ P,
    const ushort_t* __restrict__ WBF,
    const float* __restrict__ b_de, const float* __restrict__ bq_t,
    const float* __restrict__ b_1,  const float* __restrict__ b_mii,
    const float* __restrict__ bk_t, const float* __restrict__ bv_t,
    const float* __restrict__ bq_s, const float* __restrict__ bk_s,
    const float* __restrict__ bv_s, const float* __restrict__ b_c1,
    ushort_t* __restrict__ XS)
{
  const int n = blockIdx.x, b = blockIdx.y;
  const int tid = threadIdx.x, wave = tid >> 6, lane = tid & 63;
  const int l15 = lane & 15, quad = lane >> 4;

  __shared__ __align__(16) char smem[24352];
  ushort_t* bufQ = (ushort_t*)(smem + 0);       // pool A: Qt[2-4], Qs[7-8]
  ushort_t* XDg  = (ushort_t*)(smem + 0);       //   alias: XDg[5-6] (34 rows)
  ushort_t* Bc   = (ushort_t*)(smem + 4896);    // pool B: x [stage-2] stride 32
  ushort_t* bufK = (ushort_t*)(smem + 4896);    //   alias: Kt[3-4], Ks[7-8]
  ushort_t* bufD = (ushort_t*)(smem + 9504);    // D[2-3], x1c[6-7]
  ushort_t* scb  = (ushort_t*)(smem + 9504);    //   alias: P bf16 [4-5],[8-9]
  ushort_t* Sts  = (ushort_t*)(smem + 14112);   // S [2-7]
  ushort_t* V2   = (ushort_t*)(smem + 18720);   // V [c][s] [3-5],[7-9]
  ushort_t* Pts  = (ushort_t*)(smem + 18720);   //   alias: P staging, stride 16
  float* delay_s = (float*)(smem + 23840);
  float* urow    = (float*)(smem + 23968);
  float* Mrow    = (float*)(smem + 24096);

  // ---- staging (gl_lds16, wave-aligned; zero VALU conversion) ----
  {
    const ushort_t* xsrc = xbf + (size_t)((b * N_ + n)) * T_ * 32;     // 768 ushorts
    const ushort_t* psrc = P + (size_t)n * UE_COLS + (size_t)b * T_ * SD_; // 384 ushorts
    if (wave == 0) {
      gl_lds16(xsrc + lane * 8, &Bc[lane * 8]);
    } else if (wave == 1) {
      if (lane < 32) gl_lds16(xsrc + (64 + lane) * 8, &Bc[(64 + lane) * 8]);
      else { int t = lane - 32; urow[t] = (t < 24) ? u[((size_t)b*N_ + n)*T_ + t] : 0.f; }
    } else if (wave == 2) {
      if (lane < 48) gl_lds16(psrc + lane * 8, &Pts[lane * 8]);
      else { int t0 = (lane - 48) * 2;
             delay_s[t0]     = (t0     < 24) ? delay[n*T_ + t0]     : 0.f;
             delay_s[t0 + 1] = (t0 + 1 < 24) ? delay[n*T_ + t0 + 1] : 0.f; }
    } else {
      Mrow[lane] = Mbuf[n*COUT_ + lane];
    }
  }
  __syncthreads();

  const int c0 = wave * 16;
  const float Rn = Rbuf[n];
  float x1r[2][4];   // x_input1 registers, p2 -> p5

  // ---- phase 2: D, Q_t, x_input1(regs), S ----
  {
    bf16x8 aD = *(const bf16x8*)(WBF + WB_DE   + (c0+l15)*32 + quad*8);
    bf16x8 aQ = *(const bf16x8*)(WBF + WB_QT   + (c0+l15)*32 + quad*8);
    bf16x8 a1w = *(const bf16x8*)(WBF + WB_1   + (c0+l15)*32 + quad*8);
    bf16x8 aS = *(const bf16x8*)(WBF + WB_MIIA + (c0+l15)*32 + quad*8);
    float4 bD4 = *(const float4*)&b_de [c0 + quad*4];
    float4 bQ4 = *(const float4*)&bq_t [c0 + quad*4];
    float4 b14 = *(const float4*)&b_1  [c0 + quad*4];
    float4 bS4 = *(const float4*)&b_mii[c0 + quad*4];
    float4 Mv4 = *(const float4*)&Mrow [c0 + quad*4];
    float bD[4] = {bD4.x,bD4.y,bD4.z,bD4.w};
    float bQ[4] = {bQ4.x,bQ4.y,bQ4.z,bQ4.w};
    float b1a[4] = {b14.x,b14.y,b14.z,b14.w};
    float bS[4] = {bS4.x,bS4.y,bS4.z,bS4.w};
    float Mv[4] = {Mv4.x,Mv4.y,Mv4.z,Mv4.w};
    #pragma unroll
    for (int nt = 0; nt < 2; ++nt) {
      int bt = nt*16 + l15;
      bf16x8 bx = *(const bf16x8*)&Bc[bt*32 + quad*8];
      bf16x8 bp = (bf16x8){0,0,0,0,0,0,0,0};
      if (quad < 2) bp = *(const bf16x8*)&Pts[bt*16 + quad*8];
      f32x4 z = {0.f,0.f,0.f,0.f};
      f32x4 accD = __builtin_amdgcn_mfma_f32_16x16x32_bf16(aD, bx, z, 0,0,0);
      f32x4 accQ = __builtin_amdgcn_mfma_f32_16x16x32_bf16(aQ, bx, z, 0,0,0);
      f32x4 acc1 = __builtin_amdgcn_mfma_f32_16x16x32_bf16(a1w, bx, z, 0,0,0);
      f32x4 accS = __builtin_amdgcn_mfma_f32_16x16x32_bf16(aS, bp, z, 0,0,0);
      float dl = delay_s[bt], ut = urow[bt];
      st4bf(&bufD[bt*SW + c0 + quad*4],
            (accD[0]+bD[0])*dl, (accD[1]+bD[1])*dl, (accD[2]+bD[2])*dl, (accD[3]+bD[3])*dl);
      st4bf(&bufQ[bt*SW + c0 + quad*4],
            accQ[0]+bQ[0], accQ[1]+bQ[1], accQ[2]+bQ[2], accQ[3]+bQ[3]);
      #pragma unroll
      for (int r = 0; r < 4; ++r) x1r[nt][r] = acc1[r] + b1a[r];
      st4bf(&Sts[bt*SW + c0 + quad*4],
            accS[0] + ut*Mv[0] + bS[0]*(1.f+Rn), accS[1] + ut*Mv[1] + bS[1]*(1.f+Rn),
            accS[2] + ut*Mv[2] + bS[2]*(1.f+Rn), accS[3] + ut*Mv[3] + bS[3]*(1.f+Rn));
    }
  }
  __syncthreads();

  // ---- phase 3: K_t, V_t from D; re-zero V2 cols 24..31 (Pts dead) ----
  {
    for (int i = tid; i < 512; i += 256) V2[(i>>3)*40 + 24 + (i&7)] = 0;
    bf16x8 aK0 = *(const bf16x8*)(WBF + WB_KT + (c0+l15)*64 + quad*8);
    bf16x8 aK1 = *(const bf16x8*)(WBF + WB_KT + (c0+l15)*64 + 32 + quad*8);
    bf16x8 aV0 = *(const bf16x8*)(WBF + WB_VT + (c0+l15)*64 + quad*8);
    bf16x8 aV1 = *(const bf16x8*)(WBF + WB_VT + (c0+l15)*64 + 32 + quad*8);
    float4 bK4 = *(const float4*)&bk_t[c0 + quad*4];
    float4 bV4 = *(const float4*)&bv_t[c0 + quad*4];
    float bK[4] = {bK4.x,bK4.y,bK4.z,bK4.w};
    float bV[4] = {bV4.x,bV4.y,bV4.z,bV4.w};
    #pragma unroll
    for (int nt = 0; nt < 2; ++nt) {
      int bt = nt*16 + l15;
      bf16x8 b0 = *(const bf16x8*)&bufD[bt*SW + quad*8];
      bf16x8 b1v = *(const bf16x8*)&bufD[bt*SW + 32 + quad*8];
      f32x4 accK = {0.f,0.f,0.f,0.f}, accV = {0.f,0.f,0.f,0.f};
      accK = __builtin_amdgcn_mfma_f32_16x16x32_bf16(aK0, b0,  accK, 0,0,0);
      accK = __builtin_amdgcn_mfma_f32_16x16x32_bf16(aK1, b1v, accK, 0,0,0);
      accV = __builtin_amdgcn_mfma_f32_16x16x32_bf16(aV0, b0,  accV, 0,0,0);
      accV = __builtin_amdgcn_mfma_f32_16x16x32_bf16(aV1, b1v, accV, 0,0,0);
      st4bf(&bufK[bt*SW + c0 + quad*4],
            accK[0]+bK[0], accK[1]+bK[1], accK[2]+bK[2], accK[3]+bK[3]);
      if (bt < 24) {
        #pragma unroll
        for (int r = 0; r < 4; ++r)
          V2[(c0 + quad*4 + r)*40 + bt] = f2bfb(accV[r] + bV[r]);
      }
    }
  }
  __syncthreads();

  // ---- phase 4 + softmax 1 in-register (waves 0,1) -> scb (bufD region) ----
  if (wave < 2) {
    const int mt = wave * 16;
    bf16x8 a0 = *(const bf16x8*)&bufQ[(mt+l15)*SW + quad*8];
    bf16x8 a1f = *(const bf16x8*)&bufQ[(mt+l15)*SW + 32 + quad*8];
    bf16x8 k0a = *(const bf16x8*)&bufK[l15*SW + quad*8];
    bf16x8 k0b = *(const bf16x8*)&bufK[l15*SW + 32 + quad*8];
    bf16x8 k1a = *(const bf16x8*)&bufK[(16+l15)*SW + quad*8];
    bf16x8 k1b = *(const bf16x8*)&bufK[(16+l15)*SW + 32 + quad*8];
    f32x4 s0 = {0.f,0.f,0.f,0.f}, s1 = {0.f,0.f,0.f,0.f};
    s0 = __builtin_amdgcn_mfma_f32_16x16x32_bf16(a0, k0a, s0, 0,0,0);
    s0 = __builtin_amdgcn_mfma_f32_16x16x32_bf16(a1f, k0b, s0, 0,0,0);
    s1 = __builtin_amdgcn_mfma_f32_16x16x32_bf16(a0, k1a, s1, 0,0,0);
    s1 = __builtin_amdgcn_mfma_f32_16x16x32_bf16(a1f, k1b, s1, 0,0,0);
    #pragma unroll
    for (int r = 0; r < 4; ++r) {
      float v0 = 0.125f * s0[r];
      float v1 = (l15 < 8) ? 0.125f * s1[r] : -3.0e38f;
      float mx = fmaxf(v0, v1);
      mx = fmaxf(mx, __shfl_xor(mx, 1));
      mx = fmaxf(mx, __shfl_xor(mx, 2));
      mx = fmaxf(mx, __shfl_xor(mx, 4));
      mx = fmaxf(mx, __shfl_xor(mx, 8));
      float e0 = __expf(v0 - mx);
      float e1 = (l15 < 8) ? __expf(v1 - mx) : 0.f;
      float sm = e0 + e1;
      sm += __shfl_xor(sm, 1);
      sm += __shfl_xor(sm, 2);
      sm += __shfl_xor(sm, 4);
      sm += __shfl_xor(sm, 8);
      float inv = 1.f / sm;
      int t = mt + quad*4 + r;
      bool tv = (t < 24);
      scb[t*40 + l15]      = tv ? f2bfb(e0 * inv) : (ushort_t)0;
      scb[t*40 + 16 + l15] = (tv && l15 < 8) ? f2bfb(e1 * inv) : (ushort_t)0;
    }
  }
  __syncthreads();

  // ---- phase 5: XD[c][t] = V P^T (swapped operands) + x1(regs) -> XDg ----
  {
    for (int i = tid; i < 640; i += 256) {
      int r = i >> 6, cg = i & 63;
      int row = (r == 0) ? 0 : (24 + r);
      XDg[row*SW + cg] = 0;
    }
    bf16x8 aV = *(const bf16x8*)&V2[(c0 + l15)*40 + quad*8];
    #pragma unroll
    for (int nt = 0; nt < 2; ++nt) {
      bf16x8 bP = *(const bf16x8*)&scb[(nt*16 + l15)*40 + quad*8];
      f32x4 z = {0.f,0.f,0.f,0.f};
      f32x4 acc = __builtin_amdgcn_mfma_f32_16x16x32_bf16(aV, bP, z, 0,0,0);
      int t = nt*16 + l15;
      if (t < 24) {
        #pragma unroll
        for (int r = 0; r < 4; ++r)
          XDg[(1 + t)*SW + c0 + quad*4 + r] = f2bfb(acc[r] + x1r[nt][r]);
      }
    }
  }
  __syncthreads();

  // ---- phase 6: x1c = conv_t(XD) -> bufD ----
  {
    float4 bc4 = *(const float4*)&b_c1[c0 + quad*4];
    float bc[4] = {bc4.x,bc4.y,bc4.z,bc4.w};
    f32x4 acc0 = {0.f,0.f,0.f,0.f}, acc1v = {0.f,0.f,0.f,0.f};
    #pragma unroll
    for (int d = 0; d < 3; ++d) {
      const ushort_t* Ad = WBF + WB_C1A + d*4096;
      bf16x8 a0 = *(const bf16x8*)(Ad + (c0+l15)*64 + quad*8);
      bf16x8 a1f = *(const bf16x8*)(Ad + (c0+l15)*64 + 32 + quad*8);
      {
        int rr = 0*16 + l15 + d;
        bf16x8 b0 = *(const bf16x8*)&XDg[rr*SW + quad*8];
        bf16x8 b1f = *(const bf16x8*)&XDg[rr*SW + 32 + quad*8];
        acc0 = __builtin_amdgcn_mfma_f32_16x16x32_bf16(a0, b0, acc0, 0,0,0);
        acc0 = __builtin_amdgcn_mfma_f32_16x16x32_bf16(a1f, b1f, acc0, 0,0,0);
      }
      {
        int rr = 1*16 + l15 + d;
        bf16x8 b0 = *(const bf16x8*)&XDg[rr*SW + quad*8];
        bf16x8 b1f = *(const bf16x8*)&XDg[rr*SW + 32 + quad*8];
        acc1v = __builtin_amdgcn_mfma_f32_16x16x32_bf16(a0, b0, acc1v, 0,0,0);
        acc1v = __builtin_amdgcn_mfma_f32_16x16x32_bf16(a1f, b1f, acc1v, 0,0,0);
      }
    }
    st4bf(&bufD[(0*16 + l15)*SW + c0 + quad*4],
          acc0[0]+bc[0], acc0[1]+bc[1], acc0[2]+bc[2], acc0[3]+bc[3]);
    st4bf(&bufD[(1*16 + l15)*SW + c0 + quad*4],
          acc1v[0]+bc[0], acc1v[1]+bc[1], acc1v[2]+bc[2], acc1v[3]+bc[3]);
  }
  __syncthreads();

  // ---- phase 7: Q_s (from x1c=bufD), K_s, V_s (from S) ----
  {
    bf16x8 aq0 = *(const bf16x8*)(WBF + WB_QS + (c0+l15)*64 + quad*8);
    bf16x8 aq1 = *(const bf16x8*)(WBF + WB_QS + (c0+l15)*64 + 32 + quad*8);
    bf16x8 ak0 = *(const bf16x8*)(WBF + WB_KS + (c0+l15)*64 + quad*8);
    bf16x8 ak1 = *(const bf16x8*)(WBF + WB_KS + (c0+l15)*64 + 32 + quad*8);
    bf16x8 av0 = *(const bf16x8*)(WBF + WB_VS + (c0+l15)*64 + quad*8);
    bf16x8 av1 = *(const bf16x8*)(WBF + WB_VS + (c0+l15)*64 + 32 + quad*8);
    float4 bq4 = *(const float4*)&bq_s[c0 + quad*4];
    float4 bk4 = *(const float4*)&bk_s[c0 + quad*4];
    float4 bv4 = *(const float4*)&bv_s[c0 + quad*4];
    float bq[4] = {bq4.x,bq4.y,bq4.z,bq4.w};
    float bk[4] = {bk4.x,bk4.y,bk4.z,bk4.w};
    float bv[4] = {bv4.x,bv4.y,bv4.z,bv4.w};
    #pragma unroll
    for (int nt = 0; nt < 2; ++nt) {
      int bt = nt*16 + l15;
      bf16x8 bx0 = *(const bf16x8*)&bufD[bt*SW + quad*8];
      bf16x8 bx1 = *(const bf16x8*)&bufD[bt*SW + 32 + quad*8];
      bf16x8 bs0 = *(const bf16x8*)&Sts[bt*SW + quad*8];
      bf16x8 bs1 = *(const bf16x8*)&Sts[bt*SW + 32 + quad*8];
      f32x4 accQ = {0.f,0.f,0.f,0.f}, accK = {0.f,0.f,0.f,0.f}, accV = {0.f,0.f,0.f,0.f};
      accQ = __builtin_amdgcn_mfma_f32_16x16x32_bf16(aq0, bx0, accQ, 0,0,0);
      accQ = __builtin_amdgcn_mfma_f32_16x16x32_bf16(aq1, bx1, accQ, 0,0,0);
      accK = __builtin_amdgcn_mfma_f32_16x16x32_bf16(ak0, bs0, accK, 0,0,0);
      accK = __builtin_amdgcn_mfma_f32_16x16x32_bf16(ak1, bs1, accK, 0,0,0);
      accV = __builtin_amdgcn_mfma_f32_16x16x32_bf16(av0, bs0, accV, 0,0,0);
      accV = __builtin_amdgcn_mfma_f32_16x16x32_bf16(av1, bs1, accV, 0,0,0);
      st4bf(&bufQ[bt*SW + c0 + quad*4],
            accQ[0]+bq[0], accQ[1]+bq[1], accQ[2]+bq[2], accQ[3]+bq[3]);
      st4bf(&bufK[bt*SW + c0 + quad*4],
            accK[0]+bk[0], accK[1]+bk[1], accK[2]+bk[2], accK[3]+bk[3]);
      if (bt < 24) {
        #pragma unroll
        for (int r = 0; r < 4; ++r)
          V2[(c0 + quad*4 + r)*40 + bt] = f2bfb(accV[r] + bv[r]);
      }
    }
  }
  __syncthreads();

  // ---- phase 8 + softmax 2 in-register (waves 0,1) -> scb (bufD region) ----
  if (wave < 2) {
    const int mt = wave * 16;
    bf16x8 a0 = *(const bf16x8*)&bufQ[(mt+l15)*SW + quad*8];
    bf16x8 a1f = *(const bf16x8*)&bufQ[(mt+l15)*SW + 32 + quad*8];
    bf16x8 k0a = *(const bf16x8*)&bufK[l15*SW + quad*8];
    bf16x8 k0b = *(const bf16x8*)&bufK[l15*SW + 32 + quad*8];
    bf16x8 k1a = *(const bf16x8*)&bufK[(16+l15)*SW + quad*8];
    bf16x8 k1b = *(const bf16x8*)&bufK[(16+l15)*SW + 32 + quad*8];
    f32x4 s0 = {0.f,0.f,0.f,0.f}, s1 = {0.f,0.f,0.f,0.f};
    s0 = __builtin_amdgcn_mfma_f32_16x16x32_bf16(a0, k0a, s0, 0,0,0);
    s0 = __builtin_amdgcn_mfma_f32_16x16x32_bf16(a1f, k0b, s0, 0,0,0);
    s1 = __builtin_amdgcn_mfma_f32_16x16x32_bf16(a0, k1a, s1, 0,0,0);
    s1 = __builtin_amdgcn_mfma_f32_16x16x32_bf16(a1f, k1b, s1, 0,0,0);
    #pragma unroll
    for (int r = 0; r < 4; ++r) {
      float v0 = 0.125f * s0[r];
      float v1 = (l15 < 8) ? 0.125f * s1[r] : -3.0e38f;
      float mx = fmaxf(v0, v1);
      mx = fmaxf(mx, __shfl_xor(mx, 1));
      mx = fmaxf(mx, __shfl_xor(mx, 2));
      mx = fmaxf(mx, __shfl_xor(mx, 4));
      mx = fmaxf(mx, __shfl_xor(mx, 8));
      float e0 = __expf(v0 - mx);
      float e1 = (l15 < 8) ? __expf(v1 - mx) : 0.f;
      float sm = e0 + e1;
      sm += __shfl_xor(sm, 1);
      sm += __shfl_xor(sm, 2);
      sm += __shfl_xor(sm, 4);
      sm += __shfl_xor(sm, 8);
      float inv = 1.f / sm;
      int t = mt + quad*4 + r;
      bool tv = (t < 24);
      scb[t*40 + l15]      = tv ? f2bfb(e0 * inv) : (ushort_t)0;
      scb[t*40 + 16 + l15] = (tv && l15 < 8) ? f2bfb(e1 * inv) : (ushort_t)0;
    }
  }
  __syncthreads();

  // ---- phase 9: XS = A_s @ V_s -> global [n][b][c][t] ----
  {
    int nc = wave * 16;
    bf16x8 bv0 = *(const bf16x8*)&V2[(nc + l15)*40 + quad*8];
    #pragma unroll
    for (int mt = 0; mt < 2; ++mt) {
      bf16x8 af = *(const bf16x8*)&scb[(mt*16 + l15)*40 + quad*8];
      f32x4 z = {0.f,0.f,0.f,0.f};
      f32x4 acc = __builtin_amdgcn_mfma_f32_16x16x32_bf16(af, bv0, z, 0,0,0);
      int ccol = nc + l15;
      int t0 = mt*16 + quad*4;
      if (t0 < 24) {
        uint2 w;
        w.x = rne2(acc[0], acc[1]);
        w.y = rne2(acc[2], acc[3]);
        *(uint2*)(XS + (size_t)n*XS_COLS + (size_t)b*COUT_*T_ + ccol*T_ + t0) = w;
      }
    }
  }
}

// ---------------------------------------------------------------------------
// k_final: Chebyshev-gate GEMM on MFMA + MFMA x_input1 (unchanged from R6)
// ---------------------------------------------------------------------------
#define ZW 200
__global__ __launch_bounds__(256) void k_final(
    const float* __restrict__ x,
    const ushort_t* __restrict__ XS, const ushort_t* __restrict__ Y1h,
    const ushort_t* __restrict__ Y2h,
    const ushort_t* __restrict__ WGBF, const ushort_t* __restrict__ WBF,
    const float* __restrict__ b_1, const float* __restrict__ b_g,
    int h, float* __restrict__ out)
{
  const int n = blockIdx.x, bb = blockIdx.y, tid = threadIdx.x;
  const int b = h * 8 + bb;
  const int wave = tid >> 6, lane = tid & 63;
  const int l15 = lane & 15, quad = lane >> 4;

  __shared__ __align__(16) ushort_t Zt[32*ZW];   // 12800 B
  __shared__ __align__(16) ushort_t xb[32*40];   // 2560 B, [t][ci] bf16 x-tile

  size_t baseg = (size_t)n * XS_COLS + (size_t)b * COUT_ * T_;
  size_t baseh = (size_t)n * HALF_COLS + (size_t)bb * COUT_ * T_;

  for (int i = tid; i < 8*ZW; i += 256) Zt[24*ZW + i] = 0;
  for (int i = tid; i < COUT_*T_; i += 256) {
    int c = i / T_, t = i - c*T_;
    ushort_t* zr = &Zt[t*ZW + 3*c];
    zr[0] = XS [baseg + i];
    zr[1] = Y1h[baseh + i];
    zr[2] = Y2h[baseh + i];
  }
  for (int i = tid; i < CIN_*T_; i += 256) {
    int ci = i / T_, t = i - ci*T_;
    xb[t*40 + ci] = f2bfb(x[(((size_t)b * CIN_ + ci) * N_ + n) * T_ + t]);
  }
  __syncthreads();

  f32x4 accF[2] = {{0.f,0.f,0.f,0.f},{0.f,0.f,0.f,0.f}};
  f32x4 accG[2] = {{0.f,0.f,0.f,0.f},{0.f,0.f,0.f,0.f}};
  f32x4 accX[2] = {{0.f,0.f,0.f,0.f},{0.f,0.f,0.f,0.f}};
  const ushort_t* WF = WGBF + (size_t)(wave*16 + l15)*192 + quad*8;
  const ushort_t* WG = WF + 64*192;
  bf16x8 aW1 = *(const bf16x8*)(WBF + WB_1 + (wave*16 + l15)*32 + quad*8);
  #pragma unroll
  for (int nt = 0; nt < 2; ++nt) {
    bf16x8 bx = *(const bf16x8*)&xb[(nt*16 + l15)*40 + quad*8];
    accX[nt] = __builtin_amdgcn_mfma_f32_16x16x32_bf16(aW1, bx, accX[nt], 0,0,0);
  }
  #pragma unroll
  for (int ks = 0; ks < 6; ++ks) {
    bf16x8 wf = *(const bf16x8*)(WF + ks*32);
    bf16x8 wg = *(const bf16x8*)(WG + ks*32);
    #pragma unroll
    for (int nt = 0; nt < 2; ++nt) {
      bf16x8 bz = *(const bf16x8*)&Zt[(nt*16 + l15)*ZW + ks*32 + quad*8];
      accF[nt] = __builtin_amdgcn_mfma_f32_16x16x32_bf16(wf, bz, accF[nt], 0,0,0);
      accG[nt] = __builtin_amdgcn_mfma_f32_16x16x32_bf16(wg, bz, accG[nt], 0,0,0);
    }
  }

  {
    float4 bgF4 = *(const float4*)&b_g[wave*16 + quad*4];
    float4 bgG4 = *(const float4*)&b_g[64 + wave*16 + quad*4];
    float4 b14  = *(const float4*)&b_1[wave*16 + quad*4];
    float bgF[4] = {bgF4.x, bgF4.y, bgF4.z, bgF4.w};
    float bgG[4] = {bgG4.x, bgG4.y, bgG4.z, bgG4.w};
    float b1a[4] = {b14.x, b14.y, b14.z, b14.w};
    #pragma unroll
    for (int nt = 0; nt < 2; ++nt) {
      int t = nt*16 + l15;
      if (t < 24) {
        #pragma unroll
        for (int r = 0; r < 4; ++r) {
          int c = wave*16 + quad*4 + r;
          float fv = accF[nt][r] + bgF[r] + accX[nt][r] + b1a[r];
          float gv = accG[nt][r] + bgG[r];
          out[(((size_t)b * COUT_ + c) * N_ + n) * T_ + t] = fv * sigm_(gv);
        }
      }
    }
  }
}

// ---------------------------------------------------------------------------
extern "C" void kernel_launch(void* const* d_in, const int* in_sizes, int n_in,
                              void* d_out, int out_size, void* d_ws, size_t ws_size,
                              hipStream_t stream) {
  const float* x        = (const float*)d_in[0];
  const float* supports = (const float*)d_in[1];
  const float* CD       = (const float*)d_in[2];
  const float* CS       = (const float*)d_in[3];
  const float* adj      = (const float*)d_in[4];
  const float* W_de  = (const float*)d_in[5];  const float* b_de  = (const float*)d_in[6];
  const float* Wd    = (const float*)d_in[7];
  const float* W_pro = (const float*)d_in[8];  const float* b_pro = (const float*)d_in[9];
  const float* W_mii = (const float*)d_in[10]; const float* b_mii = (const float*)d_in[11];
  const float* W_1   = (const float*)d_in[12]; const float* b_1   = (const float*)d_in[13];
  const float* Wq_t  = (const float*)d_in[14]; const float* bq_t  = (const float*)d_in[15];
  const float* Wk_t  = (const float*)d_in[16]; const float* bk_t  = (const float*)d_in[17];
  const float* Wv_t  = (const float*)d_in[18]; const float* bv_t  = (const float*)d_in[19];
  const float* W_c1  = (const float*)d_in[20]; const float* b_c1  = (const float*)d_in[21];
  const float* Wq_s  = (const float*)d_in[22]; const float* bq_s  = (const float*)d_in[23];
  const float* Wk_s  = (const float*)d_in[24]; const float* bk_s  = (const float*)d_in[25];
  const float* Wv_s  = (const float*)d_in[26]; const float* bv_s  = (const float*)d_in[27];
  const float* W_g   = (const float*)d_in[28]; const float* b_g   = (const float*)d_in[29];
  float* out = (float*)d_out;

  char* ws = (char*)d_ws;
  float*    delay = (float*)(ws + OFF_DELAY);
  float*    Mbuf  = (float*)(ws + OFF_M);
  float*    Rbuf  = (float*)(ws + OFF_R);
  float*    u     = (float*)(ws + OFF_U);
  float*    W1T   = (float*)(ws + OFF_W1T);
  ushort_t* WGBF  = (ushort_t*)(ws + OFF_WGBF);
  ushort_t* Sbf   = (ushort_t*)(ws + OFF_SBF);
  ushort_t* adjbf = (ushort_t*)(ws + OFF_ADJBF);
  ushort_t* STbf  = (ushort_t*)(ws + OFF_STBF);
  ushort_t* L2bf  = (ushort_t*)(ws + OFF_L2BF);
  ushort_t* Ue    = (ushort_t*)(ws + OFF_X1);
  ushort_t* P     = (ushort_t*)(ws + OFF_X1);   // overwrites Ue (dead)
  ushort_t* xbf   = (ushort_t*)(ws + OFF_X2);   // bf16 x copy (steps 5-8)
  ushort_t* XST   = (ushort_t*)(ws + OFF_X2);   // overwrites xbf (step 9)
  ushort_t* UeT   = (ushort_t*)(ws + OFF_Y1H);  // temp (steps 6-7)
  ushort_t* XS    = (ushort_t*)(ws + OFF_XS);
  ushort_t* Y1h   = (ushort_t*)(ws + OFF_Y1H);
  ushort_t* Y2h   = (ushort_t*)(ws + OFF_Y2H);
  ushort_t* WBF   = (ushort_t*)(ws + OFF_WBF);

  (void)in_sizes; (void)n_in; (void)out_size; (void)ws_size;

  // 1) conversions + weight prep
  k_prep<<<dim3((PREP_TOTAL + 255)/256), 256, 0, stream>>>(
      supports, adj, W_de, Wq_t, W_1, W_mii, Wk_t, Wv_t, Wq_s, Wk_s, Wv_s,
      W_c1, W_g, Sbf, adjbf, W1T, WGBF, WBF);
  // 2) delay / Mbuf / Rbuf
  k_pre<<<dim3((NT_ + N_*COUT_ + 8*N_ + 255)/256), 256, 0, stream>>>(
      CD, Wd, CS, W_mii, adj, delay, Mbuf, Rbuf);
  // 3) S^T via coalesced transpose
  k_tr<<<dim3(N_/32, N_/32), 256, 0, stream>>>(Sbf, STbf, N_, N_);
  // 4) L2 = 2*S@S - I
  k_mmx<2><<<dim3(8, 8), 256, 0, stream>>>(Sbf, STbf, L2bf, 1024);
  // 5) u + Ue + xbf
  k_u<<<dim3((BNT_ + 255)/256), 256, 0, stream>>>(x, W_pro, b_pro, CS, u, Ue, xbf);
  // 6) UeT (relocated to Y1H region — xbf now owns X2)
  k_tr<<<dim3(UE_COLS/32, N_/32), 256, 0, stream>>>(Ue, UeT, N_, UE_COLS);
  // 7) P = adj @ Ue
  k_mmx<0><<<dim3(UE_COLS/128, N_/128), 256, 0, stream>>>(adjbf, UeT, P, UE_COLS);
  // 8) MFMA attention pipeline -> XS
  k_attn_mfma<<<dim3(N_, B_), 256, 0, stream>>>(
      xbf, delay, Mbuf, Rbuf, u, P, WBF,
      b_de, bq_t, b_1, b_mii, bk_t, bv_t, bq_s, bk_s, bv_s, b_c1, XS);
  // 9) per half: transpose (XST overwrites xbf — attn done), fused Y1/Y2, final
  for (int h = 0; h < 2; ++h) {
    k_tr<<<dim3(HALF_COLS/32, N_/32), 256, 0, stream>>>(
        XS + (size_t)h * HALF_COLS, XST, N_, XS_COLS);
    k_mmy<<<dim3(HALF_COLS/128, 16), 256, 0, stream>>>(
        Sbf, L2bf, XST, Y1h, Y2h, HALF_COLS);
    k_final<<<dim3(N_, 8), 256, 0, stream>>>(
        x, XS, Y1h, Y2h, WGBF, WBF, b_1, b_g, h, out);
  }
}

// Round 9
// 685.850 us; speedup vs baseline: 1.1328x; 1.0390x over previous
//
#include <hip/hip_runtime.h>
#include <cstdint>
#include <cstddef>

#define B_    16
#define CIN_  32
#define COUT_ 64
#define N_    1024
#define T_    24
#define SD_   16
#define DD_   16

#define NT_      (N_*T_)          // 24576
#define BNT_     (B_*N_*T_)       // 393216
#define UE_COLS  (B_*T_*SD_)      // 6144
#define XS_COLS  (B_*COUT_*T_)    // 24576
#define HALF_COLS (XS_COLS/2)     // 12288

typedef unsigned short ushort_t;
using bf16x8 = __attribute__((ext_vector_type(8))) short;
using f32x4  = __attribute__((ext_vector_type(4))) float;

// ---- workspace byte offsets ----
#define OFF_DELAY 0ul
#define OFF_M     98304ul
#define OFF_R     360448ul
#define OFF_U     364544ul
#define OFF_WGBF  2048000ul              // bf16 W_g copy (24576 elems = 49152 B)
#define OFF_SBF   2195456ul
#define OFF_ADJBF 4292608ul
#define OFF_STBF  6389760ul
#define OFF_L2BF  8486912ul
#define OFF_X1    10584064ul             // Ue then P (bf16 1024*6144)
#define OFF_X2    23166976ul             // xbf (25165824 B exactly) then XST_h
#define OFF_XS    48332800ul             // bf16 1024*24576
#define OFF_Y1H   98664448ul             // UeT (step 5-6), then Y1h (step 8)
#define OFF_Y2H   123830272ul            // bf16 1024*12288
#define OFF_WBF   148996096ul            // bf16 weights, 40960 elems = 81920 B

// bf16 weight sub-offsets (element index within WBF)
#define WB_DE   0
#define WB_QT   2048
#define WB_1    4096
#define WB_MIIA 6144
#define WB_KT   8192
#define WB_VT   12288
#define WB_QS   16384
#define WB_KS   20480
#define WB_VS   24576
#define WB_C1A  28672   // [3][64][64]

__device__ __forceinline__ float bfb2f(ushort_t h) {
  union { unsigned u; float f; } v; v.u = ((unsigned)h) << 16; return v.f;
}
// software round-to-nearest-even f32->bf16 (R4's HW v_cvt_pk_bf16_f32 asm
// FAILED numerics — biased rounding accumulated to 3x threshold; keep RNE)
__device__ __forceinline__ ushort_t f2bfb(float f) {
  union { float f; unsigned u; } v; v.f = f;
  unsigned u = v.u;
  return (ushort_t)((u + 0x7fffu + ((u >> 16) & 1u)) >> 16);
}
// RNE pack of two f32 into one u32 (lo = low 16 bits), bit-identical to
// f2bfb pair, fewer VALU ops.
__device__ __forceinline__ unsigned rne2(float lo, float hi) {
  union { float f; unsigned u; } a, b;
  a.f = lo; b.f = hi;
  unsigned ua = (a.u + 0x7fffu + ((a.u >> 16) & 1u)) >> 16;
  unsigned ub = (b.u + 0x7fffu + ((b.u >> 16) & 1u)) & 0xffff0000u;
  return ua | ub;
}
__device__ __forceinline__ float sigm_(float z) { return 1.f / (1.f + __expf(-z)); }

__device__ __forceinline__ void gl_lds16(const ushort_t* g, ushort_t* l) {
  __builtin_amdgcn_global_load_lds(
      (const __attribute__((address_space(1))) unsigned int*)g,
      (__attribute__((address_space(3))) unsigned int*)l, 16, 0, 0);
}

__device__ __forceinline__ void st4bf(ushort_t* p, float v0, float v1, float v2, float v3) {
  uint2 w;
  w.x = rne2(v0, v1);
  w.y = rne2(v2, v3);
  *(uint2*)p = w;
}

// ---------------------------------------------------------------------------
// k_prep (R9: k_pre merged in, dead W1T branch removed): bf16 supports/adj,
// bf16 W_g copy, bf16 weight copies, delay/Mbuf/Rbuf.
// All sub-range offsets divisible by 64 so Rbuf's 8-lane shfl groups stay
// wave-aligned.
// ---------------------------------------------------------------------------
__global__ __launch_bounds__(256) void k_prep(
    const float* __restrict__ supports, const float* __restrict__ adj,
    const float* __restrict__ W_de, const float* __restrict__ Wq_t,
    const float* __restrict__ W_1, const float* __restrict__ W_mii,
    const float* __restrict__ Wk_t, const float* __restrict__ Wv_t,
    const float* __restrict__ Wq_s, const float* __restrict__ Wk_s,
    const float* __restrict__ Wv_s, const float* __restrict__ W_c1,
    const float* __restrict__ W_g,
    const float* __restrict__ CD, const float* __restrict__ Wd,
    const float* __restrict__ CS,
    ushort_t* __restrict__ Sbf, ushort_t* __restrict__ adjbf,
    ushort_t* __restrict__ WGBF, ushort_t* __restrict__ WBF,
    float* __restrict__ delay, float* __restrict__ Mbuf,
    float* __restrict__ Rbuf)
{
  int idx = blockIdx.x * 256 + threadIdx.x;
  if (idx < N_*N_) {
    Sbf[idx]   = f2bfb(supports[idx]);
    adjbf[idx] = f2bfb(adj[idx]);
  }
  int j = idx - N_*N_;
  if (j < 0) return;
  if (j < 24576) { WGBF[j] = f2bfb(W_g[j]); return; }
  j -= 24576;
  if (j < 2048) { WBF[WB_DE + j] = f2bfb(W_de[j]); return; }
  j -= 2048;
  if (j < 2048) { WBF[WB_QT + j] = f2bfb(Wq_t[j]); return; }
  j -= 2048;
  if (j < 2048) { WBF[WB_1 + j] = f2bfb(W_1[j]); return; }
  j -= 2048;
  if (j < 2048) { int c = j>>5, k = j&31;
                  WBF[WB_MIIA + j] = (k < 16) ? f2bfb(W_mii[c*16 + k]) : (ushort_t)0; return; }
  j -= 2048;
  if (j < 4096) { WBF[WB_KT + j] = f2bfb(Wk_t[j]); return; }
  j -= 4096;
  if (j < 4096) { WBF[WB_VT + j] = f2bfb(Wv_t[j]); return; }
  j -= 4096;
  if (j < 4096) { WBF[WB_QS + j] = f2bfb(Wq_s[j]); return; }
  j -= 4096;
  if (j < 4096) { WBF[WB_KS + j] = f2bfb(Wk_s[j]); return; }
  j -= 4096;
  if (j < 4096) { WBF[WB_VS + j] = f2bfb(Wv_s[j]); return; }
  j -= 4096;
  if (j < 12288) { int d = j >> 12, r = j & 4095, c = r >> 6, jj = r & 63;
                   WBF[WB_C1A + j] = f2bfb(W_c1[(c*64 + jj)*3 + d]); return; }
  j -= 12288;
  // ---- merged k_pre work ----
  if (j < NT_) {
    int n = j / T_, t = j % T_;
    float z = 0.f;
    #pragma unroll
    for (int d = 0; d < DD_; ++d) z += CD[n*DD_ + d] * Wd[d*T_ + t];
    delay[j] = sigm_(tanhf(z));
    return;
  }
  j -= NT_;
  if (j < N_*COUT_) {
    int n = j / COUT_, c = j % COUT_;
    float z = 0.f;
    #pragma unroll
    for (int e = 0; e < SD_; ++e) z += CS[n*SD_ + e] * W_mii[c*SD_ + e];
    Mbuf[j] = z;
    return;
  }
  j -= N_*COUT_;
  if (j < 8*N_) {
    int n = j >> 3, jl = j & 7;
    const float* row = adj + (size_t)n * N_;
    float s = 0.f;
    for (int m = jl; m < N_; m += 8) s += row[m];
    s += __shfl_xor(s, 1);
    s += __shfl_xor(s, 2);
    s += __shfl_xor(s, 4);
    if (jl == 0) Rbuf[n] = s;
  }
}
#define PREP_TOTAL (N_*N_ + 24576 + 2048*4 + 4096*5 + 12288 + NT_ + N_*COUT_ + 8*N_)

// ---------------------------------------------------------------------------
// k_u: u + Ue + xbf (bf16 transposed x copy: row (b*N+n)*T+t, 32 channels)
// ---------------------------------------------------------------------------
__global__ __launch_bounds__(256) void k_u(
    const float* __restrict__ x, const float* __restrict__ W_pro,
    const float* __restrict__ b_pro, const float* __restrict__ CS,
    float* __restrict__ u, ushort_t* __restrict__ Ue,
    ushort_t* __restrict__ xbf)
{
  int idx = blockIdx.x * 256 + threadIdx.x;
  if (idx >= BNT_) return;
  int t = idx % T_;
  int n = (idx / T_) % N_;
  int b = idx / (T_ * N_);
  const float* xp = x + ((size_t)b * CIN_ * N_ + n) * T_ + t;
  float xv[CIN_];
  float z = b_pro[0];
  #pragma unroll
  for (int i = 0; i < CIN_; ++i) { xv[i] = xp[(size_t)i * NT_]; z += W_pro[i] * xv[i]; }
  u[idx] = z;
  ushort_t* up = Ue + (size_t)n * UE_COLS + (b * T_ + t) * SD_;
  unsigned w[8];
  #pragma unroll
  for (int e = 0; e < 8; ++e)
    w[e] = rne2(z * CS[n*SD_ + 2*e], z * CS[n*SD_ + 2*e + 1]);
  ((uint4*)up)[0] = make_uint4(w[0], w[1], w[2], w[3]);
  ((uint4*)up)[1] = make_uint4(w[4], w[5], w[6], w[7]);
  ushort_t* xr = xbf + (size_t)idx * 32;
  unsigned q[16];
  #pragma unroll
  for (int e = 0; e < 16; ++e)
    q[e] = rne2(xv[2*e], xv[2*e + 1]);
  ((uint4*)xr)[0] = make_uint4(q[0],  q[1],  q[2],  q[3]);
  ((uint4*)xr)[1] = make_uint4(q[4],  q[5],  q[6],  q[7]);
  ((uint4*)xr)[2] = make_uint4(q[8],  q[9],  q[10], q[11]);
  ((uint4*)xr)[3] = make_uint4(q[12], q[13], q[14], q[15]);
}

// ---------------------------------------------------------------------------
// k_tr: bf16 transpose dst[c*R + r] = src[r*sstride + c]
// ---------------------------------------------------------------------------
__global__ __launch_bounds__(256) void k_tr(
    const ushort_t* __restrict__ src, ushort_t* __restrict__ dst,
    int R, int sstride)
{
  __shared__ ushort_t tb[32][33];
  const int tid = threadIdx.x;
  const int tx = tid & 31, ty = tid >> 5;
  const int c0 = blockIdx.x * 32, r0 = blockIdx.y * 32;
  #pragma unroll
  for (int p = 0; p < 4; ++p) {
    int r = r0 + ty + p*8;
    tb[ty + p*8][tx] = src[(size_t)r * sstride + c0 + tx];
  }
  __syncthreads();
  #pragma unroll
  for (int p = 0; p < 4; ++p) {
    int c = c0 + ty + p*8;
    dst[(size_t)c * R + r0 + tx] = tb[tx][ty + p*8];
  }
}

// ---------------------------------------------------------------------------
// k_mmx: MFMA GEMM
// ---------------------------------------------------------------------------
template<int MODE>
__global__ __launch_bounds__(256) void k_mmx(
    const ushort_t* __restrict__ Abf, const ushort_t* __restrict__ BT,
    ushort_t* __restrict__ Cc, int ncols)
{
  __shared__ ushort_t As[128*64];
  __shared__ ushort_t Bs[128*64];
  const int tid  = threadIdx.x;
  const int wave = tid >> 6, lane = tid & 63;
  const int row0 = blockIdx.y * 128;
  const int col0 = blockIdx.x * 128;
  const int wm = (wave >> 1) * 64, wn = (wave & 1) * 64;
  const int l15 = lane & 15, quad = lane >> 4, l7 = lane & 7;

  f32x4 acc[4][4];
  #pragma unroll
  for (int i = 0; i < 4; ++i)
    #pragma unroll
    for (int j = 0; j < 4; ++j) acc[i][j] = (f32x4){0.f,0.f,0.f,0.f};

  for (int kb = 0; kb < 1024; kb += 64) {
    #pragma unroll
    for (int p = 0; p < 4; ++p) {
      int chunk = p*256 + tid;
      int r = chunk >> 3, pc = chunk & 7;
      int kc = pc ^ (r & 7);
      gl_lds16(Abf + (size_t)(row0 + r)*1024 + (kb + kc*8), &As[chunk*8]);
    }
    #pragma unroll
    for (int p = 0; p < 4; ++p) {
      int chunk = p*256 + tid;
      int r = chunk >> 3, pc = chunk & 7;
      int kc = pc ^ (r & 7);
      gl_lds16(BT + (size_t)(col0 + r)*1024 + (kb + kc*8), &Bs[chunk*8]);
    }
    __syncthreads();
    #pragma unroll
    for (int kh = 0; kh < 2; ++kh) {
      const int kcb = kh * 4;
      bf16x8 af[4], bfr[4];
      #pragma unroll
      for (int mi = 0; mi < 4; ++mi)
        af[mi] = *(const bf16x8*)&As[(wm + mi*16 + l15)*64 + (((kcb + quad) ^ l7) << 3)];
      #pragma unroll
      for (int ni = 0; ni < 4; ++ni)
        bfr[ni] = *(const bf16x8*)&Bs[(wn + ni*16 + l15)*64 + (((kcb + quad) ^ l7) << 3)];
      #pragma unroll
      for (int mi = 0; mi < 4; ++mi)
        #pragma unroll
        for (int ni = 0; ni < 4; ++ni)
          acc[mi][ni] = __builtin_amdgcn_mfma_f32_16x16x32_bf16(
              af[mi], bfr[ni], acc[mi][ni], 0, 0, 0);
    }
    __syncthreads();
  }

  #pragma unroll
  for (int mi = 0; mi < 4; ++mi) {
    int grow_b = row0 + wm + mi*16 + quad*4;
    #pragma unroll
    for (int ni = 0; ni < 4; ++ni) {
      int gcol = col0 + wn + ni*16 + l15;
      #pragma unroll
      for (int j = 0; j < 4; ++j) {
        float v = acc[mi][ni][j];
        int grow = grow_b + j;
        if (MODE == 2) v = 2.f*v - ((grow == gcol) ? 1.f : 0.f);
        Cc[(size_t)grow * ncols + gcol] = f2bfb(v);
      }
    }
  }
}

// ---------------------------------------------------------------------------
// k_mmy: fused Y1=S@XST, Y2=L2@XST in one launch (by<8 -> Y1, else Y2).
// ---------------------------------------------------------------------------
__global__ __launch_bounds__(256) void k_mmy(
    const ushort_t* __restrict__ Sbf, const ushort_t* __restrict__ L2bf,
    const ushort_t* __restrict__ BT,
    ushort_t* __restrict__ Y1, ushort_t* __restrict__ Y2, int ncols)
{
  __shared__ ushort_t As[128*64];
  __shared__ ushort_t Bs[128*64];
  const int tid  = threadIdx.x;
  const int wave = tid >> 6, lane = tid & 63;
  const bool isY2 = blockIdx.y >= 8;
  const ushort_t* Abf = isY2 ? L2bf : Sbf;
  ushort_t* Cc = isY2 ? Y2 : Y1;
  const int row0 = (blockIdx.y & 7) * 128;
  const int col0 = blockIdx.x * 128;
  const int wm = (wave >> 1) * 64, wn = (wave & 1) * 64;
  const int l15 = lane & 15, quad = lane >> 4, l7 = lane & 7;

  f32x4 acc[4][4];
  #pragma unroll
  for (int i = 0; i < 4; ++i)
    #pragma unroll
    for (int j = 0; j < 4; ++j) acc[i][j] = (f32x4){0.f,0.f,0.f,0.f};

  for (int kb = 0; kb < 1024; kb += 64) {
    #pragma unroll
    for (int p = 0; p < 4; ++p) {
      int chunk = p*256 + tid;
      int r = chunk >> 3, pc = chunk & 7;
      int kc = pc ^ (r & 7);
      gl_lds16(Abf + (size_t)(row0 + r)*1024 + (kb + kc*8), &As[chunk*8]);
    }
    #pragma unroll
    for (int p = 0; p < 4; ++p) {
      int chunk = p*256 + tid;
      int r = chunk >> 3, pc = chunk & 7;
      int kc = pc ^ (r & 7);
      gl_lds16(BT + (size_t)(col0 + r)*1024 + (kb + kc*8), &Bs[chunk*8]);
    }
    __syncthreads();
    #pragma unroll
    for (int kh = 0; kh < 2; ++kh) {
      const int kcb = kh * 4;
      bf16x8 af[4], bfr[4];
      #pragma unroll
      for (int mi = 0; mi < 4; ++mi)
        af[mi] = *(const bf16x8*)&As[(wm + mi*16 + l15)*64 + (((kcb + quad) ^ l7) << 3)];
      #pragma unroll
      for (int ni = 0; ni < 4; ++ni)
        bfr[ni] = *(const bf16x8*)&Bs[(wn + ni*16 + l15)*64 + (((kcb + quad) ^ l7) << 3)];
      #pragma unroll
      for (int mi = 0; mi < 4; ++mi)
        #pragma unroll
        for (int ni = 0; ni < 4; ++ni)
          acc[mi][ni] = __builtin_amdgcn_mfma_f32_16x16x32_bf16(
              af[mi], bfr[ni], acc[mi][ni], 0, 0, 0);
    }
    __syncthreads();
  }

  #pragma unroll
  for (int mi = 0; mi < 4; ++mi) {
    int grow_b = row0 + wm + mi*16 + quad*4;
    #pragma unroll
    for (int ni = 0; ni < 4; ++ni) {
      int gcol = col0 + wn + ni*16 + l15;
      #pragma unroll
      for (int j = 0; j < 4; ++j)
        Cc[(size_t)(grow_b + j) * ncols + gcol] = f2bfb(acc[mi][ni][j]);
    }
  }
}

// ---------------------------------------------------------------------------
// k_attn_mfma: unchanged from R8 (passed; FETCH 20.6 MB, 187 us)
// ---------------------------------------------------------------------------
#define SW 72
__global__ __launch_bounds__(256, 6) void k_attn_mfma(
    const ushort_t* __restrict__ xbf,
    const float* __restrict__ delay, const float* __restrict__ Mbuf,
    const float* __restrict__ Rbuf, const float* __restrict__ u,
    const ushort_t* __restrict__ P,
    const ushort_t* __restrict__ WBF,
    const float* __restrict__ b_de, const float* __restrict__ bq_t,
    const float* __restrict__ b_1,  const float* __restrict__ b_mii,
    const float* __restrict__ bk_t, const float* __restrict__ bv_t,
    const float* __restrict__ bq_s, const float* __restrict__ bk_s,
    const float* __restrict__ bv_s, const float* __restrict__ b_c1,
    ushort_t* __restrict__ XS)
{
  const int n = blockIdx.x, b = blockIdx.y;
  const int tid = threadIdx.x, wave = tid >> 6, lane = tid & 63;
  const int l15 = lane & 15, quad = lane >> 4;

  __shared__ __align__(16) char smem[24352];
  ushort_t* bufQ = (ushort_t*)(smem + 0);       // pool A: Qt[2-4], Qs[7-8]
  ushort_t* XDg  = (ushort_t*)(smem + 0);       //   alias: XDg[5-6] (34 rows)
  ushort_t* Bc   = (ushort_t*)(smem + 4896);    // pool B: x [stage-2] stride 32
  ushort_t* bufK = (ushort_t*)(smem + 4896);    //   alias: Kt[3-4], Ks[7-8]
  ushort_t* bufD = (ushort_t*)(smem + 9504);    // D[2-3], x1c[6-7]
  ushort_t* scb  = (ushort_t*)(smem + 9504);    //   alias: P bf16 [4-5],[8-9]
  ushort_t* Sts  = (ushort_t*)(smem + 14112);   // S [2-7]
  ushort_t* V2   = (ushort_t*)(smem + 18720);   // V [c][s] [3-5],[7-9]
  ushort_t* Pts  = (ushort_t*)(smem + 18720);   //   alias: P staging, stride 16
  float* delay_s = (float*)(smem + 23840);
  float* urow    = (float*)(smem + 23968);
  float* Mrow    = (float*)(smem + 24096);

  // ---- staging (gl_lds16, wave-aligned from lane 0; zero VALU conversion) ----
  {
    const ushort_t* xsrc = xbf + (size_t)((b * N_ + n)) * T_ * 32;     // 768 ushorts
    const ushort_t* psrc = P + (size_t)n * UE_COLS + (size_t)b * T_ * SD_; // 384 ushorts
    if (wave == 0) {
      gl_lds16(xsrc + lane * 8, &Bc[lane * 8]);
    } else if (wave == 1) {
      if (lane < 32) gl_lds16(xsrc + (64 + lane) * 8, &Bc[(64 + lane) * 8]);
      else { int t = lane - 32; urow[t] = (t < 24) ? u[((size_t)b*N_ + n)*T_ + t] : 0.f; }
    } else if (wave == 2) {
      if (lane < 48) gl_lds16(psrc + lane * 8, &Pts[lane * 8]);
      else { int t0 = (lane - 48) * 2;
             delay_s[t0]     = (t0     < 24) ? delay[n*T_ + t0]     : 0.f;
             delay_s[t0 + 1] = (t0 + 1 < 24) ? delay[n*T_ + t0 + 1] : 0.f; }
    } else {
      Mrow[lane] = Mbuf[n*COUT_ + lane];
    }
  }
  __syncthreads();

  const int c0 = wave * 16;
  const float Rn = Rbuf[n];
  float x1r[2][4];   // x_input1 registers, p2 -> p5

  // ---- phase 2: D, Q_t, x_input1(regs), S ----
  {
    bf16x8 aD = *(const bf16x8*)(WBF + WB_DE   + (c0+l15)*32 + quad*8);
    bf16x8 aQ = *(const bf16x8*)(WBF + WB_QT   + (c0+l15)*32 + quad*8);
    bf16x8 a1w = *(const bf16x8*)(WBF + WB_1   + (c0+l15)*32 + quad*8);
    bf16x8 aS = *(const bf16x8*)(WBF + WB_MIIA + (c0+l15)*32 + quad*8);
    float4 bD4 = *(const float4*)&b_de [c0 + quad*4];
    float4 bQ4 = *(const float4*)&bq_t [c0 + quad*4];
    float4 b14 = *(const float4*)&b_1  [c0 + quad*4];
    float4 bS4 = *(const float4*)&b_mii[c0 + quad*4];
    float4 Mv4 = *(const float4*)&Mrow [c0 + quad*4];
    float bD[4] = {bD4.x,bD4.y,bD4.z,bD4.w};
    float bQ[4] = {bQ4.x,bQ4.y,bQ4.z,bQ4.w};
    float b1a[4] = {b14.x,b14.y,b14.z,b14.w};
    float bS[4] = {bS4.x,bS4.y,bS4.z,bS4.w};
    float Mv[4] = {Mv4.x,Mv4.y,Mv4.z,Mv4.w};
    #pragma unroll
    for (int nt = 0; nt < 2; ++nt) {
      int bt = nt*16 + l15;
      bf16x8 bx = *(const bf16x8*)&Bc[bt*32 + quad*8];
      bf16x8 bp = (bf16x8){0,0,0,0,0,0,0,0};
      if (quad < 2) bp = *(const bf16x8*)&Pts[bt*16 + quad*8];
      f32x4 z = {0.f,0.f,0.f,0.f};
      f32x4 accD = __builtin_amdgcn_mfma_f32_16x16x32_bf16(aD, bx, z, 0,0,0);
      f32x4 accQ = __builtin_amdgcn_mfma_f32_16x16x32_bf16(aQ, bx, z, 0,0,0);
      f32x4 acc1 = __builtin_amdgcn_mfma_f32_16x16x32_bf16(a1w, bx, z, 0,0,0);
      f32x4 accS = __builtin_amdgcn_mfma_f32_16x16x32_bf16(aS, bp, z, 0,0,0);
      float dl = delay_s[bt], ut = urow[bt];
      st4bf(&bufD[bt*SW + c0 + quad*4],
            (accD[0]+bD[0])*dl, (accD[1]+bD[1])*dl, (accD[2]+bD[2])*dl, (accD[3]+bD[3])*dl);
      st4bf(&bufQ[bt*SW + c0 + quad*4],
            accQ[0]+bQ[0], accQ[1]+bQ[1], accQ[2]+bQ[2], accQ[3]+bQ[3]);
      #pragma unroll
      for (int r = 0; r < 4; ++r) x1r[nt][r] = acc1[r] + b1a[r];
      st4bf(&Sts[bt*SW + c0 + quad*4],
            accS[0] + ut*Mv[0] + bS[0]*(1.f+Rn), accS[1] + ut*Mv[1] + bS[1]*(1.f+Rn),
            accS[2] + ut*Mv[2] + bS[2]*(1.f+Rn), accS[3] + ut*Mv[3] + bS[3]*(1.f+Rn));
    }
  }
  __syncthreads();

  // ---- phase 3: K_t, V_t from D; re-zero V2 cols 24..31 (Pts dead) ----
  {
    for (int i = tid; i < 512; i += 256) V2[(i>>3)*40 + 24 + (i&7)] = 0;
    bf16x8 aK0 = *(const bf16x8*)(WBF + WB_KT + (c0+l15)*64 + quad*8);
    bf16x8 aK1 = *(const bf16x8*)(WBF + WB_KT + (c0+l15)*64 + 32 + quad*8);
    bf16x8 aV0 = *(const bf16x8*)(WBF + WB_VT + (c0+l15)*64 + quad*8);
    bf16x8 aV1 = *(const bf16x8*)(WBF + WB_VT + (c0+l15)*64 + 32 + quad*8);
    float4 bK4 = *(const float4*)&bk_t[c0 + quad*4];
    float4 bV4 = *(const float4*)&bv_t[c0 + quad*4];
    float bK[4] = {bK4.x,bK4.y,bK4.z,bK4.w};
    float bV[4] = {bV4.x,bV4.y,bV4.z,bV4.w};
    #pragma unroll
    for (int nt = 0; nt < 2; ++nt) {
      int bt = nt*16 + l15;
      bf16x8 b0 = *(const bf16x8*)&bufD[bt*SW + quad*8];
      bf16x8 b1v = *(const bf16x8*)&bufD[bt*SW + 32 + quad*8];
      f32x4 accK = {0.f,0.f,0.f,0.f}, accV = {0.f,0.f,0.f,0.f};
      accK = __builtin_amdgcn_mfma_f32_16x16x32_bf16(aK0, b0,  accK, 0,0,0);
      accK = __builtin_amdgcn_mfma_f32_16x16x32_bf16(aK1, b1v, accK, 0,0,0);
      accV = __builtin_amdgcn_mfma_f32_16x16x32_bf16(aV0, b0,  accV, 0,0,0);
      accV = __builtin_amdgcn_mfma_f32_16x16x32_bf16(aV1, b1v, accV, 0,0,0);
      st4bf(&bufK[bt*SW + c0 + quad*4],
            accK[0]+bK[0], accK[1]+bK[1], accK[2]+bK[2], accK[3]+bK[3]);
      if (bt < 24) {
        #pragma unroll
        for (int r = 0; r < 4; ++r)
          V2[(c0 + quad*4 + r)*40 + bt] = f2bfb(accV[r] + bV[r]);
      }
    }
  }
  __syncthreads();

  // ---- phase 4 + softmax 1 in-register (waves 0,1) -> scb (bufD region) ----
  if (wave < 2) {
    const int mt = wave * 16;
    bf16x8 a0 = *(const bf16x8*)&bufQ[(mt+l15)*SW + quad*8];
    bf16x8 a1f = *(const bf16x8*)&bufQ[(mt+l15)*SW + 32 + quad*8];
    bf16x8 k0a = *(const bf16x8*)&bufK[l15*SW + quad*8];
    bf16x8 k0b = *(const bf16x8*)&bufK[l15*SW + 32 + quad*8];
    bf16x8 k1a = *(const bf16x8*)&bufK[(16+l15)*SW + quad*8];
    bf16x8 k1b = *(const bf16x8*)&bufK[(16+l15)*SW + 32 + quad*8];
    f32x4 s0 = {0.f,0.f,0.f,0.f}, s1 = {0.f,0.f,0.f,0.f};
    s0 = __builtin_amdgcn_mfma_f32_16x16x32_bf16(a0, k0a, s0, 0,0,0);
    s0 = __builtin_amdgcn_mfma_f32_16x16x32_bf16(a1f, k0b, s0, 0,0,0);
    s1 = __builtin_amdgcn_mfma_f32_16x16x32_bf16(a0, k1a, s1, 0,0,0);
    s1 = __builtin_amdgcn_mfma_f32_16x16x32_bf16(a1f, k1b, s1, 0,0,0);
    #pragma unroll
    for (int r = 0; r < 4; ++r) {
      float v0 = 0.125f * s0[r];
      float v1 = (l15 < 8) ? 0.125f * s1[r] : -3.0e38f;
      float mx = fmaxf(v0, v1);
      mx = fmaxf(mx, __shfl_xor(mx, 1));
      mx = fmaxf(mx, __shfl_xor(mx, 2));
      mx = fmaxf(mx, __shfl_xor(mx, 4));
      mx = fmaxf(mx, __shfl_xor(mx, 8));
      float e0 = __expf(v0 - mx);
      float e1 = (l15 < 8) ? __expf(v1 - mx) : 0.f;
      float sm = e0 + e1;
      sm += __shfl_xor(sm, 1);
      sm += __shfl_xor(sm, 2);
      sm += __shfl_xor(sm, 4);
      sm += __shfl_xor(sm, 8);
      float inv = 1.f / sm;
      int t = mt + quad*4 + r;
      bool tv = (t < 24);
      scb[t*40 + l15]      = tv ? f2bfb(e0 * inv) : (ushort_t)0;
      scb[t*40 + 16 + l15] = (tv && l15 < 8) ? f2bfb(e1 * inv) : (ushort_t)0;
    }
  }
  __syncthreads();

  // ---- phase 5: XD[c][t] = V P^T (swapped operands) + x1(regs) -> XDg ----
  {
    for (int i = tid; i < 640; i += 256) {
      int r = i >> 6, cg = i & 63;
      int row = (r == 0) ? 0 : (24 + r);
      XDg[row*SW + cg] = 0;
    }
    bf16x8 aV = *(const bf16x8*)&V2[(c0 + l15)*40 + quad*8];
    #pragma unroll
    for (int nt = 0; nt < 2; ++nt) {
      bf16x8 bP = *(const bf16x8*)&scb[(nt*16 + l15)*40 + quad*8];
      f32x4 z = {0.f,0.f,0.f,0.f};
      f32x4 acc = __builtin_amdgcn_mfma_f32_16x16x32_bf16(aV, bP, z, 0,0,0);
      int t = nt*16 + l15;
      if (t < 24) {
        #pragma unroll
        for (int r = 0; r < 4; ++r)
          XDg[(1 + t)*SW + c0 + quad*4 + r] = f2bfb(acc[r] + x1r[nt][r]);
      }
    }
  }
  __syncthreads();

  // ---- phase 6: x1c = conv_t(XD) -> bufD ----
  {
    float4 bc4 = *(const float4*)&b_c1[c0 + quad*4];
    float bc[4] = {bc4.x,bc4.y,bc4.z,bc4.w};
    f32x4 acc0 = {0.f,0.f,0.f,0.f}, acc1v = {0.f,0.f,0.f,0.f};
    #pragma unroll
    for (int d = 0; d < 3; ++d) {
      const ushort_t* Ad = WBF + WB_C1A + d*4096;
      bf16x8 a0 = *(const bf16x8*)(Ad + (c0+l15)*64 + quad*8);
      bf16x8 a1f = *(const bf16x8*)(Ad + (c0+l15)*64 + 32 + quad*8);
      {
        int rr = 0*16 + l15 + d;
        bf16x8 b0 = *(const bf16x8*)&XDg[rr*SW + quad*8];
        bf16x8 b1f = *(const bf16x8*)&XDg[rr*SW + 32 + quad*8];
        acc0 = __builtin_amdgcn_mfma_f32_16x16x32_bf16(a0, b0, acc0, 0,0,0);
        acc0 = __builtin_amdgcn_mfma_f32_16x16x32_bf16(a1f, b1f, acc0, 0,0,0);
      }
      {
        int rr = 1*16 + l15 + d;
        bf16x8 b0 = *(const bf16x8*)&XDg[rr*SW + quad*8];
        bf16x8 b1f = *(const bf16x8*)&XDg[rr*SW + 32 + quad*8];
        acc1v = __builtin_amdgcn_mfma_f32_16x16x32_bf16(a0, b0, acc1v, 0,0,0);
        acc1v = __builtin_amdgcn_mfma_f32_16x16x32_bf16(a1f, b1f, acc1v, 0,0,0);
      }
    }
    st4bf(&bufD[(0*16 + l15)*SW + c0 + quad*4],
          acc0[0]+bc[0], acc0[1]+bc[1], acc0[2]+bc[2], acc0[3]+bc[3]);
    st4bf(&bufD[(1*16 + l15)*SW + c0 + quad*4],
          acc1v[0]+bc[0], acc1v[1]+bc[1], acc1v[2]+bc[2], acc1v[3]+bc[3]);
  }
  __syncthreads();

  // ---- phase 7: Q_s (from x1c=bufD), K_s, V_s (from S) ----
  {
    bf16x8 aq0 = *(const bf16x8*)(WBF + WB_QS + (c0+l15)*64 + quad*8);
    bf16x8 aq1 = *(const bf16x8*)(WBF + WB_QS + (c0+l15)*64 + 32 + quad*8);
    bf16x8 ak0 = *(const bf16x8*)(WBF + WB_KS + (c0+l15)*64 + quad*8);
    bf16x8 ak1 = *(const bf16x8*)(WBF + WB_KS + (c0+l15)*64 + 32 + quad*8);
    bf16x8 av0 = *(const bf16x8*)(WBF + WB_VS + (c0+l15)*64 + quad*8);
    bf16x8 av1 = *(const bf16x8*)(WBF + WB_VS + (c0+l15)*64 + 32 + quad*8);
    float4 bq4 = *(const float4*)&bq_s[c0 + quad*4];
    float4 bk4 = *(const float4*)&bk_s[c0 + quad*4];
    float4 bv4 = *(const float4*)&bv_s[c0 + quad*4];
    float bq[4] = {bq4.x,bq4.y,bq4.z,bq4.w};
    float bk[4] = {bk4.x,bk4.y,bk4.z,bk4.w};
    float bv[4] = {bv4.x,bv4.y,bv4.z,bv4.w};
    #pragma unroll
    for (int nt = 0; nt < 2; ++nt) {
      int bt = nt*16 + l15;
      bf16x8 bx0 = *(const bf16x8*)&bufD[bt*SW + quad*8];
      bf16x8 bx1 = *(const bf16x8*)&bufD[bt*SW + 32 + quad*8];
      bf16x8 bs0 = *(const bf16x8*)&Sts[bt*SW + quad*8];
      bf16x8 bs1 = *(const bf16x8*)&Sts[bt*SW + 32 + quad*8];
      f32x4 accQ = {0.f,0.f,0.f,0.f}, accK = {0.f,0.f,0.f,0.f}, accV = {0.f,0.f,0.f,0.f};
      accQ = __builtin_amdgcn_mfma_f32_16x16x32_bf16(aq0, bx0, accQ, 0,0,0);
      accQ = __builtin_amdgcn_mfma_f32_16x16x32_bf16(aq1, bx1, accQ, 0,0,0);
      accK = __builtin_amdgcn_mfma_f32_16x16x32_bf16(ak0, bs0, accK, 0,0,0);
      accK = __builtin_amdgcn_mfma_f32_16x16x32_bf16(ak1, bs1, accK, 0,0,0);
      accV = __builtin_amdgcn_mfma_f32_16x16x32_bf16(av0, bs0, accV, 0,0,0);
      accV = __builtin_amdgcn_mfma_f32_16x16x32_bf16(av1, bs1, accV, 0,0,0);
      st4bf(&bufQ[bt*SW + c0 + quad*4],
            accQ[0]+bq[0], accQ[1]+bq[1], accQ[2]+bq[2], accQ[3]+bq[3]);
      st4bf(&bufK[bt*SW + c0 + quad*4],
            accK[0]+bk[0], accK[1]+bk[1], accK[2]+bk[2], accK[3]+bk[3]);
      if (bt < 24) {
        #pragma unroll
        for (int r = 0; r < 4; ++r)
          V2[(c0 + quad*4 + r)*40 + bt] = f2bfb(accV[r] + bv[r]);
      }
    }
  }
  __syncthreads();

  // ---- phase 8 + softmax 2 in-register (waves 0,1) -> scb (bufD region) ----
  if (wave < 2) {
    const int mt = wave * 16;
    bf16x8 a0 = *(const bf16x8*)&bufQ[(mt+l15)*SW + quad*8];
    bf16x8 a1f = *(const bf16x8*)&bufQ[(mt+l15)*SW + 32 + quad*8];
    bf16x8 k0a = *(const bf16x8*)&bufK[l15*SW + quad*8];
    bf16x8 k0b = *(const bf16x8*)&bufK[l15*SW + 32 + quad*8];
    bf16x8 k1a = *(const bf16x8*)&bufK[(16+l15)*SW + quad*8];
    bf16x8 k1b = *(const bf16x8*)&bufK[(16+l15)*SW + 32 + quad*8];
    f32x4 s0 = {0.f,0.f,0.f,0.f}, s1 = {0.f,0.f,0.f,0.f};
    s0 = __builtin_amdgcn_mfma_f32_16x16x32_bf16(a0, k0a, s0, 0,0,0);
    s0 = __builtin_amdgcn_mfma_f32_16x16x32_bf16(a1f, k0b, s0, 0,0,0);
    s1 = __builtin_amdgcn_mfma_f32_16x16x32_bf16(a0, k1a, s1, 0,0,0);
    s1 = __builtin_amdgcn_mfma_f32_16x16x32_bf16(a1f, k1b, s1, 0,0,0);
    #pragma unroll
    for (int r = 0; r < 4; ++r) {
      float v0 = 0.125f * s0[r];
      float v1 = (l15 < 8) ? 0.125f * s1[r] : -3.0e38f;
      float mx = fmaxf(v0, v1);
      mx = fmaxf(mx, __shfl_xor(mx, 1));
      mx = fmaxf(mx, __shfl_xor(mx, 2));
      mx = fmaxf(mx, __shfl_xor(mx, 4));
      mx = fmaxf(mx, __shfl_xor(mx, 8));
      float e0 = __expf(v0 - mx);
      float e1 = (l15 < 8) ? __expf(v1 - mx) : 0.f;
      float sm = e0 + e1;
      sm += __shfl_xor(sm, 1);
      sm += __shfl_xor(sm, 2);
      sm += __shfl_xor(sm, 4);
      sm += __shfl_xor(sm, 8);
      float inv = 1.f / sm;
      int t = mt + quad*4 + r;
      bool tv = (t < 24);
      scb[t*40 + l15]      = tv ? f2bfb(e0 * inv) : (ushort_t)0;
      scb[t*40 + 16 + l15] = (tv && l15 < 8) ? f2bfb(e1 * inv) : (ushort_t)0;
    }
  }
  __syncthreads();

  // ---- phase 9: XS = A_s @ V_s -> global [n][b][c][t] ----
  {
    int nc = wave * 16;
    bf16x8 bv0 = *(const bf16x8*)&V2[(nc + l15)*40 + quad*8];
    #pragma unroll
    for (int mt = 0; mt < 2; ++mt) {
      bf16x8 af = *(const bf16x8*)&scb[(mt*16 + l15)*40 + quad*8];
      f32x4 z = {0.f,0.f,0.f,0.f};
      f32x4 acc = __builtin_amdgcn_mfma_f32_16x16x32_bf16(af, bv0, z, 0,0,0);
      int ccol = nc + l15;
      int t0 = mt*16 + quad*4;
      if (t0 < 24) {
        uint2 w;
        w.x = rne2(acc[0], acc[1]);
        w.y = rne2(acc[2], acc[3]);
        *(uint2*)(XS + (size_t)n*XS_COLS + (size_t)b*COUT_*T_ + ccol*T_ + t0) = w;
      }
    }
  }
}

// ---------------------------------------------------------------------------
// k_final R9: Chebyshev-gate + x1 GEMMs on MFMA.
//  - Zt staged via uint4 vector loads (XS/Y1h/Y2h per-block slices are
//    contiguous 1536 elems each) — was 4608 scalar 2B loads + div per elem.
//  - xb staged from xbf via gl_lds16 (wave-aligned from lane 0), stride 32.
//  - Zt/xb guard rows dropped: B-frag row t only feeds output column t, and
//    all t>=24 outputs are guarded off (same invariant as k_attn, passed).
// ---------------------------------------------------------------------------
#define ZW 200
__global__ __launch_bounds__(256) void k_final(
    const ushort_t* __restrict__ xbf,
    const ushort_t* __restrict__ XS, const ushort_t* __restrict__ Y1h,
    const ushort_t* __restrict__ Y2h,
    const ushort_t* __restrict__ WGBF, const ushort_t* __restrict__ WBF,
    const float* __restrict__ b_1, const float* __restrict__ b_g,
    int h, float* __restrict__ out)
{
  const int n = blockIdx.x, bb = blockIdx.y, tid = threadIdx.x;
  const int b = h * 8 + bb;
  const int wave = tid >> 6, lane = tid & 63;
  const int l15 = lane & 15, quad = lane >> 4;

  __shared__ __align__(16) ushort_t Zt[32*ZW];   // 12800 B, rows 24-31 stale
  __shared__ __align__(16) ushort_t xb[32*32];   // 2048 B, rows 24-31 stale

  const size_t baseg = (size_t)n * XS_COLS + (size_t)b * COUT_ * T_;
  const size_t baseh = (size_t)n * HALF_COLS + (size_t)bb * COUT_ * T_;

  // xb <- xbf (contiguous 768 ushorts = 96 16B-chunks), wave-aligned gl_lds16
  {
    const ushort_t* xsrc = xbf + (size_t)(b * N_ + n) * T_ * 32;
    if (wave == 0)                 gl_lds16(xsrc + lane * 8, &xb[lane * 8]);
    else if (wave == 1 && lane < 32) gl_lds16(xsrc + (64 + lane) * 8, &xb[(64 + lane) * 8]);
  }
  // Zt <- XS/Y1h/Y2h interleaved: 576 uint4 loads, incremental (c,t) unpack
  for (int i = tid; i < 576; i += 256) {
    int a = i / 192, r = i - a * 192;
    const ushort_t* src = (a == 0) ? (XS + baseg) : (a == 1) ? (Y1h + baseh) : (Y2h + baseh);
    union { uint4 q; ushort_t s[8]; } v;
    v.q = ((const uint4*)src)[r];
    int e0 = r * 8;
    int c = e0 / 24, t = e0 - c * 24;
    #pragma unroll
    for (int e = 0; e < 8; ++e) {
      Zt[t * ZW + 3 * c + a] = v.s[e];
      if (++t == 24) { t = 0; ++c; }
    }
  }
  __syncthreads();

  f32x4 accF[2] = {{0.f,0.f,0.f,0.f},{0.f,0.f,0.f,0.f}};
  f32x4 accG[2] = {{0.f,0.f,0.f,0.f},{0.f,0.f,0.f,0.f}};
  f32x4 accX[2] = {{0.f,0.f,0.f,0.f},{0.f,0.f,0.f,0.f}};
  const ushort_t* WF = WGBF + (size_t)(wave*16 + l15)*192 + quad*8;
  const ushort_t* WG = WF + 64*192;
  bf16x8 aW1 = *(const bf16x8*)(WBF + WB_1 + (wave*16 + l15)*32 + quad*8);
  #pragma unroll
  for (int nt = 0; nt < 2; ++nt) {
    bf16x8 bx = *(const bf16x8*)&xb[(nt*16 + l15)*32 + quad*8];
    accX[nt] = __builtin_amdgcn_mfma_f32_16x16x32_bf16(aW1, bx, accX[nt], 0,0,0);
  }
  #pragma unroll
  for (int ks = 0; ks < 6; ++ks) {
    bf16x8 wf = *(const bf16x8*)(WF + ks*32);
    bf16x8 wg = *(const bf16x8*)(WG + ks*32);
    #pragma unroll
    for (int nt = 0; nt < 2; ++nt) {
      bf16x8 bz = *(const bf16x8*)&Zt[(nt*16 + l15)*ZW + ks*32 + quad*8];
      accF[nt] = __builtin_amdgcn_mfma_f32_16x16x32_bf16(wf, bz, accF[nt], 0,0,0);
      accG[nt] = __builtin_amdgcn_mfma_f32_16x16x32_bf16(wg, bz, accG[nt], 0,0,0);
    }
  }

  {
    float4 bgF4 = *(const float4*)&b_g[wave*16 + quad*4];
    float4 bgG4 = *(const float4*)&b_g[64 + wave*16 + quad*4];
    float4 b14  = *(const float4*)&b_1[wave*16 + quad*4];
    float bgF[4] = {bgF4.x, bgF4.y, bgF4.z, bgF4.w};
    float bgG[4] = {bgG4.x, bgG4.y, bgG4.z, bgG4.w};
    float b1a[4] = {b14.x, b14.y, b14.z, b14.w};
    #pragma unroll
    for (int nt = 0; nt < 2; ++nt) {
      int t = nt*16 + l15;
      if (t < 24) {
        #pragma unroll
        for (int r = 0; r < 4; ++r) {
          int c = wave*16 + quad*4 + r;
          float fv = accF[nt][r] + bgF[r] + accX[nt][r] + b1a[r];
          float gv = accG[nt][r] + bgG[r];
          out[(((size_t)b * COUT_ + c) * N_ + n) * T_ + t] = fv * sigm_(gv);
        }
      }
    }
  }
}

// ---------------------------------------------------------------------------
extern "C" void kernel_launch(void* const* d_in, const int* in_sizes, int n_in,
                              void* d_out, int out_size, void* d_ws, size_t ws_size,
                              hipStream_t stream) {
  const float* x        = (const float*)d_in[0];
  const float* supports = (const float*)d_in[1];
  const float* CD       = (const float*)d_in[2];
  const float* CS       = (const float*)d_in[3];
  const float* adj      = (const float*)d_in[4];
  const float* W_de  = (const float*)d_in[5];  const float* b_de  = (const float*)d_in[6];
  const float* Wd    = (const float*)d_in[7];
  const float* W_pro = (const float*)d_in[8];  const float* b_pro = (const float*)d_in[9];
  const float* W_mii = (const float*)d_in[10]; const float* b_mii = (const float*)d_in[11];
  const float* W_1   = (const float*)d_in[12]; const float* b_1   = (const float*)d_in[13];
  const float* Wq_t  = (const float*)d_in[14]; const float* bq_t  = (const float*)d_in[15];
  const float* Wk_t  = (const float*)d_in[16]; const float* bk_t  = (const float*)d_in[17];
  const float* Wv_t  = (const float*)d_in[18]; const float* bv_t  = (const float*)d_in[19];
  const float* W_c1  = (const float*)d_in[20]; const float* b_c1  = (const float*)d_in[21];
  const float* Wq_s  = (const float*)d_in[22]; const float* bq_s  = (const float*)d_in[23];
  const float* Wk_s  = (const float*)d_in[24]; const float* bk_s  = (const float*)d_in[25];
  const float* Wv_s  = (const float*)d_in[26]; const float* bv_s  = (const float*)d_in[27];
  const float* W_g   = (const float*)d_in[28]; const float* b_g   = (const float*)d_in[29];
  float* out = (float*)d_out;

  char* ws = (char*)d_ws;
  float*    delay = (float*)(ws + OFF_DELAY);
  float*    Mbuf  = (float*)(ws + OFF_M);
  float*    Rbuf  = (float*)(ws + OFF_R);
  float*    u     = (float*)(ws + OFF_U);
  ushort_t* WGBF  = (ushort_t*)(ws + OFF_WGBF);
  ushort_t* Sbf   = (ushort_t*)(ws + OFF_SBF);
  ushort_t* adjbf = (ushort_t*)(ws + OFF_ADJBF);
  ushort_t* STbf  = (ushort_t*)(ws + OFF_STBF);
  ushort_t* L2bf  = (ushort_t*)(ws + OFF_L2BF);
  ushort_t* Ue    = (ushort_t*)(ws + OFF_X1);
  ushort_t* P     = (ushort_t*)(ws + OFF_X1);   // overwrites Ue (dead)
  ushort_t* xbf   = (ushort_t*)(ws + OFF_X2);   // bf16 x copy (steps 4-8)
  ushort_t* XST   = (ushort_t*)(ws + OFF_X2);   // overwrites xbf (step 8; xbf
                                                // still read by k_final via
                                                // stream-ordered? NO — see note)
  ushort_t* UeT   = (ushort_t*)(ws + OFF_Y1H);  // temp (steps 5-6)
  ushort_t* XS    = (ushort_t*)(ws + OFF_XS);
  ushort_t* Y1h   = (ushort_t*)(ws + OFF_Y1H);
  ushort_t* Y2h   = (ushort_t*)(ws + OFF_Y2H);
  ushort_t* WBF   = (ushort_t*)(ws + OFF_WBF);

  (void)in_sizes; (void)n_in; (void)out_size; (void)ws_size;

  // NOTE: k_final now reads xbf, and XST aliases xbf's region. The h-loop
  // transposes XS half h into XST *before* k_final(h) runs — but k_final
  // reads xbf rows for ALL b in [h*8, h*8+8). XST is 12.58 MB and xbf is
  // 25.17 MB; XST overwrites the FIRST half of the region. xbf rows for
  // b >= 8 live in the second half (offset b*N*T*32 elems >= 12.58 MB).
  // For h=0: k_final reads b=0..7 (first half of xbf) but XST(h=0) has
  // already clobbered it -> WRONG. Fix: transpose order swapped — process
  // h=1 first (XST clobbers first half while k_final(h=1) reads second
  // half), then h=0 would read clobbered first half. Still wrong.
  // => keep xbf alive: place XST in the UeT slot (Y1H region) instead?
  // Y1h is written by k_mmy in the same iteration. Use Y2H+? No.
  // Resolution: XST moves to the SECOND half-region trick is fragile;
  // instead allocate XST after WBF (ws tail) — 12.58 MB at OFF_XST.
  ushort_t* XSTt = (ushort_t*)(ws + 149078016ul);  // after WBF (81920 B), 12.58 MB

  // 1) conversions + weight prep + delay/Mbuf/Rbuf (k_pre merged)
  k_prep<<<dim3((PREP_TOTAL + 255)/256), 256, 0, stream>>>(
      supports, adj, W_de, Wq_t, W_1, W_mii, Wk_t, Wv_t, Wq_s, Wk_s, Wv_s,
      W_c1, W_g, CD, Wd, CS, Sbf, adjbf, WGBF, WBF, delay, Mbuf, Rbuf);
  // 2) S^T via coalesced transpose
  k_tr<<<dim3(N_/32, N_/32), 256, 0, stream>>>(Sbf, STbf, N_, N_);
  // 3) L2 = 2*S@S - I
  k_mmx<2><<<dim3(8, 8), 256, 0, stream>>>(Sbf, STbf, L2bf, 1024);
  // 4) u + Ue + xbf
  k_u<<<dim3((BNT_ + 255)/256), 256, 0, stream>>>(x, W_pro, b_pro, CS, u, Ue, xbf);
  // 5) UeT (Y1H region — xbf owns X2)
  k_tr<<<dim3(UE_COLS/32, N_/32), 256, 0, stream>>>(Ue, UeT, N_, UE_COLS);
  // 6) P = adj @ Ue
  k_mmx<0><<<dim3(UE_COLS/128, N_/128), 256, 0, stream>>>(adjbf, UeT, P, UE_COLS);
  // 7) MFMA attention pipeline -> XS
  k_attn_mfma<<<dim3(N_, B_), 256, 0, stream>>>(
      xbf, delay, Mbuf, Rbuf, u, P, WBF,
      b_de, bq_t, b_1, b_mii, bk_t, bv_t, bq_s, bk_s, bv_s, b_c1, XS);
  // 8) per half: transpose (XSTt tail region — xbf stays live for k_final),
  //    fused Y1/Y2 GEMM, final
  for (int h = 0; h < 2; ++h) {
    k_tr<<<dim3(HALF_COLS/32, N_/32), 256, 0, stream>>>(
        XS + (size_t)h * HALF_COLS, XSTt, N_, XS_COLS);
    k_mmy<<<dim3(HALF_COLS/128, 16), 256, 0, stream>>>(
        Sbf, L2bf, XSTt, Y1h, Y2h, HALF_COLS);
    k_final<<<dim3(N_, 8), 256, 0, stream>>>(
        xbf, XS, Y1h, Y2h, WGBF, WBF, b_1, b_g, h, out);
  }
  (void)XST;
}